// Round 3
// baseline (2204.903 us; speedup 1.0000x reference)
//
#include <hip/hip_runtime.h>
#include <hip/hip_bf16.h>

#define HID 96
#define INDIM 128
#define OUTDIM 64
#define THID (3*HID)   // 288
#define NT 4

__device__ __forceinline__ float ldmix(const void* p, long i, int mode) {
    return mode ? ((const float*)p)[i]
                : __bfloat162float(((const __hip_bfloat16*)p)[i]);
}

// ---------------- dtype sniffer: fp32 data has uniform-random low 16 bits ----------------
__global__ void sniff_kernel(const unsigned int* xw, int* mode) {
    if (threadIdx.x == 0 && blockIdx.x == 0) {
        int cnt = 0;
        for (int i = 0; i < 4096; i++) {
            unsigned int low = xw[i] & 0xFFFFu;
            unsigned int e = (low >> 7) & 0xFFu;
            if (e >= 0xC0u) cnt++;   // |value| >= 2^65 or NaN/Inf as bf16: never for real data
        }
        *mode = (cnt > 256) ? 1 : 0;  // 1 = fp32 inputs, 0 = bf16 inputs
    }
}

// ---------------- x -> fp32 ----------------
__global__ void xconv_kernel(const void* x, float* __restrict__ x_f, const int* mode, int total) {
    int m = *mode;
    int tid = blockIdx.x*blockDim.x + threadIdx.x;
    if (tid < total) x_f[tid] = ldmix(x, tid, m);
}

// ---------------- weight prep: -> fp32, transpose GRU weights ----------------
// smallf layout: [0..95] b_in, [96..383] bih, [384..671] bhh, [672..735] b_out,
//                [736..751] tau_w2, [752..767] tau_b1, [768] tau_b2
__global__ void prep_kernel(const void* w_in, const void* b_in, const void* tau_w1,
                            const void* tau_b1, const void* tau_w2, const void* tau_b2,
                            const void* wih, const void* whh, const void* bih, const void* bhh,
                            const void* w_out, const void* b_out,
                            float* wihT, float* whhT, float* w_in_f, float* w_out_f,
                            float* tau_w1_f, float* smallf, const int* mode) {
    int m = *mode;
    int tid = blockIdx.x*blockDim.x + threadIdx.x;
    if (tid < THID*HID) {           // 27648: transpose [288,96] -> [96,288]
        int j = tid / HID, k = tid % HID;
        wihT[k*THID + j] = ldmix(wih, tid, m);
        whhT[k*THID + j] = ldmix(whh, tid, m);
    }
    if (tid < INDIM*HID)  w_in_f[tid]   = ldmix(w_in, tid, m);
    if (tid < HID*OUTDIM) w_out_f[tid]  = ldmix(w_out, tid, m);
    if (tid < INDIM*16)   tau_w1_f[tid] = ldmix(tau_w1, tid, m);
    if (tid < HID)    smallf[tid]       = ldmix(b_in, tid, m);
    if (tid < THID) { smallf[96+tid]    = ldmix(bih, tid, m);
                      smallf[384+tid]   = ldmix(bhh, tid, m); }
    if (tid < OUTDIM) smallf[672+tid]   = ldmix(b_out, tid, m);
    if (tid < 16)   { smallf[736+tid]   = ldmix(tau_w2, tid, m);
                      smallf[752+tid]   = ldmix(tau_b1, tid, m); }
    if (tid == 0)     smallf[768]       = ldmix(tau_b2, 0, m);
}

// ---------------- h0 = relu(x @ w_in + b_in) ----------------
__global__ void h0_kernel(const float* __restrict__ x_f, const float* __restrict__ w_in_f,
                          const float* __restrict__ smallf, float* __restrict__ h, int N) {
    int tid = blockIdx.x*blockDim.x + threadIdx.x;
    if (tid >= N*HID) return;
    int n = tid / HID, j = tid % HID;
    const float* xr = x_f + (size_t)n*INDIM;
    float acc = smallf[j];
    #pragma unroll 8
    for (int k = 0; k < INDIM; k++) acc += xr[k] * w_in_f[k*HID + j];
    h[tid] = fmaxf(acc, 0.f);
}

// ---------------- tau MLP -> steps (wave per node, coalesced) ----------------
__global__ void tau_kernel(const float* __restrict__ x_f, const float* __restrict__ tau_w1_f,
                           const float* __restrict__ smallf,
                           int* __restrict__ steps, int* cnt6, int N) {
    int gtid = blockIdx.x*blockDim.x + threadIdx.x;
    int n = gtid >> 6;          // wave per node
    int lane = threadIdx.x & 63;
    if (n >= N) return;
    const float* xr = x_f + (size_t)n*INDIM;
    float x0 = xr[lane];        // coalesced 256B wave-load
    float x1 = xr[64 + lane];
    const float* w0 = tau_w1_f + lane*16;        // L1-resident (8 KB total)
    const float* w1 = tau_w1_f + (64 + lane)*16;
    float acc[16];
    #pragma unroll
    for (int j = 0; j < 16; j++) acc[j] = x0*w0[j] + x1*w1[j];
    // butterfly reduce 16 accumulators across 64 lanes
    #pragma unroll
    for (int ofs = 32; ofs > 0; ofs >>= 1) {
        #pragma unroll
        for (int j = 0; j < 16; j++) acc[j] += __shfl_down(acc[j], ofs);
    }
    if (lane == 0) {
        float z = smallf[768];
        #pragma unroll
        for (int j = 0; j < 16; j++) z += fmaxf(acc[j] + smallf[752+j], 0.f) * smallf[736+j];
        // softplus, stable form: max(z,0) + log1p(exp(-|z|))
        float tau = fmaxf(z, 0.f) + log1pf(expf(-fabsf(z)));
        float inv = 1.0f / tau;
        int s;
        if (inv >= 5.0f) s = 5;
        else { s = (int)inv; if (s < 0) s = 0; if (s > 5) s = 5; }
        steps[n] = s;
        atomicAdd(&cnt6[s], 1);
    }
}

// ---------------- CSR build ----------------
__global__ void deg_kernel(const int* __restrict__ row, int* deg, int E) {
    int e = blockIdx.x*blockDim.x + threadIdx.x;
    if (e < E) atomicAdd(&deg[row[e]], 1);
}

// single-block scan: off = exclusive_scan(deg); also bucket starts (descending steps)
__global__ void scan_kernel(const int* __restrict__ deg, int* __restrict__ off,
                            const int* __restrict__ cnt6, int* __restrict__ bstart, int N) {
    __shared__ int buf[1024];
    int tid = threadIdx.x;
    int C = (N + 1023) / 1024;
    int start = tid * C, end = min(start + C, N);
    if (end < start) end = start;
    int s = 0;
    for (int i = start; i < end; i++) s += deg[i];
    buf[tid] = s; __syncthreads();
    for (int ofs = 1; ofs < 1024; ofs <<= 1) {
        int t = (tid >= ofs) ? buf[tid - ofs] : 0;
        __syncthreads();
        buf[tid] += t;
        __syncthreads();
    }
    int incl = buf[tid];
    int run = incl - s;                 // exclusive prefix for this chunk
    for (int i = start; i < end; i++) { off[i] = run; run += deg[i]; }
    if (tid == 1023) off[N] = incl;     // = E
    if (tid == 0) {
        int running = 0;
        for (int ss = 5; ss >= 0; --ss) { bstart[ss] = running; running += cnt6[ss]; }
        bstart[6] = running;            // = N
    }
}

__global__ void fill_kernel(const int* __restrict__ row, const int* __restrict__ col,
                            const int* __restrict__ off, int* cur, int* __restrict__ csr_col, int E) {
    int e = blockIdx.x*blockDim.x + threadIdx.x;
    if (e >= E) return;
    int r = row[e];
    int p = atomicAdd(&cur[r], 1);
    csr_col[off[r] + p] = col[e];
}

// order nodes by descending steps (counting-sort scatter). K[t] = bstart[t].
__global__ void order_kernel(const int* __restrict__ steps, const int* __restrict__ bstart,
                             int* cur6, int* __restrict__ order, int N) {
    int n = blockIdx.x*blockDim.x + threadIdx.x;
    if (n >= N) return;
    int s = steps[n];
    int p = atomicAdd(&cur6[s], 1);
    order[bstart[s] + p] = n;
}

// ---------------- iteration kernels (grid-stride; active count read from device) ----------------
__global__ void agg_kernel(const float* __restrict__ h, const int* __restrict__ off,
                           const int* __restrict__ csr_col, const int* __restrict__ order,
                           const int* __restrict__ bstart, int t, float* __restrict__ agg) {
    int K = bstart[t];
    int total = K * HID;
    int stride = gridDim.x * blockDim.x;
    for (int idx = blockIdx.x*blockDim.x + threadIdx.x; idx < total; idx += stride) {
        int li = idx / HID, f = idx % HID;
        int i = order[li];
        float hv = h[i*HID + f];
        int e0 = off[i], e1 = off[i+1];
        float acc = 0.f;
        for (int e = e0; e < e1; e++) {
            int c = csr_col[e];
            acc += fabsf(hv - h[c*HID + f]);
        }
        agg[i*HID + f] = acc;
    }
}

__global__ void gru_kernel(const float* __restrict__ h, const float* __restrict__ agg,
                           const float* __restrict__ wihT, const float* __restrict__ whhT,
                           const float* __restrict__ smallf, const int* __restrict__ order,
                           const int* __restrict__ bstart, int t, float* __restrict__ hnew) {
    int K = bstart[t];
    int tiles = (K + NT - 1) / NT;
    int total = tiles * HID;
    int stride = gridDim.x * blockDim.x;
    for (int idx = blockIdx.x*blockDim.x + threadIdx.x; idx < total; idx += stride) {
        int tile = idx / HID, jj = idx % HID;
        int n[NT]; bool valid[NT];
        #pragma unroll
        for (int u = 0; u < NT; u++) {
            int li = tile*NT + u;
            valid[u] = li < K;
            n[u] = valid[u] ? order[li] : order[0];
        }
        float gri[NT], gzi[NT], gni[NT], grh[NT], gzh[NT], gnh[NT];
        #pragma unroll
        for (int u = 0; u < NT; u++) { gri[u]=gzi[u]=gni[u]=grh[u]=gzh[u]=gnh[u]=0.f; }
        for (int k = 0; k < HID; k++) {
            const float* wi = wihT + k*THID;
            const float* wh = whhT + k*THID;
            float wi0 = wi[jj], wi1 = wi[HID+jj], wi2 = wi[2*HID+jj];
            float wh0 = wh[jj], wh1 = wh[HID+jj], wh2 = wh[2*HID+jj];
            #pragma unroll
            for (int u = 0; u < NT; u++) {
                float a  = agg[n[u]*HID + k];
                float hv = h  [n[u]*HID + k];
                gri[u] += a*wi0;  gzi[u] += a*wi1;  gni[u] += a*wi2;
                grh[u] += hv*wh0; gzh[u] += hv*wh1; gnh[u] += hv*wh2;
            }
        }
        float bir = smallf[96+jj],  biz = smallf[96+HID+jj],  bin = smallf[96+2*HID+jj];
        float bhr = smallf[384+jj], bhz = smallf[384+HID+jj], bhn = smallf[384+2*HID+jj];
        #pragma unroll
        for (int u = 0; u < NT; u++) {
            if (!valid[u]) continue;
            float r  = 1.f/(1.f + expf(-(gri[u]+bir + grh[u]+bhr)));
            float z  = 1.f/(1.f + expf(-(gzi[u]+biz + gzh[u]+bhz)));
            float nn = tanhf(gni[u]+bin + r*(gnh[u]+bhn));
            float hv = h[n[u]*HID + jj];
            hnew[n[u]*HID + jj] = (1.f - z)*nn + z*hv;
        }
    }
}

__global__ void commit_kernel(float* __restrict__ h, const float* __restrict__ hnew,
                              const int* __restrict__ order, const int* __restrict__ bstart, int t) {
    int K = bstart[t];
    int total = K * HID;
    int stride = gridDim.x * blockDim.x;
    for (int idx = blockIdx.x*blockDim.x + threadIdx.x; idx < total; idx += stride) {
        int li = idx / HID, f = idx % HID;
        int i = order[li];
        h[i*HID + f] = hnew[i*HID + f];
    }
}

// ---------------- out = h @ w_out + b_out (dtype per mode) ----------------
__global__ void out_kernel(const float* __restrict__ h, const float* __restrict__ w_out_f,
                           const float* __restrict__ smallf, void* out, const int* mode, int N) {
    int tid = blockIdx.x*blockDim.x + threadIdx.x;
    if (tid >= N*OUTDIM) return;
    int n = tid / OUTDIM, o = tid % OUTDIM;
    float acc = smallf[672+o];
    const float* hr = h + n*HID;
    #pragma unroll 8
    for (int k = 0; k < HID; k++) acc += hr[k] * w_out_f[k*OUTDIM + o];
    if (*mode) ((float*)out)[tid] = acc;
    else       ((__hip_bfloat16*)out)[tid] = __float2bfloat16(acc);
}

extern "C" void kernel_launch(void* const* d_in, const int* in_sizes, int n_in,
                              void* d_out, int out_size, void* d_ws, size_t ws_size,
                              hipStream_t stream) {
    const void* x      = d_in[0];
    const int*  ei     = (const int*)d_in[1];
    const void* w_in   = d_in[2],  *b_in   = d_in[3];
    const void* tau_w1 = d_in[4],  *tau_b1 = d_in[5];
    const void* tau_w2 = d_in[6],  *tau_b2 = d_in[7];
    const void* wih    = d_in[8],  *whh    = d_in[9];
    const void* bih    = d_in[10], *bhh    = d_in[11];
    const void* w_out  = d_in[12], *b_out  = d_in[13];

    int N = in_sizes[0] / INDIM;
    int E = in_sizes[1] / 2;
    const int* row = ei;
    const int* col = ei + E;

    char* ws = (char*)d_ws;
    size_t o = 0;
    auto take = [&](size_t bytes) -> char* {
        char* p = ws + o;
        o = (o + bytes + 255) & ~(size_t)255;
        return p;
    };
    float* x_f      = (float*)take((size_t)N*INDIM*4);
    float* h        = (float*)take((size_t)N*HID*4);
    float* agg      = (float*)take((size_t)N*HID*4);
    float* hnew     = (float*)take((size_t)N*HID*4);
    float* wihT     = (float*)take((size_t)THID*HID*4);
    float* whhT     = (float*)take((size_t)THID*HID*4);
    float* w_in_f   = (float*)take((size_t)INDIM*HID*4);
    float* w_out_f  = (float*)take((size_t)HID*OUTDIM*4);
    float* tau_w1_f = (float*)take((size_t)INDIM*16*4);
    float* smallf   = (float*)take(1024*4);
    int*   off      = (int*)take((size_t)(N+1)*4);
    int*   csr_col  = (int*)take((size_t)E*4);
    int*   order    = (int*)take((size_t)N*4);
    int*   steps    = (int*)take((size_t)N*4);
    int*   bstart   = (int*)take(64);
    int*   mode     = (int*)take(64);
    // zero region (memset each launch): deg, cur, cnt6, cur6
    char*  zbase    = ws + o;
    int*   deg      = (int*)take((size_t)N*4);
    int*   cur      = (int*)take((size_t)N*4);
    int*   cnt6     = (int*)take(64);
    int*   cur6     = (int*)take(64);
    size_t zbytes   = (size_t)((ws + o) - zbase);

    hipMemsetAsync(zbase, 0, zbytes, stream);
    sniff_kernel<<<1, 64, 0, stream>>>((const unsigned int*)x, mode);

    xconv_kernel<<<(N*INDIM + 255)/256, 256, 0, stream>>>(x, x_f, mode, N*INDIM);
    prep_kernel<<<(THID*HID + 255)/256, 256, 0, stream>>>(
        w_in, b_in, tau_w1, tau_b1, tau_w2, tau_b2, wih, whh, bih, bhh, w_out, b_out,
        wihT, whhT, w_in_f, w_out_f, tau_w1_f, smallf, mode);

    h0_kernel<<<(N*HID + 255)/256, 256, 0, stream>>>(x_f, w_in_f, smallf, h, N);
    tau_kernel<<<((size_t)N*64 + 255)/256, 256, 0, stream>>>(x_f, tau_w1_f, smallf, steps, cnt6, N);
    deg_kernel<<<(E + 255)/256, 256, 0, stream>>>(row, deg, E);
    scan_kernel<<<1, 1024, 0, stream>>>(deg, off, cnt6, bstart, N);
    fill_kernel<<<(E + 255)/256, 256, 0, stream>>>(row, col, off, cur, csr_col, E);
    order_kernel<<<(N + 255)/256, 256, 0, stream>>>(steps, bstart, cur6, order, N);

    for (int t = 0; t < 5; t++) {
        agg_kernel<<<4096, 256, 0, stream>>>(h, off, csr_col, order, bstart, t, agg);
        gru_kernel<<<2048, 256, 0, stream>>>(h, agg, wihT, whhT, smallf, order, bstart, t, hnew);
        commit_kernel<<<2048, 256, 0, stream>>>(h, hnew, order, bstart, t);
    }

    out_kernel<<<(N*OUTDIM + 255)/256, 256, 0, stream>>>(h, w_out_f, smallf, d_out, mode, N);
}

// Round 5
// 1400.083 us; speedup vs baseline: 1.5748x; 1.5748x over previous
//
#include <hip/hip_runtime.h>
#include <hip/hip_bf16.h>

#define HID 96
#define INDIM 128
#define OUTDIM 64
#define THID (3*HID)   // 288
#define NT 4

__device__ __forceinline__ float ldmix(const void* p, long i, int mode) {
    return mode ? ((const float*)p)[i]
                : __bfloat162float(((const __hip_bfloat16*)p)[i]);
}

// ---------------- dtype sniffer: fp32 data has uniform-random low 16 bits ----------------
__global__ void sniff_kernel(const unsigned int* xw, int* mode) {
    if (threadIdx.x == 0 && blockIdx.x == 0) {
        int cnt = 0;
        for (int i = 0; i < 4096; i++) {
            unsigned int low = xw[i] & 0xFFFFu;
            unsigned int e = (low >> 7) & 0xFFu;
            if (e >= 0xC0u) cnt++;
        }
        *mode = (cnt > 256) ? 1 : 0;  // 1 = fp32 inputs, 0 = bf16 inputs
    }
}

// ---------------- x -> fp32 ----------------
__global__ void xconv_kernel(const void* x, float* __restrict__ x_f, const int* mode, int total) {
    int m = *mode;
    int tid = blockIdx.x*blockDim.x + threadIdx.x;
    if (tid < total) x_f[tid] = ldmix(x, tid, m);
}

// ---------------- weight prep ----------------
// smallf layout: [0..95] b_in, [96..383] bih, [384..671] bhh, [672..735] b_out,
//                [736..751] tau_w2, [752..767] tau_b1, [768] tau_b2
__global__ void prep_kernel(const void* w_in, const void* b_in, const void* tau_w1,
                            const void* tau_b1, const void* tau_w2, const void* tau_b2,
                            const void* wih, const void* whh, const void* bih, const void* bhh,
                            const void* w_out, const void* b_out,
                            float* wihT, float* whhT, float* w_in_f, float* w_out_f,
                            float* tau_w1_f, float* smallf, const int* mode) {
    int m = *mode;
    int tid = blockIdx.x*blockDim.x + threadIdx.x;
    if (tid < THID*HID) {           // transpose [288,96] -> [96,288]
        int j = tid / HID, k = tid % HID;
        wihT[k*THID + j] = ldmix(wih, tid, m);
        whhT[k*THID + j] = ldmix(whh, tid, m);
    }
    if (tid < INDIM*HID)  w_in_f[tid]   = ldmix(w_in, tid, m);
    if (tid < HID*OUTDIM) w_out_f[tid]  = ldmix(w_out, tid, m);
    if (tid < INDIM*16)   tau_w1_f[tid] = ldmix(tau_w1, tid, m);
    if (tid < HID)    smallf[tid]       = ldmix(b_in, tid, m);
    if (tid < THID) { smallf[96+tid]    = ldmix(bih, tid, m);
                      smallf[384+tid]   = ldmix(bhh, tid, m); }
    if (tid < OUTDIM) smallf[672+tid]   = ldmix(b_out, tid, m);
    if (tid < 16)   { smallf[736+tid]   = ldmix(tau_w2, tid, m);
                      smallf[752+tid]   = ldmix(tau_b1, tid, m); }
    if (tid == 0)     smallf[768]       = ldmix(tau_b2, 0, m);
}

// ---------------- h0 = relu(x @ w_in + b_in) ----------------
__global__ void h0_kernel(const float* __restrict__ x_f, const float* __restrict__ w_in_f,
                          const float* __restrict__ smallf, float* __restrict__ h, int N) {
    int tid = blockIdx.x*blockDim.x + threadIdx.x;
    if (tid >= N*HID) return;
    int n = tid / HID, j = tid % HID;
    const float* xr = x_f + (size_t)n*INDIM;
    float acc = smallf[j];
    #pragma unroll 8
    for (int k = 0; k < INDIM; k++) acc += xr[k] * w_in_f[k*HID + j];
    h[tid] = fmaxf(acc, 0.f);
}

// ---------------- tau MLP -> steps (wave per node; no atomics) ----------------
__global__ void tau_kernel(const float* __restrict__ x_f, const float* __restrict__ tau_w1_f,
                           const float* __restrict__ smallf,
                           int* __restrict__ steps, int N) {
    int gtid = blockIdx.x*blockDim.x + threadIdx.x;
    int n = gtid >> 6;          // wave per node
    int lane = threadIdx.x & 63;
    if (n >= N) return;
    const float* xr = x_f + (size_t)n*INDIM;
    float x0 = xr[lane];        // coalesced 256B wave-load
    float x1 = xr[64 + lane];
    const float* w0 = tau_w1_f + lane*16;        // L1-resident (8 KB total)
    const float* w1 = tau_w1_f + (64 + lane)*16;
    float acc[16];
    #pragma unroll
    for (int j = 0; j < 16; j++) acc[j] = x0*w0[j] + x1*w1[j];
    #pragma unroll
    for (int ofs = 32; ofs > 0; ofs >>= 1) {
        #pragma unroll
        for (int j = 0; j < 16; j++) acc[j] += __shfl_down(acc[j], ofs);
    }
    if (lane == 0) {
        float z = smallf[768];
        #pragma unroll
        for (int j = 0; j < 16; j++) z += fmaxf(acc[j] + smallf[752+j], 0.f) * smallf[736+j];
        float tau = fmaxf(z, 0.f) + log1pf(expf(-fabsf(z)));   // stable softplus
        float inv = 1.0f / tau;
        int s;
        if (inv >= 5.0f) s = 5;
        else { s = (int)inv; if (s < 0) s = 0; if (s > 5) s = 5; }
        steps[n] = s;
    }
}

// ---------------- deterministic bucket sort by steps (single block, no atomics) ----------------
// order = nodes sorted by (steps descending, node index ascending); bstart[s] = start of bucket s,
// so the first bstart[t] entries are exactly the nodes with steps > t.
__global__ void bucket_kernel(const int* __restrict__ steps, int* __restrict__ bstart,
                              int* __restrict__ order, int N) {
    __shared__ int buf[1024];
    __shared__ int btot[6];
    __shared__ int sb[8];
    int tid = threadIdx.x;
    int C = (N + 1023) / 1024;
    int start = tid * C, end = min(start + C, N);
    // per-chunk bucket counts (registers)
    int cnt[6] = {0,0,0,0,0,0};
    for (int i = start; i < end; i++) cnt[steps[i]]++;
    // per-bucket exclusive scan across the 1024 chunks
    int myoff[6];
    #pragma unroll
    for (int s = 0; s < 6; s++) {
        buf[tid] = cnt[s];
        __syncthreads();
        for (int ofs = 1; ofs < 1024; ofs <<= 1) {
            int t = (tid >= ofs) ? buf[tid - ofs] : 0;
            __syncthreads();
            buf[tid] += t;
            __syncthreads();
        }
        myoff[s] = buf[tid] - cnt[s];
        if (tid == 1023) btot[s] = buf[tid];
        __syncthreads();
    }
    if (tid == 0) {
        int running = 0;
        for (int ss = 5; ss >= 0; --ss) { sb[ss] = running; bstart[ss] = running; running += btot[ss]; }
        bstart[6] = running;            // = N
    }
    __syncthreads();
    int pos[6];
    #pragma unroll
    for (int s = 0; s < 6; s++) pos[s] = sb[s] + myoff[s];
    for (int i = start; i < end; i++) {
        int s = steps[i];
        order[pos[s]++] = i;
    }
}

// ---------------- CSR build ----------------
__global__ void deg_kernel(const int* __restrict__ row, int* deg, int E) {
    int e = blockIdx.x*blockDim.x + threadIdx.x;
    if (e < E) atomicAdd(&deg[row[e]], 1);
}

// single-block scan: off = exclusive_scan(deg)
__global__ void scan_kernel(const int* __restrict__ deg, int* __restrict__ off, int N) {
    __shared__ int buf[1024];
    int tid = threadIdx.x;
    int C = (N + 1023) / 1024;
    int start = tid * C, end = min(start + C, N);
    if (end < start) end = start;
    int s = 0;
    for (int i = start; i < end; i++) s += deg[i];
    buf[tid] = s; __syncthreads();
    for (int ofs = 1; ofs < 1024; ofs <<= 1) {
        int t = (tid >= ofs) ? buf[tid - ofs] : 0;
        __syncthreads();
        buf[tid] += t;
        __syncthreads();
    }
    int incl = buf[tid];
    int run = incl - s;
    for (int i = start; i < end; i++) { off[i] = run; run += deg[i]; }
    if (tid == 1023) off[N] = incl;     // = E
}

__global__ void fill_kernel(const int* __restrict__ row, const int* __restrict__ col,
                            const int* __restrict__ off, int* cur, int* __restrict__ csr_col, int E) {
    int e = blockIdx.x*blockDim.x + threadIdx.x;
    if (e >= E) return;
    int r = row[e];
    int p = atomicAdd(&cur[r], 1);
    csr_col[off[r] + p] = col[e];
}

// ---------------- iteration kernels ----------------
__global__ void agg_kernel(const float* __restrict__ h, const int* __restrict__ off,
                           const int* __restrict__ csr_col, const int* __restrict__ order,
                           const int* __restrict__ bstart, int t, float* __restrict__ agg) {
    int K = bstart[t];
    int total = K * HID;
    int stride = gridDim.x * blockDim.x;
    for (int idx = blockIdx.x*blockDim.x + threadIdx.x; idx < total; idx += stride) {
        int li = idx / HID, f = idx % HID;
        int i = order[li];
        float hv = h[i*HID + f];
        int e0 = off[i], e1 = off[i+1];
        float acc = 0.f;
        for (int e = e0; e < e1; e++) {
            int c = csr_col[e];
            acc += fabsf(hv - h[c*HID + f]);
        }
        agg[i*HID + f] = acc;
    }
}

__global__ void gru_kernel(const float* __restrict__ h, const float* __restrict__ agg,
                           const float* __restrict__ wihT, const float* __restrict__ whhT,
                           const float* __restrict__ smallf, const int* __restrict__ order,
                           const int* __restrict__ bstart, int t, float* __restrict__ hnew) {
    int K = bstart[t];
    int tiles = (K + NT - 1) / NT;
    int total = tiles * HID;
    int stride = gridDim.x * blockDim.x;
    for (int idx = blockIdx.x*blockDim.x + threadIdx.x; idx < total; idx += stride) {
        int tile = idx / HID, jj = idx % HID;
        int n[NT]; bool valid[NT];
        #pragma unroll
        for (int u = 0; u < NT; u++) {
            int li = tile*NT + u;
            valid[u] = li < K;
            n[u] = order[valid[u] ? li : (K - 1)];   // clamp to an active node
        }
        float gri[NT], gzi[NT], gni[NT], grh[NT], gzh[NT], gnh[NT];
        #pragma unroll
        for (int u = 0; u < NT; u++) { gri[u]=gzi[u]=gni[u]=grh[u]=gzh[u]=gnh[u]=0.f; }
        for (int k = 0; k < HID; k++) {
            const float* wi = wihT + k*THID;
            const float* wh = whhT + k*THID;
            float wi0 = wi[jj], wi1 = wi[HID+jj], wi2 = wi[2*HID+jj];
            float wh0 = wh[jj], wh1 = wh[HID+jj], wh2 = wh[2*HID+jj];
            #pragma unroll
            for (int u = 0; u < NT; u++) {
                float a  = agg[n[u]*HID + k];
                float hv = h  [n[u]*HID + k];
                gri[u] += a*wi0;  gzi[u] += a*wi1;  gni[u] += a*wi2;
                grh[u] += hv*wh0; gzh[u] += hv*wh1; gnh[u] += hv*wh2;
            }
        }
        float bir = smallf[96+jj],  biz = smallf[96+HID+jj],  bin = smallf[96+2*HID+jj];
        float bhr = smallf[384+jj], bhz = smallf[384+HID+jj], bhn = smallf[384+2*HID+jj];
        #pragma unroll
        for (int u = 0; u < NT; u++) {
            if (!valid[u]) continue;
            float r  = 1.f/(1.f + expf(-(gri[u]+bir + grh[u]+bhr)));
            float z  = 1.f/(1.f + expf(-(gzi[u]+biz + gzh[u]+bhz)));
            float nn = tanhf(gni[u]+bin + r*(gnh[u]+bhn));
            float hv = h[n[u]*HID + jj];
            hnew[n[u]*HID + jj] = (1.f - z)*nn + z*hv;
        }
    }
}

__global__ void commit_kernel(float* __restrict__ h, const float* __restrict__ hnew,
                              const int* __restrict__ order, const int* __restrict__ bstart, int t) {
    int K = bstart[t];
    int total = K * HID;
    int stride = gridDim.x * blockDim.x;
    for (int idx = blockIdx.x*blockDim.x + threadIdx.x; idx < total; idx += stride) {
        int li = idx / HID, f = idx % HID;
        int i = order[li];
        h[i*HID + f] = hnew[i*HID + f];
    }
}

// ---------------- out = h @ w_out + b_out (dtype per mode) ----------------
__global__ void out_kernel(const float* __restrict__ h, const float* __restrict__ w_out_f,
                           const float* __restrict__ smallf, void* out, const int* mode, int N) {
    int tid = blockIdx.x*blockDim.x + threadIdx.x;
    if (tid >= N*OUTDIM) return;
    int n = tid / OUTDIM, o = tid % OUTDIM;
    float acc = smallf[672+o];
    const float* hr = h + n*HID;
    #pragma unroll 8
    for (int k = 0; k < HID; k++) acc += hr[k] * w_out_f[k*OUTDIM + o];
    if (*mode) ((float*)out)[tid] = acc;
    else       ((__hip_bfloat16*)out)[tid] = __float2bfloat16(acc);
}

extern "C" void kernel_launch(void* const* d_in, const int* in_sizes, int n_in,
                              void* d_out, int out_size, void* d_ws, size_t ws_size,
                              hipStream_t stream) {
    const void* x      = d_in[0];
    const int*  ei     = (const int*)d_in[1];
    const void* w_in   = d_in[2],  *b_in   = d_in[3];
    const void* tau_w1 = d_in[4],  *tau_b1 = d_in[5];
    const void* tau_w2 = d_in[6],  *tau_b2 = d_in[7];
    const void* wih    = d_in[8],  *whh    = d_in[9];
    const void* bih    = d_in[10], *bhh    = d_in[11];
    const void* w_out  = d_in[12], *b_out  = d_in[13];

    int N = in_sizes[0] / INDIM;
    int E = in_sizes[1] / 2;
    const int* row = ei;
    const int* col = ei + E;

    char* ws = (char*)d_ws;
    size_t o = 0;
    auto take = [&](size_t bytes) -> char* {
        char* p = ws + o;
        o = (o + bytes + 255) & ~(size_t)255;
        return p;
    };
    float* x_f      = (float*)take((size_t)N*INDIM*4);
    float* h        = (float*)take((size_t)N*HID*4);
    float* agg      = (float*)take((size_t)N*HID*4);
    float* hnew     = (float*)take((size_t)N*HID*4);
    float* wihT     = (float*)take((size_t)THID*HID*4);
    float* whhT     = (float*)take((size_t)THID*HID*4);
    float* w_in_f   = (float*)take((size_t)INDIM*HID*4);
    float* w_out_f  = (float*)take((size_t)HID*OUTDIM*4);
    float* tau_w1_f = (float*)take((size_t)INDIM*16*4);
    float* smallf   = (float*)take(1024*4);
    int*   off      = (int*)take((size_t)(N+1)*4);
    int*   csr_col  = (int*)take((size_t)E*4);
    int*   order    = (int*)take((size_t)N*4);
    int*   steps    = (int*)take((size_t)N*4);
    int*   bstart   = (int*)take(64);
    int*   mode     = (int*)take(64);
    // zero region (memset each launch): deg, cur
    char*  zbase    = ws + o;
    int*   deg      = (int*)take((size_t)N*4);
    int*   cur      = (int*)take((size_t)N*4);
    size_t zbytes   = (size_t)((ws + o) - zbase);

    hipMemsetAsync(zbase, 0, zbytes, stream);
    sniff_kernel<<<1, 64, 0, stream>>>((const unsigned int*)x, mode);

    xconv_kernel<<<(N*INDIM + 255)/256, 256, 0, stream>>>(x, x_f, mode, N*INDIM);
    prep_kernel<<<(THID*HID + 255)/256, 256, 0, stream>>>(
        w_in, b_in, tau_w1, tau_b1, tau_w2, tau_b2, wih, whh, bih, bhh, w_out, b_out,
        wihT, whhT, w_in_f, w_out_f, tau_w1_f, smallf, mode);

    h0_kernel<<<(N*HID + 255)/256, 256, 0, stream>>>(x_f, w_in_f, smallf, h, N);
    tau_kernel<<<((size_t)N*64 + 255)/256, 256, 0, stream>>>(x_f, tau_w1_f, smallf, steps, N);
    bucket_kernel<<<1, 1024, 0, stream>>>(steps, bstart, order, N);
    deg_kernel<<<(E + 255)/256, 256, 0, stream>>>(row, deg, E);
    scan_kernel<<<1, 1024, 0, stream>>>(deg, off, N);
    fill_kernel<<<(E + 255)/256, 256, 0, stream>>>(row, col, off, cur, csr_col, E);

    for (int t = 0; t < 5; t++) {
        agg_kernel<<<4096, 256, 0, stream>>>(h, off, csr_col, order, bstart, t, agg);
        gru_kernel<<<2048, 256, 0, stream>>>(h, agg, wihT, whhT, smallf, order, bstart, t, hnew);
        commit_kernel<<<2048, 256, 0, stream>>>(h, hnew, order, bstart, t);
    }

    out_kernel<<<(N*OUTDIM + 255)/256, 256, 0, stream>>>(h, w_out_f, smallf, d_out, mode, N);
}

// Round 7
// 1066.422 us; speedup vs baseline: 2.0676x; 1.3129x over previous
//
#include <hip/hip_runtime.h>
#include <hip/hip_bf16.h>

#define HID 96
#define INDIM 128
#define OUTDIM 64
#define BM 128

typedef __attribute__((ext_vector_type(8))) short short8;
typedef __attribute__((ext_vector_type(4))) float floatx4;
typedef unsigned short ushort_t;

__device__ __forceinline__ float ldmix(const void* p, long i, int mode) {
    return mode ? ((const float*)p)[i]
                : __bfloat162float(((const __hip_bfloat16*)p)[i]);
}

__device__ __forceinline__ void split_bf16(float v, __hip_bfloat16* hi, __hip_bfloat16* lo) {
    __hip_bfloat16 h = __float2bfloat16(v);
    *hi = h;
    *lo = __float2bfloat16(v - __bfloat162float(h));
}

// ---------------- dtype sniffer ----------------
__global__ void sniff_kernel(const unsigned int* xw, int* mode) {
    if (threadIdx.x == 0 && blockIdx.x == 0) {
        int cnt = 0;
        for (int i = 0; i < 4096; i++) {
            unsigned int low = xw[i] & 0xFFFFu;
            unsigned int e = (low >> 7) & 0xFFu;
            if (e >= 0xC0u) cnt++;
        }
        *mode = (cnt > 256) ? 1 : 0;  // 1 = fp32 inputs, 0 = bf16 inputs
    }
}

// ---------------- x -> fp32 ----------------
__global__ void xconv_kernel(const void* x, float* __restrict__ x_f, const int* mode, int total) {
    int m = *mode;
    int tid = blockIdx.x*blockDim.x + threadIdx.x;
    if (tid < total) x_f[tid] = ldmix(x, tid, m);
}

// ---------------- weight prep ----------------
// smallf: [0..95] b_in, [96..383] bih, [384..671] bhh, [672..735] b_out,
//         [736..751] tau_w2, [752..767] tau_b1, [768] tau_b2
// W2T hi/lo: [384 cols][192 k]. col c = g*96+jj, gates g: 0=r,1=z,2=inn,3=hn.
__global__ void prep_kernel(const void* w_in, const void* b_in, const void* tau_w1,
                            const void* tau_b1, const void* tau_w2, const void* tau_b2,
                            const void* wih, const void* whh, const void* bih, const void* bhh,
                            const void* w_out, const void* b_out,
                            __hip_bfloat16* W2T_hi, __hip_bfloat16* W2T_lo,
                            float* w_in_f, float* w_out_f,
                            float* tau_w1_f, float* smallf, const int* mode) {
    int m = *mode;
    int tid = blockIdx.x*blockDim.x + threadIdx.x;
    if (tid < 384*192) {
        int c = tid / 192, k = tid % 192;
        int g = c / 96, jj = c % 96;
        float v = 0.f;
        if (k < 96) {
            if (g == 0)      v = ldmix(wih, (long)(jj)*96 + k, m);
            else if (g == 1) v = ldmix(wih, (long)(96+jj)*96 + k, m);
            else if (g == 2) v = ldmix(wih, (long)(192+jj)*96 + k, m);
        } else {
            int kk = k - 96;
            if (g == 0)      v = ldmix(whh, (long)(jj)*96 + kk, m);
            else if (g == 1) v = ldmix(whh, (long)(96+jj)*96 + kk, m);
            else if (g == 3) v = ldmix(whh, (long)(192+jj)*96 + kk, m);
        }
        split_bf16(v, &W2T_hi[tid], &W2T_lo[tid]);
    }
    if (tid < INDIM*HID)  w_in_f[tid]   = ldmix(w_in, tid, m);
    if (tid < HID*OUTDIM) w_out_f[tid]  = ldmix(w_out, tid, m);
    if (tid < INDIM*16)   tau_w1_f[tid] = ldmix(tau_w1, tid, m);
    if (tid < HID)    smallf[tid]       = ldmix(b_in, tid, m);
    if (tid < 3*HID){ smallf[96+tid]    = ldmix(bih, tid, m);
                      smallf[384+tid]   = ldmix(bhh, tid, m); }
    if (tid < OUTDIM) smallf[672+tid]   = ldmix(b_out, tid, m);
    if (tid < 16)   { smallf[736+tid]   = ldmix(tau_w2, tid, m);
                      smallf[752+tid]   = ldmix(tau_b1, tid, m); }
    if (tid == 0)     smallf[768]       = ldmix(tau_b2, 0, m);
}

// ---------------- h0 = relu(x @ w_in + b_in) ----------------
__global__ void h0_kernel(const float* __restrict__ x_f, const float* __restrict__ w_in_f,
                          const float* __restrict__ smallf, float* __restrict__ h, int N) {
    int tid = blockIdx.x*blockDim.x + threadIdx.x;
    if (tid >= N*HID) return;
    int n = tid / HID, j = tid % HID;
    const float* xr = x_f + (size_t)n*INDIM;
    float acc = smallf[j];
    #pragma unroll 8
    for (int k = 0; k < INDIM; k++) acc += xr[k] * w_in_f[k*HID + j];
    h[tid] = fmaxf(acc, 0.f);
}

// ---------------- tau MLP -> steps (wave per node; no atomics) ----------------
__global__ void tau_kernel(const float* __restrict__ x_f, const float* __restrict__ tau_w1_f,
                           const float* __restrict__ smallf,
                           int* __restrict__ steps, int N) {
    int gtid = blockIdx.x*blockDim.x + threadIdx.x;
    int n = gtid >> 6;
    int lane = threadIdx.x & 63;
    if (n >= N) return;
    const float* xr = x_f + (size_t)n*INDIM;
    float x0 = xr[lane];
    float x1 = xr[64 + lane];
    const float* w0 = tau_w1_f + lane*16;
    const float* w1 = tau_w1_f + (64 + lane)*16;
    float acc[16];
    #pragma unroll
    for (int j = 0; j < 16; j++) acc[j] = x0*w0[j] + x1*w1[j];
    #pragma unroll
    for (int ofs = 32; ofs > 0; ofs >>= 1) {
        #pragma unroll
        for (int j = 0; j < 16; j++) acc[j] += __shfl_down(acc[j], ofs);
    }
    if (lane == 0) {
        float z = smallf[768];
        #pragma unroll
        for (int j = 0; j < 16; j++) z += fmaxf(acc[j] + smallf[752+j], 0.f) * smallf[736+j];
        float tau = fmaxf(z, 0.f) + log1pf(expf(-fabsf(z)));
        float inv = 1.0f / tau;
        int s;
        if (inv >= 5.0f) s = 5;
        else { s = (int)inv; if (s < 0) s = 0; if (s > 5) s = 5; }
        steps[n] = s;
    }
}

// ---------------- deterministic bucket sort by steps (single block) ----------------
__global__ void bucket_kernel(const int* __restrict__ steps, int* __restrict__ bstart,
                              int* __restrict__ order, int N) {
    __shared__ int buf[1024];
    __shared__ int btot[6];
    __shared__ int sb[8];
    int tid = threadIdx.x;
    int C = (N + 1023) / 1024;
    int start = tid * C, end = min(start + C, N);
    int cnt[6] = {0,0,0,0,0,0};
    for (int i = start; i < end; i++) cnt[steps[i]]++;
    int myoff[6];
    #pragma unroll
    for (int s = 0; s < 6; s++) {
        buf[tid] = cnt[s];
        __syncthreads();
        for (int ofs = 1; ofs < 1024; ofs <<= 1) {
            int t = (tid >= ofs) ? buf[tid - ofs] : 0;
            __syncthreads();
            buf[tid] += t;
            __syncthreads();
        }
        myoff[s] = buf[tid] - cnt[s];
        if (tid == 1023) btot[s] = buf[tid];
        __syncthreads();
    }
    if (tid == 0) {
        int running = 0;
        for (int ss = 5; ss >= 0; --ss) { sb[ss] = running; bstart[ss] = running; running += btot[ss]; }
        bstart[6] = running;
    }
    __syncthreads();
    int pos[6];
    #pragma unroll
    for (int s = 0; s < 6; s++) pos[s] = sb[s] + myoff[s];
    for (int i = start; i < end; i++) {
        int s = steps[i];
        order[pos[s]++] = i;
    }
}

// ---------------- pack h into order-space (bf16 hi/lo planes) ----------------
__global__ void pack_kernel(const float* __restrict__ h, const int* __restrict__ order,
                            __hip_bfloat16* __restrict__ hHi, __hip_bfloat16* __restrict__ hLo, int N) {
    int tid = blockIdx.x*blockDim.x + threadIdx.x;
    if (tid >= N*HID) return;
    int li = tid / HID, f = tid % HID;
    int n = order[li];
    float v = h[(size_t)n*HID + f];
    split_bf16(v, &hHi[tid], &hLo[tid]);
}

// ---------------- CSR build ----------------
__global__ void deg_kernel(const int* __restrict__ row, int* deg, int E) {
    int e = blockIdx.x*blockDim.x + threadIdx.x;
    if (e < E) atomicAdd(&deg[row[e]], 1);
}

__global__ void scan_kernel(const int* __restrict__ deg, int* __restrict__ off, int N) {
    __shared__ int buf[1024];
    int tid = threadIdx.x;
    int C = (N + 1023) / 1024;
    int start = tid * C, end = min(start + C, N);
    if (end < start) end = start;
    int s = 0;
    for (int i = start; i < end; i++) s += deg[i];
    buf[tid] = s; __syncthreads();
    for (int ofs = 1; ofs < 1024; ofs <<= 1) {
        int t = (tid >= ofs) ? buf[tid - ofs] : 0;
        __syncthreads();
        buf[tid] += t;
        __syncthreads();
    }
    int incl = buf[tid];
    int run = incl - s;
    for (int i = start; i < end; i++) { off[i] = run; run += deg[i]; }
    if (tid == 1023) off[N] = incl;
}

__global__ void fill_kernel(const int* __restrict__ row, const int* __restrict__ col,
                            const int* __restrict__ off, int* cur, int* __restrict__ csr_col, int E) {
    int e = blockIdx.x*blockDim.x + threadIdx.x;
    if (e >= E) return;
    int r = row[e];
    int p = atomicAdd(&cur[r], 1);
    csr_col[off[r] + p] = col[e];
}

// ---------------- aggregation -> packed bf16 hi/lo ----------------
__global__ void agg_kernel(const float* __restrict__ h, const int* __restrict__ off,
                           const int* __restrict__ csr_col, const int* __restrict__ order,
                           const int* __restrict__ bstart, int t,
                           __hip_bfloat16* __restrict__ aggHi, __hip_bfloat16* __restrict__ aggLo) {
    int K = bstart[t];
    int total = K * HID;
    int stride = gridDim.x * blockDim.x;
    for (int idx = blockIdx.x*blockDim.x + threadIdx.x; idx < total; idx += stride) {
        int li = idx / HID, f = idx % HID;
        int i = order[li];
        float hv = h[(size_t)i*HID + f];
        int e0 = off[i], e1 = off[i+1];
        float acc = 0.f;
        for (int e = e0; e < e1; e++) {
            int c = csr_col[e];
            acc += fabsf(hv - h[(size_t)c*HID + f]);
        }
        split_bf16(acc, &aggHi[idx], &aggLo[idx]);
    }
}

// ---------------- GRU via split-bf16 MFMA GEMM, fused epilogue ----------------
// A = [agg | h] (K x 192) as hi+lo planes; B = W2T^T (192 x 384) as hi+lo.
// acc = Ah*Bh + Al*Bh + Ah*Bl  (~fp32-accurate). 512 threads, 8 waves x 16 rows.
__global__ void __launch_bounds__(512) gru_kernel(
        const __hip_bfloat16* __restrict__ aggHi, const __hip_bfloat16* __restrict__ aggLo,
        const __hip_bfloat16* __restrict__ hHi,   const __hip_bfloat16* __restrict__ hLo,
        const __hip_bfloat16* __restrict__ WHi,   const __hip_bfloat16* __restrict__ WLo,
        const float* __restrict__ smallf, const int* __restrict__ bstart, int t,
        float* __restrict__ hnewP, int N) {
    int K = bstart[t];
    int row0 = blockIdx.x * BM;
    if (row0 >= K) return;
    int jj0 = blockIdx.y * 16;

    __shared__ ushort_t Ah[128*200];   // hi: [agg|h] 128 x (192+8)
    __shared__ ushort_t Al[128*200];   // lo
    __shared__ ushort_t Wh[64*200];    // hi: 64 cols x (192+8)
    __shared__ ushort_t Wl[64*200];

    int tid = threadIdx.x;
    const ushort_t* aH = (const ushort_t*)aggHi;
    const ushort_t* aL = (const ushort_t*)aggLo;
    const ushort_t* hH = (const ushort_t*)hHi;
    const ushort_t* hL = (const ushort_t*)hLo;
    const ushort_t* wH = (const ushort_t*)WHi;
    const ushort_t* wL = (const ushort_t*)WLo;
    long limit = (long)N * HID;
    #pragma unroll
    for (int j = 0; j < 3; j++) {
        int e = (tid + j*512) * 8;
        {
            int r = e / 96, c = e % 96;
            long ge = (long)(row0 + r)*96 + c;
            short8 vah = {0,0,0,0,0,0,0,0}, val = vah, vhh = vah, vhl = vah;
            if (ge + 8 <= limit) {
                vah = *(const short8*)(aH + ge);
                val = *(const short8*)(aL + ge);
                vhh = *(const short8*)(hH + ge);
                vhl = *(const short8*)(hL + ge);
            }
            *(short8*)(&Ah[r*200 + c])      = vah;
            *(short8*)(&Al[r*200 + c])      = val;
            *(short8*)(&Ah[r*200 + 96 + c]) = vhh;
            *(short8*)(&Al[r*200 + 96 + c]) = vhl;
        }
        {
            int wrow = e / 192, k = e % 192;
            int g = wrow >> 4, cc = wrow & 15;
            long wi = (long)(g*96 + jj0 + cc)*192 + k;
            *(short8*)(&Wh[wrow*200 + k]) = *(const short8*)(wH + wi);
            *(short8*)(&Wl[wrow*200 + k]) = *(const short8*)(wL + wi);
        }
    }
    __syncthreads();

    int lane = tid & 63;
    int w = tid >> 6;                  // 0..7, wave handles rows w*16..w*16+15
    int m15 = lane & 15, quad = lane >> 4;
    floatx4 acc[4];
    #pragma unroll
    for (int g = 0; g < 4; g++) acc[g] = (floatx4){0.f, 0.f, 0.f, 0.f};

    int abase = (w*16 + m15)*200 + quad*8;
    #pragma unroll
    for (int ks = 0; ks < 6; ks++) {
        int k0 = ks*32;
        short8 ah = *(const short8*)(&Ah[abase + k0]);
        short8 al = *(const short8*)(&Al[abase + k0]);
        #pragma unroll
        for (int g = 0; g < 4; g++) {
            int wb = (g*16 + m15)*200 + quad*8 + k0;
            short8 bh = *(const short8*)(&Wh[wb]);
            short8 bl = *(const short8*)(&Wl[wb]);
            acc[g] = __builtin_amdgcn_mfma_f32_16x16x32_bf16(ah, bh, acc[g], 0, 0, 0);
            acc[g] = __builtin_amdgcn_mfma_f32_16x16x32_bf16(al, bh, acc[g], 0, 0, 0);
            acc[g] = __builtin_amdgcn_mfma_f32_16x16x32_bf16(ah, bl, acc[g], 0, 0, 0);
        }
    }

    int jj = jj0 + m15;
    float bir = smallf[96+jj],  biz = smallf[192+jj], bin = smallf[288+jj];
    float bhr = smallf[384+jj], bhz = smallf[480+jj], bhn = smallf[576+jj];
    #pragma unroll
    for (int reg = 0; reg < 4; reg++) {
        int li = row0 + w*16 + quad*4 + reg;
        if (li < K) {
            float rp = acc[0][reg] + bir + bhr;
            float zp = acc[1][reg] + biz + bhz;
            float ip = acc[2][reg] + bin;
            float hn = acc[3][reg] + bhn;
            float r  = 1.f/(1.f + expf(-rp));
            float z  = 1.f/(1.f + expf(-zp));
            float nn = tanhf(ip + r*hn);
            long idx = (long)li*HID + jj;
            float hold = __bfloat162float(hHi[idx]) + __bfloat162float(hLo[idx]);
            hnewP[idx] = (1.f - z)*nn + z*hold;
        }
    }
}

// ---------------- commit: active prefix -> h (node layout) + hi/lo planes ----------------
__global__ void commit_kernel(float* __restrict__ h,
                              __hip_bfloat16* __restrict__ hHi, __hip_bfloat16* __restrict__ hLo,
                              const float* __restrict__ hnewP,
                              const int* __restrict__ order, const int* __restrict__ bstart, int t) {
    int K = bstart[t];
    int total = K * HID;
    int stride = gridDim.x * blockDim.x;
    for (int idx = blockIdx.x*blockDim.x + threadIdx.x; idx < total; idx += stride) {
        int li = idx / HID, f = idx % HID;
        int i = order[li];
        float v = hnewP[idx];
        h[(size_t)i*HID + f] = v;
        split_bf16(v, &hHi[idx], &hLo[idx]);
    }
}

// ---------------- out = h @ w_out + b_out (dtype per mode) ----------------
__global__ void out_kernel(const float* __restrict__ h, const float* __restrict__ w_out_f,
                           const float* __restrict__ smallf, void* out, const int* mode, int N) {
    int tid = blockIdx.x*blockDim.x + threadIdx.x;
    if (tid >= N*OUTDIM) return;
    int n = tid / OUTDIM, o = tid % OUTDIM;
    float acc = smallf[672+o];
    const float* hr = h + (size_t)n*HID;
    #pragma unroll 8
    for (int k = 0; k < HID; k++) acc += hr[k] * w_out_f[k*OUTDIM + o];
    if (*mode) ((float*)out)[tid] = acc;
    else       ((__hip_bfloat16*)out)[tid] = __float2bfloat16(acc);
}

extern "C" void kernel_launch(void* const* d_in, const int* in_sizes, int n_in,
                              void* d_out, int out_size, void* d_ws, size_t ws_size,
                              hipStream_t stream) {
    const void* x      = d_in[0];
    const int*  ei     = (const int*)d_in[1];
    const void* w_in   = d_in[2],  *b_in   = d_in[3];
    const void* tau_w1 = d_in[4],  *tau_b1 = d_in[5];
    const void* tau_w2 = d_in[6],  *tau_b2 = d_in[7];
    const void* wih    = d_in[8],  *whh    = d_in[9];
    const void* bih    = d_in[10], *bhh    = d_in[11];
    const void* w_out  = d_in[12], *b_out  = d_in[13];

    int N = in_sizes[0] / INDIM;
    int E = in_sizes[1] / 2;
    const int* row = ei;
    const int* col = ei + E;

    char* ws = (char*)d_ws;
    size_t o = 0;
    auto take = [&](size_t bytes) -> char* {
        char* p = ws + o;
        o = (o + bytes + 255) & ~(size_t)255;
        return p;
    };
    float* x_f      = (float*)take((size_t)N*INDIM*4);   // reused as hnewP after tau/h0
    float* hnewP    = x_f;
    float* h        = (float*)take((size_t)N*HID*4);
    __hip_bfloat16* hHi   = (__hip_bfloat16*)take((size_t)N*HID*2);
    __hip_bfloat16* hLo   = (__hip_bfloat16*)take((size_t)N*HID*2);
    __hip_bfloat16* aggHi = (__hip_bfloat16*)take((size_t)N*HID*2);
    __hip_bfloat16* aggLo = (__hip_bfloat16*)take((size_t)N*HID*2);
    __hip_bfloat16* W2T_hi= (__hip_bfloat16*)take((size_t)384*192*2);
    __hip_bfloat16* W2T_lo= (__hip_bfloat16*)take((size_t)384*192*2);
    float* w_in_f   = (float*)take((size_t)INDIM*HID*4);
    float* w_out_f  = (float*)take((size_t)HID*OUTDIM*4);
    float* tau_w1_f = (float*)take((size_t)INDIM*16*4);
    float* smallf   = (float*)take(1024*4);
    int*   off      = (int*)take((size_t)(N+1)*4);
    int*   csr_col  = (int*)take((size_t)E*4);
    int*   order    = (int*)take((size_t)N*4);
    int*   steps    = (int*)take((size_t)N*4);
    int*   bstart   = (int*)take(64);
    int*   mode     = (int*)take(64);
    char*  zbase    = ws + o;
    int*   deg      = (int*)take((size_t)N*4);
    int*   cur      = (int*)take((size_t)N*4);
    size_t zbytes   = (size_t)((ws + o) - zbase);

    hipMemsetAsync(zbase, 0, zbytes, stream);
    sniff_kernel<<<1, 64, 0, stream>>>((const unsigned int*)x, mode);

    xconv_kernel<<<(N*INDIM + 255)/256, 256, 0, stream>>>(x, x_f, mode, N*INDIM);
    prep_kernel<<<(384*192 + 255)/256, 256, 0, stream>>>(
        w_in, b_in, tau_w1, tau_b1, tau_w2, tau_b2, wih, whh, bih, bhh, w_out, b_out,
        W2T_hi, W2T_lo, w_in_f, w_out_f, tau_w1_f, smallf, mode);

    h0_kernel<<<(N*HID + 255)/256, 256, 0, stream>>>(x_f, w_in_f, smallf, h, N);
    tau_kernel<<<((size_t)N*64 + 255)/256, 256, 0, stream>>>(x_f, tau_w1_f, smallf, steps, N);
    bucket_kernel<<<1, 1024, 0, stream>>>(steps, bstart, order, N);
    pack_kernel<<<(N*HID + 255)/256, 256, 0, stream>>>(h, order, hHi, hLo, N);
    deg_kernel<<<(E + 255)/256, 256, 0, stream>>>(row, deg, E);
    scan_kernel<<<1, 1024, 0, stream>>>(deg, off, N);
    fill_kernel<<<(E + 255)/256, 256, 0, stream>>>(row, col, off, cur, csr_col, E);

    dim3 ggrid((N + BM - 1)/BM, 6);
    for (int t = 0; t < 5; t++) {
        agg_kernel<<<4096, 256, 0, stream>>>(h, off, csr_col, order, bstart, t, aggHi, aggLo);
        gru_kernel<<<ggrid, 512, 0, stream>>>(aggHi, aggLo, hHi, hLo, W2T_hi, W2T_lo,
                                              smallf, bstart, t, hnewP, N);
        commit_kernel<<<2048, 256, 0, stream>>>(h, hHi, hLo, hnewP, order, bstart, t);
    }

    out_kernel<<<(N*OUTDIM + 255)/256, 256, 0, stream>>>(h, w_out_f, smallf, d_out, mode, N);
}

// Round 8
// 990.822 us; speedup vs baseline: 2.2253x; 1.0763x over previous
//
#include <hip/hip_runtime.h>
#include <hip/hip_bf16.h>

#define HID 96
#define INDIM 128
#define OUTDIM 64
#define BM 128

typedef __attribute__((ext_vector_type(8))) short short8;
typedef __attribute__((ext_vector_type(4))) short short4_t;
typedef __attribute__((ext_vector_type(4))) float floatx4;
typedef unsigned short ushort_t;

__device__ __forceinline__ float ldmix(const void* p, long i, int mode) {
    return mode ? ((const float*)p)[i]
                : __bfloat162float(((const __hip_bfloat16*)p)[i]);
}

__device__ __forceinline__ void split_bf16(float v, __hip_bfloat16* hi, __hip_bfloat16* lo) {
    __hip_bfloat16 h = __float2bfloat16(v);
    *hi = h;
    *lo = __float2bfloat16(v - __bfloat162float(h));
}

__device__ __forceinline__ void split_us(float v, ushort_t* hi, ushort_t* lo) {
    __hip_bfloat16 h = __float2bfloat16(v);
    float hf = __bfloat162float(h);
    __hip_bfloat16 l = __float2bfloat16(v - hf);
    *hi = *(ushort_t*)&h;
    *lo = *(ushort_t*)&l;
}

// ---------------- dtype sniffer ----------------
__global__ void sniff_kernel(const unsigned int* xw, int* mode) {
    if (threadIdx.x == 0 && blockIdx.x == 0) {
        int cnt = 0;
        for (int i = 0; i < 4096; i++) {
            unsigned int low = xw[i] & 0xFFFFu;
            unsigned int e = (low >> 7) & 0xFFu;
            if (e >= 0xC0u) cnt++;
        }
        *mode = (cnt > 256) ? 1 : 0;  // 1 = fp32 inputs, 0 = bf16 inputs
    }
}

// ---------------- x -> fp32 ----------------
__global__ void xconv_kernel(const void* x, float* __restrict__ x_f, const int* mode, int total) {
    int m = *mode;
    int tid = blockIdx.x*blockDim.x + threadIdx.x;
    if (tid < total) x_f[tid] = ldmix(x, tid, m);
}

// ---------------- weight prep ----------------
// smallf: [0..95] b_in, [96..383] bih, [384..671] bhh, [672..735] b_out,
//         [736..751] tau_w2, [752..767] tau_b1, [768] tau_b2
// W2T hi/lo: [384 cols][192 k]. col c = g*96+jj, gates g: 0=r,1=z,2=inn,3=hn.
// WinT hi/lo: [96 cols][128 k], WinT[j][k] = w_in[k][j].
__global__ void prep_kernel(const void* w_in, const void* b_in, const void* tau_w1,
                            const void* tau_b1, const void* tau_w2, const void* tau_b2,
                            const void* wih, const void* whh, const void* bih, const void* bhh,
                            const void* w_out, const void* b_out,
                            __hip_bfloat16* W2T_hi, __hip_bfloat16* W2T_lo,
                            __hip_bfloat16* WinT_hi, __hip_bfloat16* WinT_lo,
                            float* w_out_f,
                            float* tau_w1_f, float* smallf, const int* mode) {
    int m = *mode;
    int tid = blockIdx.x*blockDim.x + threadIdx.x;
    if (tid < 384*192) {
        int c = tid / 192, k = tid % 192;
        int g = c / 96, jj = c % 96;
        float v = 0.f;
        if (k < 96) {
            if (g == 0)      v = ldmix(wih, (long)(jj)*96 + k, m);
            else if (g == 1) v = ldmix(wih, (long)(96+jj)*96 + k, m);
            else if (g == 2) v = ldmix(wih, (long)(192+jj)*96 + k, m);
        } else {
            int kk = k - 96;
            if (g == 0)      v = ldmix(whh, (long)(jj)*96 + kk, m);
            else if (g == 1) v = ldmix(whh, (long)(96+jj)*96 + kk, m);
            else if (g == 3) v = ldmix(whh, (long)(192+jj)*96 + kk, m);
        }
        split_bf16(v, &W2T_hi[tid], &W2T_lo[tid]);
    }
    if (tid < 96*128) {
        int j = tid >> 7, k = tid & 127;
        float v = ldmix(w_in, (long)k*96 + j, m);
        split_bf16(v, &WinT_hi[tid], &WinT_lo[tid]);
    }
    if (tid < HID*OUTDIM) w_out_f[tid]  = ldmix(w_out, tid, m);
    if (tid < INDIM*16)   tau_w1_f[tid] = ldmix(tau_w1, tid, m);
    if (tid < HID)    smallf[tid]       = ldmix(b_in, tid, m);
    if (tid < 3*HID){ smallf[96+tid]    = ldmix(bih, tid, m);
                      smallf[384+tid]   = ldmix(bhh, tid, m); }
    if (tid < OUTDIM) smallf[672+tid]   = ldmix(b_out, tid, m);
    if (tid < 16)   { smallf[736+tid]   = ldmix(tau_w2, tid, m);
                      smallf[752+tid]   = ldmix(tau_b1, tid, m); }
    if (tid == 0)     smallf[768]       = ldmix(tau_b2, 0, m);
}

// ---------------- h0 = relu(x @ w_in + b_in) via split-bf16 MFMA ----------------
// A = x (N x 128) split in-register from x_f during staging; B = WinT^T; 128 rows x 16-col stripe.
__global__ void __launch_bounds__(512) h0_kernel(
        const float* __restrict__ x_f,
        const __hip_bfloat16* __restrict__ WinT_hi, const __hip_bfloat16* __restrict__ WinT_lo,
        const float* __restrict__ smallf, float* __restrict__ h, int N) {
    int row0 = blockIdx.x * BM;
    int jj0 = blockIdx.y * 16;

    __shared__ ushort_t Ah[128*136];
    __shared__ ushort_t Al[128*136];
    __shared__ ushort_t Wh[16*136];
    __shared__ ushort_t Wl[16*136];

    int tid = threadIdx.x;
    long limit = (long)N * INDIM;
    #pragma unroll
    for (int j = 0; j < 8; j++) {
        int e = (tid + j*512) * 4;        // float index within tile, 16384 total
        int r = e >> 7, c = e & 127;
        long ge = (long)(row0 + r)*INDIM + c;
        floatx4 v = {0.f, 0.f, 0.f, 0.f};
        if (ge + 4 <= limit) v = *(const floatx4*)(x_f + ge);
        short4_t vh4, vl4;
        #pragma unroll
        for (int q = 0; q < 4; q++) {
            ushort_t hi, lo;
            split_us(v[q], &hi, &lo);
            vh4[q] = (short)hi; vl4[q] = (short)lo;
        }
        *(short4_t*)(&Ah[r*136 + c]) = vh4;
        *(short4_t*)(&Al[r*136 + c]) = vl4;
    }
    if (tid < 256) {
        int wrow = tid >> 4;
        int k = (tid & 15) * 8;
        long wi = (long)(jj0 + wrow)*INDIM + k;
        *(short8*)(&Wh[wrow*136 + k]) = *(const short8*)((const ushort_t*)WinT_hi + wi);
        *(short8*)(&Wl[wrow*136 + k]) = *(const short8*)((const ushort_t*)WinT_lo + wi);
    }
    __syncthreads();

    int lane = tid & 63;
    int w = tid >> 6;
    int m15 = lane & 15, quad = lane >> 4;
    floatx4 acc = {0.f, 0.f, 0.f, 0.f};
    int abase = (w*16 + m15)*136 + quad*8;
    #pragma unroll
    for (int ks = 0; ks < 4; ks++) {
        int k0 = ks*32;
        short8 ah = *(const short8*)(&Ah[abase + k0]);
        short8 al = *(const short8*)(&Al[abase + k0]);
        int wb = m15*136 + quad*8 + k0;
        short8 bh = *(const short8*)(&Wh[wb]);
        short8 bl = *(const short8*)(&Wl[wb]);
        acc = __builtin_amdgcn_mfma_f32_16x16x32_bf16(ah, bh, acc, 0, 0, 0);
        acc = __builtin_amdgcn_mfma_f32_16x16x32_bf16(al, bh, acc, 0, 0, 0);
        acc = __builtin_amdgcn_mfma_f32_16x16x32_bf16(ah, bl, acc, 0, 0, 0);
    }

    int jj = jj0 + m15;
    float b = smallf[jj];
    #pragma unroll
    for (int reg = 0; reg < 4; reg++) {
        int li = row0 + w*16 + quad*4 + reg;
        if (li < N) h[(long)li*HID + jj] = fmaxf(acc[reg] + b, 0.f);
    }
}

// ---------------- tau MLP -> steps (wave per node; no atomics) ----------------
__global__ void tau_kernel(const float* __restrict__ x_f, const float* __restrict__ tau_w1_f,
                           const float* __restrict__ smallf,
                           int* __restrict__ steps, int N) {
    int gtid = blockIdx.x*blockDim.x + threadIdx.x;
    int n = gtid >> 6;
    int lane = threadIdx.x & 63;
    if (n >= N) return;
    const float* xr = x_f + (size_t)n*INDIM;
    float x0 = xr[lane];
    float x1 = xr[64 + lane];
    const float* w0 = tau_w1_f + lane*16;
    const float* w1 = tau_w1_f + (64 + lane)*16;
    float acc[16];
    #pragma unroll
    for (int j = 0; j < 16; j++) acc[j] = x0*w0[j] + x1*w1[j];
    #pragma unroll
    for (int ofs = 32; ofs > 0; ofs >>= 1) {
        #pragma unroll
        for (int j = 0; j < 16; j++) acc[j] += __shfl_down(acc[j], ofs);
    }
    if (lane == 0) {
        float z = smallf[768];
        #pragma unroll
        for (int j = 0; j < 16; j++) z += fmaxf(acc[j] + smallf[752+j], 0.f) * smallf[736+j];
        float tau = fmaxf(z, 0.f) + log1pf(expf(-fabsf(z)));
        float inv = 1.0f / tau;
        int s;
        if (inv >= 5.0f) s = 5;
        else { s = (int)inv; if (s < 0) s = 0; if (s > 5) s = 5; }
        steps[n] = s;
    }
}

// ---------------- deterministic bucket sort by steps (single block) ----------------
__global__ void bucket_kernel(const int* __restrict__ steps, int* __restrict__ bstart,
                              int* __restrict__ order, int N) {
    __shared__ int buf[1024];
    __shared__ int btot[6];
    __shared__ int sb[8];
    int tid = threadIdx.x;
    int C = (N + 1023) / 1024;
    int start = tid * C, end = min(start + C, N);
    int cnt[6] = {0,0,0,0,0,0};
    for (int i = start; i < end; i++) cnt[steps[i]]++;
    int myoff[6];
    #pragma unroll
    for (int s = 0; s < 6; s++) {
        buf[tid] = cnt[s];
        __syncthreads();
        for (int ofs = 1; ofs < 1024; ofs <<= 1) {
            int t = (tid >= ofs) ? buf[tid - ofs] : 0;
            __syncthreads();
            buf[tid] += t;
            __syncthreads();
        }
        myoff[s] = buf[tid] - cnt[s];
        if (tid == 1023) btot[s] = buf[tid];
        __syncthreads();
    }
    if (tid == 0) {
        int running = 0;
        for (int ss = 5; ss >= 0; --ss) { sb[ss] = running; bstart[ss] = running; running += btot[ss]; }
        bstart[6] = running;
    }
    __syncthreads();
    int pos[6];
    #pragma unroll
    for (int s = 0; s < 6; s++) pos[s] = sb[s] + myoff[s];
    for (int i = start; i < end; i++) {
        int s = steps[i];
        order[pos[s]++] = i;
    }
}

// ---------------- pack h into order-space (bf16 hi/lo planes) ----------------
__global__ void pack_kernel(const float* __restrict__ h, const int* __restrict__ order,
                            __hip_bfloat16* __restrict__ hHi, __hip_bfloat16* __restrict__ hLo, int N) {
    int tid = blockIdx.x*blockDim.x + threadIdx.x;
    if (tid >= N*HID) return;
    int li = tid / HID, f = tid % HID;
    int n = order[li];
    float v = h[(size_t)n*HID + f];
    split_bf16(v, &hHi[tid], &hLo[tid]);
}

// ---------------- CSR build ----------------
__global__ void deg_kernel(const int* __restrict__ row, int* deg, int E) {
    int e = blockIdx.x*blockDim.x + threadIdx.x;
    if (e < E) atomicAdd(&deg[row[e]], 1);
}

__global__ void scan_kernel(const int* __restrict__ deg, int* __restrict__ off, int N) {
    __shared__ int buf[1024];
    int tid = threadIdx.x;
    int C = (N + 1023) / 1024;
    int start = tid * C, end = min(start + C, N);
    if (end < start) end = start;
    int s = 0;
    for (int i = start; i < end; i++) s += deg[i];
    buf[tid] = s; __syncthreads();
    for (int ofs = 1; ofs < 1024; ofs <<= 1) {
        int t = (tid >= ofs) ? buf[tid - ofs] : 0;
        __syncthreads();
        buf[tid] += t;
        __syncthreads();
    }
    int incl = buf[tid];
    int run = incl - s;
    for (int i = start; i < end; i++) { off[i] = run; run += deg[i]; }
    if (tid == 1023) off[N] = incl;
}

__global__ void fill_kernel(const int* __restrict__ row, const int* __restrict__ col,
                            const int* __restrict__ off, int* cur, int* __restrict__ csr_col, int E) {
    int e = blockIdx.x*blockDim.x + threadIdx.x;
    if (e >= E) return;
    int r = row[e];
    int p = atomicAdd(&cur[r], 1);
    csr_col[off[r] + p] = col[e];
}

// ---------------- aggregation -> packed bf16 hi/lo ----------------
__global__ void agg_kernel(const float* __restrict__ h, const int* __restrict__ off,
                           const int* __restrict__ csr_col, const int* __restrict__ order,
                           const int* __restrict__ bstart, int t,
                           __hip_bfloat16* __restrict__ aggHi, __hip_bfloat16* __restrict__ aggLo) {
    int K = bstart[t];
    int total = K * HID;
    int stride = gridDim.x * blockDim.x;
    for (int idx = blockIdx.x*blockDim.x + threadIdx.x; idx < total; idx += stride) {
        int li = idx / HID, f = idx % HID;
        int i = order[li];
        float hv = h[(size_t)i*HID + f];
        int e0 = off[i], e1 = off[i+1];
        float acc = 0.f;
        for (int e = e0; e < e1; e++) {
            int c = csr_col[e];
            acc += fabsf(hv - h[(size_t)c*HID + f]);
        }
        split_bf16(acc, &aggHi[idx], &aggLo[idx]);
    }
}

// ---------------- GRU via split-bf16 MFMA GEMM, fused epilogue ----------------
__global__ void __launch_bounds__(512) gru_kernel(
        const __hip_bfloat16* __restrict__ aggHi, const __hip_bfloat16* __restrict__ aggLo,
        const __hip_bfloat16* __restrict__ hHi,   const __hip_bfloat16* __restrict__ hLo,
        const __hip_bfloat16* __restrict__ WHi,   const __hip_bfloat16* __restrict__ WLo,
        const float* __restrict__ smallf, const int* __restrict__ bstart, int t,
        float* __restrict__ hnewP, int N) {
    int K = bstart[t];
    int row0 = blockIdx.x * BM;
    if (row0 >= K) return;
    int jj0 = blockIdx.y * 16;

    __shared__ ushort_t Ah[128*200];
    __shared__ ushort_t Al[128*200];
    __shared__ ushort_t Wh[64*200];
    __shared__ ushort_t Wl[64*200];

    int tid = threadIdx.x;
    const ushort_t* aH = (const ushort_t*)aggHi;
    const ushort_t* aL = (const ushort_t*)aggLo;
    const ushort_t* hH = (const ushort_t*)hHi;
    const ushort_t* hL = (const ushort_t*)hLo;
    const ushort_t* wH = (const ushort_t*)WHi;
    const ushort_t* wL = (const ushort_t*)WLo;
    long limit = (long)N * HID;
    #pragma unroll
    for (int j = 0; j < 3; j++) {
        int e = (tid + j*512) * 8;
        {
            int r = e / 96, c = e % 96;
            long ge = (long)(row0 + r)*96 + c;
            short8 vah = {0,0,0,0,0,0,0,0}, val = vah, vhh = vah, vhl = vah;
            if (ge + 8 <= limit) {
                vah = *(const short8*)(aH + ge);
                val = *(const short8*)(aL + ge);
                vhh = *(const short8*)(hH + ge);
                vhl = *(const short8*)(hL + ge);
            }
            *(short8*)(&Ah[r*200 + c])      = vah;
            *(short8*)(&Al[r*200 + c])      = val;
            *(short8*)(&Ah[r*200 + 96 + c]) = vhh;
            *(short8*)(&Al[r*200 + 96 + c]) = vhl;
        }
        {
            int wrow = e / 192, k = e % 192;
            int g = wrow >> 4, cc = wrow & 15;
            long wi = (long)(g*96 + jj0 + cc)*192 + k;
            *(short8*)(&Wh[wrow*200 + k]) = *(const short8*)(wH + wi);
            *(short8*)(&Wl[wrow*200 + k]) = *(const short8*)(wL + wi);
        }
    }
    __syncthreads();

    int lane = tid & 63;
    int w = tid >> 6;
    int m15 = lane & 15, quad = lane >> 4;
    floatx4 acc[4];
    #pragma unroll
    for (int g = 0; g < 4; g++) acc[g] = (floatx4){0.f, 0.f, 0.f, 0.f};

    int abase = (w*16 + m15)*200 + quad*8;
    #pragma unroll
    for (int ks = 0; ks < 6; ks++) {
        int k0 = ks*32;
        short8 ah = *(const short8*)(&Ah[abase + k0]);
        short8 al = *(const short8*)(&Al[abase + k0]);
        #pragma unroll
        for (int g = 0; g < 4; g++) {
            int wb = (g*16 + m15)*200 + quad*8 + k0;
            short8 bh = *(const short8*)(&Wh[wb]);
            short8 bl = *(const short8*)(&Wl[wb]);
            acc[g] = __builtin_amdgcn_mfma_f32_16x16x32_bf16(ah, bh, acc[g], 0, 0, 0);
            acc[g] = __builtin_amdgcn_mfma_f32_16x16x32_bf16(al, bh, acc[g], 0, 0, 0);
            acc[g] = __builtin_amdgcn_mfma_f32_16x16x32_bf16(ah, bl, acc[g], 0, 0, 0);
        }
    }

    int jj = jj0 + m15;
    float bir = smallf[96+jj],  biz = smallf[192+jj], bin = smallf[288+jj];
    float bhr = smallf[384+jj], bhz = smallf[480+jj], bhn = smallf[576+jj];
    #pragma unroll
    for (int reg = 0; reg < 4; reg++) {
        int li = row0 + w*16 + quad*4 + reg;
        if (li < K) {
            float rp = acc[0][reg] + bir + bhr;
            float zp = acc[1][reg] + biz + bhz;
            float ip = acc[2][reg] + bin;
            float hn = acc[3][reg] + bhn;
            float r  = 1.f/(1.f + expf(-rp));
            float z  = 1.f/(1.f + expf(-zp));
            float nn = tanhf(ip + r*hn);
            long idx = (long)li*HID + jj;
            float hold = __bfloat162float(hHi[idx]) + __bfloat162float(hLo[idx]);
            hnewP[idx] = (1.f - z)*nn + z*hold;
        }
    }
}

// ---------------- commit: active prefix -> h (node layout) + hi/lo planes ----------------
__global__ void commit_kernel(float* __restrict__ h,
                              __hip_bfloat16* __restrict__ hHi, __hip_bfloat16* __restrict__ hLo,
                              const float* __restrict__ hnewP,
                              const int* __restrict__ order, const int* __restrict__ bstart, int t) {
    int K = bstart[t];
    int total = K * HID;
    int stride = gridDim.x * blockDim.x;
    for (int idx = blockIdx.x*blockDim.x + threadIdx.x; idx < total; idx += stride) {
        int li = idx / HID, f = idx % HID;
        int i = order[li];
        float v = hnewP[idx];
        h[(size_t)i*HID + f] = v;
        split_bf16(v, &hHi[idx], &hLo[idx]);
    }
}

// ---------------- out = h @ w_out + b_out (dtype per mode) ----------------
__global__ void out_kernel(const float* __restrict__ h, const float* __restrict__ w_out_f,
                           const float* __restrict__ smallf, void* out, const int* mode, int N) {
    int tid = blockIdx.x*blockDim.x + threadIdx.x;
    if (tid >= N*OUTDIM) return;
    int n = tid / OUTDIM, o = tid % OUTDIM;
    float acc = smallf[672+o];
    const float* hr = h + (size_t)n*HID;
    #pragma unroll 8
    for (int k = 0; k < HID; k++) acc += hr[k] * w_out_f[k*OUTDIM + o];
    if (*mode) ((float*)out)[tid] = acc;
    else       ((__hip_bfloat16*)out)[tid] = __float2bfloat16(acc);
}

extern "C" void kernel_launch(void* const* d_in, const int* in_sizes, int n_in,
                              void* d_out, int out_size, void* d_ws, size_t ws_size,
                              hipStream_t stream) {
    const void* x      = d_in[0];
    const int*  ei     = (const int*)d_in[1];
    const void* w_in   = d_in[2],  *b_in   = d_in[3];
    const void* tau_w1 = d_in[4],  *tau_b1 = d_in[5];
    const void* tau_w2 = d_in[6],  *tau_b2 = d_in[7];
    const void* wih    = d_in[8],  *whh    = d_in[9];
    const void* bih    = d_in[10], *bhh    = d_in[11];
    const void* w_out  = d_in[12], *b_out  = d_in[13];

    int N = in_sizes[0] / INDIM;
    int E = in_sizes[1] / 2;
    const int* row = ei;
    const int* col = ei + E;

    char* ws = (char*)d_ws;
    size_t o = 0;
    auto take = [&](size_t bytes) -> char* {
        char* p = ws + o;
        o = (o + bytes + 255) & ~(size_t)255;
        return p;
    };
    float* x_f      = (float*)take((size_t)N*INDIM*4);   // reused as hnewP after h0/tau
    float* hnewP    = x_f;
    float* h        = (float*)take((size_t)N*HID*4);
    __hip_bfloat16* hHi   = (__hip_bfloat16*)take((size_t)N*HID*2);
    __hip_bfloat16* hLo   = (__hip_bfloat16*)take((size_t)N*HID*2);
    __hip_bfloat16* aggHi = (__hip_bfloat16*)take((size_t)N*HID*2);
    __hip_bfloat16* aggLo = (__hip_bfloat16*)take((size_t)N*HID*2);
    __hip_bfloat16* W2T_hi= (__hip_bfloat16*)take((size_t)384*192*2);
    __hip_bfloat16* W2T_lo= (__hip_bfloat16*)take((size_t)384*192*2);
    __hip_bfloat16* WinT_hi=(__hip_bfloat16*)take((size_t)96*128*2);
    __hip_bfloat16* WinT_lo=(__hip_bfloat16*)take((size_t)96*128*2);
    float* w_out_f  = (float*)take((size_t)HID*OUTDIM*4);
    float* tau_w1_f = (float*)take((size_t)INDIM*16*4);
    float* smallf   = (float*)take(1024*4);
    int*   off      = (int*)take((size_t)(N+1)*4);
    int*   csr_col  = (int*)take((size_t)E*4);
    int*   order    = (int*)take((size_t)N*4);
    int*   steps    = (int*)take((size_t)N*4);
    int*   bstart   = (int*)take(64);
    int*   mode     = (int*)take(64);
    char*  zbase    = ws + o;
    int*   deg      = (int*)take((size_t)N*4);
    int*   cur      = (int*)take((size_t)N*4);
    size_t zbytes   = (size_t)((ws + o) - zbase);

    hipMemsetAsync(zbase, 0, zbytes, stream);
    sniff_kernel<<<1, 64, 0, stream>>>((const unsigned int*)x, mode);

    xconv_kernel<<<(N*INDIM + 255)/256, 256, 0, stream>>>(x, x_f, mode, N*INDIM);
    prep_kernel<<<(384*192 + 255)/256, 256, 0, stream>>>(
        w_in, b_in, tau_w1, tau_b1, tau_w2, tau_b2, wih, whh, bih, bhh, w_out, b_out,
        W2T_hi, W2T_lo, WinT_hi, WinT_lo, w_out_f, tau_w1_f, smallf, mode);

    dim3 hgrid((N + BM - 1)/BM, 6);
    h0_kernel<<<hgrid, 512, 0, stream>>>(x_f, WinT_hi, WinT_lo, smallf, h, N);
    tau_kernel<<<((size_t)N*64 + 255)/256, 256, 0, stream>>>(x_f, tau_w1_f, smallf, steps, N);
    bucket_kernel<<<1, 1024, 0, stream>>>(steps, bstart, order, N);
    pack_kernel<<<(N*HID + 255)/256, 256, 0, stream>>>(h, order, hHi, hLo, N);
    deg_kernel<<<(E + 255)/256, 256, 0, stream>>>(row, deg, E);
    scan_kernel<<<1, 1024, 0, stream>>>(deg, off, N);
    fill_kernel<<<(E + 255)/256, 256, 0, stream>>>(row, col, off, cur, csr_col, E);

    dim3 ggrid((N + BM - 1)/BM, 6);
    for (int t = 0; t < 5; t++) {
        agg_kernel<<<4096, 256, 0, stream>>>(h, off, csr_col, order, bstart, t, aggHi, aggLo);
        gru_kernel<<<ggrid, 512, 0, stream>>>(aggHi, aggLo, hHi, hLo, W2T_hi, W2T_lo,
                                              smallf, bstart, t, hnewP, N);
        commit_kernel<<<2048, 256, 0, stream>>>(h, hHi, hLo, hnewP, order, bstart, t);
    }

    out_kernel<<<(N*OUTDIM + 255)/256, 256, 0, stream>>>(h, w_out_f, smallf, d_out, mode, N);
}

// Round 9
// 759.654 us; speedup vs baseline: 2.9025x; 1.3043x over previous
//
#include <hip/hip_runtime.h>
#include <hip/hip_bf16.h>

#define HID 96
#define INDIM 128
#define OUTDIM 64
#define BM 128

typedef __attribute__((ext_vector_type(8))) short short8;
typedef __attribute__((ext_vector_type(4))) short short4_t;
typedef __attribute__((ext_vector_type(4))) float floatx4;
typedef unsigned short ushort_t;

__device__ __forceinline__ float ldmix(const void* p, long i, int mode) {
    return mode ? ((const float*)p)[i]
                : __bfloat162float(((const __hip_bfloat16*)p)[i]);
}

__device__ __forceinline__ void split_bf16(float v, __hip_bfloat16* hi, __hip_bfloat16* lo) {
    __hip_bfloat16 h = __float2bfloat16(v);
    *hi = h;
    *lo = __float2bfloat16(v - __bfloat162float(h));
}

__device__ __forceinline__ void split_us(float v, ushort_t* hi, ushort_t* lo) {
    __hip_bfloat16 h = __float2bfloat16(v);
    float hf = __bfloat162float(h);
    __hip_bfloat16 l = __float2bfloat16(v - hf);
    *hi = *(ushort_t*)&h;
    *lo = *(ushort_t*)&l;
}

// ---------------- dtype sniffer (parallel: 64 lanes x 64 words) ----------------
__global__ void sniff_kernel(const unsigned int* xw, int* mode) {
    int lane = threadIdx.x & 63;
    int cnt = 0;
    for (int i = lane; i < 4096; i += 64) {
        unsigned int low = xw[i] & 0xFFFFu;
        unsigned int e = (low >> 7) & 0xFFu;
        if (e >= 0xC0u) cnt++;
    }
    #pragma unroll
    for (int ofs = 32; ofs > 0; ofs >>= 1) cnt += __shfl_down(cnt, ofs);
    if (lane == 0) *mode = (cnt > 256) ? 1 : 0;  // 1 = fp32 inputs, 0 = bf16 inputs
}

// ---------------- x -> fp32 ----------------
__global__ void xconv_kernel(const void* x, float* __restrict__ x_f, const int* mode, int total) {
    int m = *mode;
    int tid = blockIdx.x*blockDim.x + threadIdx.x;
    if (tid < total) x_f[tid] = ldmix(x, tid, m);
}

// ---------------- weight prep ----------------
// smallf: [0..95] b_in, [96..383] bih, [384..671] bhh, [672..735] b_out,
//         [736..751] tau_w2, [752..767] tau_b1, [768] tau_b2
// W2T hi/lo: [384 cols][192 k]. col c = g*96+jj, gates g: 0=r,1=z,2=inn,3=hn.
// WinT hi/lo: [96 cols][128 k], WinT[j][k] = w_in[k][j].
__global__ void prep_kernel(const void* w_in, const void* b_in, const void* tau_w1,
                            const void* tau_b1, const void* tau_w2, const void* tau_b2,
                            const void* wih, const void* whh, const void* bih, const void* bhh,
                            const void* w_out, const void* b_out,
                            __hip_bfloat16* W2T_hi, __hip_bfloat16* W2T_lo,
                            __hip_bfloat16* WinT_hi, __hip_bfloat16* WinT_lo,
                            float* w_out_f,
                            float* tau_w1_f, float* smallf, const int* mode) {
    int m = *mode;
    int tid = blockIdx.x*blockDim.x + threadIdx.x;
    if (tid < 384*192) {
        int c = tid / 192, k = tid % 192;
        int g = c / 96, jj = c % 96;
        float v = 0.f;
        if (k < 96) {
            if (g == 0)      v = ldmix(wih, (long)(jj)*96 + k, m);
            else if (g == 1) v = ldmix(wih, (long)(96+jj)*96 + k, m);
            else if (g == 2) v = ldmix(wih, (long)(192+jj)*96 + k, m);
        } else {
            int kk = k - 96;
            if (g == 0)      v = ldmix(whh, (long)(jj)*96 + kk, m);
            else if (g == 1) v = ldmix(whh, (long)(96+jj)*96 + kk, m);
            else if (g == 3) v = ldmix(whh, (long)(192+jj)*96 + kk, m);
        }
        split_bf16(v, &W2T_hi[tid], &W2T_lo[tid]);
    }
    if (tid < 96*128) {
        int j = tid >> 7, k = tid & 127;
        float v = ldmix(w_in, (long)k*96 + j, m);
        split_bf16(v, &WinT_hi[tid], &WinT_lo[tid]);
    }
    if (tid < HID*OUTDIM) w_out_f[tid]  = ldmix(w_out, tid, m);
    if (tid < INDIM*16)   tau_w1_f[tid] = ldmix(tau_w1, tid, m);
    if (tid < HID)    smallf[tid]       = ldmix(b_in, tid, m);
    if (tid < 3*HID){ smallf[96+tid]    = ldmix(bih, tid, m);
                      smallf[384+tid]   = ldmix(bhh, tid, m); }
    if (tid < OUTDIM) smallf[672+tid]   = ldmix(b_out, tid, m);
    if (tid < 16)   { smallf[736+tid]   = ldmix(tau_w2, tid, m);
                      smallf[752+tid]   = ldmix(tau_b1, tid, m); }
    if (tid == 0)     smallf[768]       = ldmix(tau_b2, 0, m);
}

// ---------------- h0 = relu(x @ w_in + b_in) via split-bf16 MFMA ----------------
__global__ void __launch_bounds__(512) h0_kernel(
        const float* __restrict__ x_f,
        const __hip_bfloat16* __restrict__ WinT_hi, const __hip_bfloat16* __restrict__ WinT_lo,
        const float* __restrict__ smallf, float* __restrict__ h, int N) {
    int row0 = blockIdx.x * BM;
    int jj0 = blockIdx.y * 16;

    __shared__ ushort_t Ah[128*136];
    __shared__ ushort_t Al[128*136];
    __shared__ ushort_t Wh[16*136];
    __shared__ ushort_t Wl[16*136];

    int tid = threadIdx.x;
    long limit = (long)N * INDIM;
    #pragma unroll
    for (int j = 0; j < 8; j++) {
        int e = (tid + j*512) * 4;
        int r = e >> 7, c = e & 127;
        long ge = (long)(row0 + r)*INDIM + c;
        floatx4 v = {0.f, 0.f, 0.f, 0.f};
        if (ge + 4 <= limit) v = *(const floatx4*)(x_f + ge);
        short4_t vh4, vl4;
        #pragma unroll
        for (int q = 0; q < 4; q++) {
            ushort_t hi, lo;
            split_us(v[q], &hi, &lo);
            vh4[q] = (short)hi; vl4[q] = (short)lo;
        }
        *(short4_t*)(&Ah[r*136 + c]) = vh4;
        *(short4_t*)(&Al[r*136 + c]) = vl4;
    }
    if (tid < 256) {
        int wrow = tid >> 4;
        int k = (tid & 15) * 8;
        long wi = (long)(jj0 + wrow)*INDIM + k;
        *(short8*)(&Wh[wrow*136 + k]) = *(const short8*)((const ushort_t*)WinT_hi + wi);
        *(short8*)(&Wl[wrow*136 + k]) = *(const short8*)((const ushort_t*)WinT_lo + wi);
    }
    __syncthreads();

    int lane = tid & 63;
    int w = tid >> 6;
    int m15 = lane & 15, quad = lane >> 4;
    floatx4 acc = {0.f, 0.f, 0.f, 0.f};
    int abase = (w*16 + m15)*136 + quad*8;
    #pragma unroll
    for (int ks = 0; ks < 4; ks++) {
        int k0 = ks*32;
        short8 ah = *(const short8*)(&Ah[abase + k0]);
        short8 al = *(const short8*)(&Al[abase + k0]);
        int wb = m15*136 + quad*8 + k0;
        short8 bh = *(const short8*)(&Wh[wb]);
        short8 bl = *(const short8*)(&Wl[wb]);
        acc = __builtin_amdgcn_mfma_f32_16x16x32_bf16(ah, bh, acc, 0, 0, 0);
        acc = __builtin_amdgcn_mfma_f32_16x16x32_bf16(al, bh, acc, 0, 0, 0);
        acc = __builtin_amdgcn_mfma_f32_16x16x32_bf16(ah, bl, acc, 0, 0, 0);
    }

    int jj = jj0 + m15;
    float b = smallf[jj];
    #pragma unroll
    for (int reg = 0; reg < 4; reg++) {
        int li = row0 + w*16 + quad*4 + reg;
        if (li < N) h[(long)li*HID + jj] = fmaxf(acc[reg] + b, 0.f);
    }
}

// ---------------- tau MLP -> steps (wave per node; no atomics) ----------------
__global__ void tau_kernel(const float* __restrict__ x_f, const float* __restrict__ tau_w1_f,
                           const float* __restrict__ smallf,
                           int* __restrict__ steps, int N) {
    int gtid = blockIdx.x*blockDim.x + threadIdx.x;
    int n = gtid >> 6;
    int lane = threadIdx.x & 63;
    if (n >= N) return;
    const float* xr = x_f + (size_t)n*INDIM;
    float x0 = xr[lane];
    float x1 = xr[64 + lane];
    const float* w0 = tau_w1_f + lane*16;
    const float* w1 = tau_w1_f + (64 + lane)*16;
    float acc[16];
    #pragma unroll
    for (int j = 0; j < 16; j++) acc[j] = x0*w0[j] + x1*w1[j];
    #pragma unroll
    for (int ofs = 32; ofs > 0; ofs >>= 1) {
        #pragma unroll
        for (int j = 0; j < 16; j++) acc[j] += __shfl_down(acc[j], ofs);
    }
    if (lane == 0) {
        float z = smallf[768];
        #pragma unroll
        for (int j = 0; j < 16; j++) z += fmaxf(acc[j] + smallf[752+j], 0.f) * smallf[736+j];
        float tau = fmaxf(z, 0.f) + log1pf(expf(-fabsf(z)));
        float inv = 1.0f / tau;
        int s;
        if (inv >= 5.0f) s = 5;
        else { s = (int)inv; if (s < 0) s = 0; if (s > 5) s = 5; }
        steps[n] = s;
    }
}

// ---------------- deterministic bucket sort by steps (single block) ----------------
__global__ void bucket_kernel(const int* __restrict__ steps, int* __restrict__ bstart,
                              int* __restrict__ order, int N) {
    __shared__ int buf[1024];
    __shared__ int btot[6];
    __shared__ int sb[8];
    int tid = threadIdx.x;
    int C = (N + 1023) / 1024;
    int start = tid * C, end = min(start + C, N);
    int cnt[6] = {0,0,0,0,0,0};
    for (int i = start; i < end; i++) cnt[steps[i]]++;
    int myoff[6];
    #pragma unroll
    for (int s = 0; s < 6; s++) {
        buf[tid] = cnt[s];
        __syncthreads();
        for (int ofs = 1; ofs < 1024; ofs <<= 1) {
            int t = (tid >= ofs) ? buf[tid - ofs] : 0;
            __syncthreads();
            buf[tid] += t;
            __syncthreads();
        }
        myoff[s] = buf[tid] - cnt[s];
        if (tid == 1023) btot[s] = buf[tid];
        __syncthreads();
    }
    if (tid == 0) {
        int running = 0;
        for (int ss = 5; ss >= 0; --ss) { sb[ss] = running; bstart[ss] = running; running += btot[ss]; }
        bstart[6] = running;
    }
    __syncthreads();
    int pos[6];
    #pragma unroll
    for (int s = 0; s < 6; s++) pos[s] = sb[s] + myoff[s];
    for (int i = start; i < end; i++) {
        int s = steps[i];
        order[pos[s]++] = i;
    }
}

// ---------------- pack h into order-space (bf16 hi/lo planes) ----------------
__global__ void pack_kernel(const float* __restrict__ h, const int* __restrict__ order,
                            __hip_bfloat16* __restrict__ hHi, __hip_bfloat16* __restrict__ hLo, int N) {
    int tid = blockIdx.x*blockDim.x + threadIdx.x;
    if (tid >= N*HID) return;
    int li = tid / HID, f = tid % HID;
    int n = order[li];
    float v = h[(size_t)n*HID + f];
    split_bf16(v, &hHi[tid], &hLo[tid]);
}

// ---------------- CSR build ----------------
__global__ void deg_kernel(const int* __restrict__ row, int* deg, int E) {
    int e = blockIdx.x*blockDim.x + threadIdx.x;
    if (e < E) atomicAdd(&deg[row[e]], 1);
}

__global__ void scan_kernel(const int* __restrict__ deg, int* __restrict__ off, int N) {
    __shared__ int buf[1024];
    int tid = threadIdx.x;
    int C = (N + 1023) / 1024;
    int start = tid * C, end = min(start + C, N);
    if (end < start) end = start;
    int s = 0;
    for (int i = start; i < end; i++) s += deg[i];
    buf[tid] = s; __syncthreads();
    for (int ofs = 1; ofs < 1024; ofs <<= 1) {
        int t = (tid >= ofs) ? buf[tid - ofs] : 0;
        __syncthreads();
        buf[tid] += t;
        __syncthreads();
    }
    int incl = buf[tid];
    int run = incl - s;
    for (int i = start; i < end; i++) { off[i] = run; run += deg[i]; }
    if (tid == 1023) off[N] = incl;
}

__global__ void fill_kernel(const int* __restrict__ row, const int* __restrict__ col,
                            const int* __restrict__ off, int* cur, int* __restrict__ csr_col, int E) {
    int e = blockIdx.x*blockDim.x + threadIdx.x;
    if (e >= E) return;
    int r = row[e];
    int p = atomicAdd(&cur[r], 1);
    csr_col[off[r] + p] = col[e];
}

// ---------------- aggregation -> packed bf16 hi/lo (4-way unrolled gathers) ----------------
__global__ void agg_kernel(const float* __restrict__ h, const int* __restrict__ off,
                           const int* __restrict__ csr_col, const int* __restrict__ order,
                           const int* __restrict__ bstart, int t,
                           __hip_bfloat16* __restrict__ aggHi, __hip_bfloat16* __restrict__ aggLo) {
    int K = bstart[t];
    int total = K * HID;
    int stride = gridDim.x * blockDim.x;
    for (int idx = blockIdx.x*blockDim.x + threadIdx.x; idx < total; idx += stride) {
        int li = idx / HID, f = idx % HID;
        int i = order[li];
        float hv = h[(size_t)i*HID + f];
        int e0 = off[i], e1 = off[i+1];
        float acc = 0.f;
        int e = e0;
        for (; e + 4 <= e1; e += 4) {
            int c0 = csr_col[e],   c1 = csr_col[e+1];
            int c2 = csr_col[e+2], c3 = csr_col[e+3];
            float v0 = h[(size_t)c0*HID + f];
            float v1 = h[(size_t)c1*HID + f];
            float v2 = h[(size_t)c2*HID + f];
            float v3 = h[(size_t)c3*HID + f];
            acc += fabsf(hv - v0) + fabsf(hv - v1) + fabsf(hv - v2) + fabsf(hv - v3);
        }
        for (; e < e1; e++) {
            int c = csr_col[e];
            acc += fabsf(hv - h[(size_t)c*HID + f]);
        }
        split_bf16(acc, &aggHi[idx], &aggLo[idx]);
    }
}

// ---------------- GRU via split-bf16 MFMA GEMM, fused epilogue ----------------
__global__ void __launch_bounds__(512) gru_kernel(
        const __hip_bfloat16* __restrict__ aggHi, const __hip_bfloat16* __restrict__ aggLo,
        const __hip_bfloat16* __restrict__ hHi,   const __hip_bfloat16* __restrict__ hLo,
        const __hip_bfloat16* __restrict__ WHi,   const __hip_bfloat16* __restrict__ WLo,
        const float* __restrict__ smallf, const int* __restrict__ bstart, int t,
        float* __restrict__ hnewP, int N) {
    int K = bstart[t];
    int row0 = blockIdx.x * BM;
    if (row0 >= K) return;
    int jj0 = blockIdx.y * 16;

    __shared__ ushort_t Ah[128*200];
    __shared__ ushort_t Al[128*200];
    __shared__ ushort_t Wh[64*200];
    __shared__ ushort_t Wl[64*200];

    int tid = threadIdx.x;
    const ushort_t* aH = (const ushort_t*)aggHi;
    const ushort_t* aL = (const ushort_t*)aggLo;
    const ushort_t* hH = (const ushort_t*)hHi;
    const ushort_t* hL = (const ushort_t*)hLo;
    const ushort_t* wH = (const ushort_t*)WHi;
    const ushort_t* wL = (const ushort_t*)WLo;
    long limit = (long)N * HID;
    #pragma unroll
    for (int j = 0; j < 3; j++) {
        int e = (tid + j*512) * 8;
        {
            int r = e / 96, c = e % 96;
            long ge = (long)(row0 + r)*96 + c;
            short8 vah = {0,0,0,0,0,0,0,0}, val = vah, vhh = vah, vhl = vah;
            if (ge + 8 <= limit) {
                vah = *(const short8*)(aH + ge);
                val = *(const short8*)(aL + ge);
                vhh = *(const short8*)(hH + ge);
                vhl = *(const short8*)(hL + ge);
            }
            *(short8*)(&Ah[r*200 + c])      = vah;
            *(short8*)(&Al[r*200 + c])      = val;
            *(short8*)(&Ah[r*200 + 96 + c]) = vhh;
            *(short8*)(&Al[r*200 + 96 + c]) = vhl;
        }
        {
            int wrow = e / 192, k = e % 192;
            int g = wrow >> 4, cc = wrow & 15;
            long wi = (long)(g*96 + jj0 + cc)*192 + k;
            *(short8*)(&Wh[wrow*200 + k]) = *(const short8*)(wH + wi);
            *(short8*)(&Wl[wrow*200 + k]) = *(const short8*)(wL + wi);
        }
    }
    __syncthreads();

    int lane = tid & 63;
    int w = tid >> 6;
    int m15 = lane & 15, quad = lane >> 4;
    floatx4 acc[4];
    #pragma unroll
    for (int g = 0; g < 4; g++) acc[g] = (floatx4){0.f, 0.f, 0.f, 0.f};

    int abase = (w*16 + m15)*200 + quad*8;
    #pragma unroll
    for (int ks = 0; ks < 6; ks++) {
        int k0 = ks*32;
        short8 ah = *(const short8*)(&Ah[abase + k0]);
        short8 al = *(const short8*)(&Al[abase + k0]);
        #pragma unroll
        for (int g = 0; g < 4; g++) {
            int wb = (g*16 + m15)*200 + quad*8 + k0;
            short8 bh = *(const short8*)(&Wh[wb]);
            short8 bl = *(const short8*)(&Wl[wb]);
            acc[g] = __builtin_amdgcn_mfma_f32_16x16x32_bf16(ah, bh, acc[g], 0, 0, 0);
            acc[g] = __builtin_amdgcn_mfma_f32_16x16x32_bf16(al, bh, acc[g], 0, 0, 0);
            acc[g] = __builtin_amdgcn_mfma_f32_16x16x32_bf16(ah, bl, acc[g], 0, 0, 0);
        }
    }

    int jj = jj0 + m15;
    float bir = smallf[96+jj],  biz = smallf[192+jj], bin = smallf[288+jj];
    float bhr = smallf[384+jj], bhz = smallf[480+jj], bhn = smallf[576+jj];
    #pragma unroll
    for (int reg = 0; reg < 4; reg++) {
        int li = row0 + w*16 + quad*4 + reg;
        if (li < K) {
            float rp = acc[0][reg] + bir + bhr;
            float zp = acc[1][reg] + biz + bhz;
            float ip = acc[2][reg] + bin;
            float hn = acc[3][reg] + bhn;
            float r  = 1.f/(1.f + expf(-rp));
            float z  = 1.f/(1.f + expf(-zp));
            float nn = tanhf(ip + r*hn);
            long idx = (long)li*HID + jj;
            float hold = __bfloat162float(hHi[idx]) + __bfloat162float(hLo[idx]);
            hnewP[idx] = (1.f - z)*nn + z*hold;
        }
    }
}

// ---------------- commit: active prefix -> h (node layout) + hi/lo planes ----------------
__global__ void commit_kernel(float* __restrict__ h,
                              __hip_bfloat16* __restrict__ hHi, __hip_bfloat16* __restrict__ hLo,
                              const float* __restrict__ hnewP,
                              const int* __restrict__ order, const int* __restrict__ bstart, int t) {
    int K = bstart[t];
    int total = K * HID;
    int stride = gridDim.x * blockDim.x;
    for (int idx = blockIdx.x*blockDim.x + threadIdx.x; idx < total; idx += stride) {
        int li = idx / HID, f = idx % HID;
        int i = order[li];
        float v = hnewP[idx];
        h[(size_t)i*HID + f] = v;
        split_bf16(v, &hHi[idx], &hLo[idx]);
    }
}

// ---------------- out = h @ w_out + b_out (dtype per mode) ----------------
__global__ void out_kernel(const float* __restrict__ h, const float* __restrict__ w_out_f,
                           const float* __restrict__ smallf, void* out, const int* mode, int N) {
    int tid = blockIdx.x*blockDim.x + threadIdx.x;
    if (tid >= N*OUTDIM) return;
    int n = tid / OUTDIM, o = tid % OUTDIM;
    float acc = smallf[672+o];
    const float* hr = h + (size_t)n*HID;
    #pragma unroll 8
    for (int k = 0; k < HID; k++) acc += hr[k] * w_out_f[k*OUTDIM + o];
    if (*mode) ((float*)out)[tid] = acc;
    else       ((__hip_bfloat16*)out)[tid] = __float2bfloat16(acc);
}

extern "C" void kernel_launch(void* const* d_in, const int* in_sizes, int n_in,
                              void* d_out, int out_size, void* d_ws, size_t ws_size,
                              hipStream_t stream) {
    const void* x      = d_in[0];
    const int*  ei     = (const int*)d_in[1];
    const void* w_in   = d_in[2],  *b_in   = d_in[3];
    const void* tau_w1 = d_in[4],  *tau_b1 = d_in[5];
    const void* tau_w2 = d_in[6],  *tau_b2 = d_in[7];
    const void* wih    = d_in[8],  *whh    = d_in[9];
    const void* bih    = d_in[10], *bhh    = d_in[11];
    const void* w_out  = d_in[12], *b_out  = d_in[13];

    int N = in_sizes[0] / INDIM;
    int E = in_sizes[1] / 2;
    const int* row = ei;
    const int* col = ei + E;

    char* ws = (char*)d_ws;
    size_t o = 0;
    auto take = [&](size_t bytes) -> char* {
        char* p = ws + o;
        o = (o + bytes + 255) & ~(size_t)255;
        return p;
    };
    float* x_f      = (float*)take((size_t)N*INDIM*4);   // reused as hnewP after h0/tau
    float* hnewP    = x_f;
    float* h        = (float*)take((size_t)N*HID*4);
    __hip_bfloat16* hHi   = (__hip_bfloat16*)take((size_t)N*HID*2);
    __hip_bfloat16* hLo   = (__hip_bfloat16*)take((size_t)N*HID*2);
    __hip_bfloat16* aggHi = (__hip_bfloat16*)take((size_t)N*HID*2);
    __hip_bfloat16* aggLo = (__hip_bfloat16*)take((size_t)N*HID*2);
    __hip_bfloat16* W2T_hi= (__hip_bfloat16*)take((size_t)384*192*2);
    __hip_bfloat16* W2T_lo= (__hip_bfloat16*)take((size_t)384*192*2);
    __hip_bfloat16* WinT_hi=(__hip_bfloat16*)take((size_t)96*128*2);
    __hip_bfloat16* WinT_lo=(__hip_bfloat16*)take((size_t)96*128*2);
    float* w_out_f  = (float*)take((size_t)HID*OUTDIM*4);
    float* tau_w1_f = (float*)take((size_t)INDIM*16*4);
    float* smallf   = (float*)take(1024*4);
    int*   off      = (int*)take((size_t)(N+1)*4);
    int*   csr_col  = (int*)take((size_t)E*4);
    int*   order    = (int*)take((size_t)N*4);
    int*   steps    = (int*)take((size_t)N*4);
    int*   bstart   = (int*)take(64);
    int*   mode     = (int*)take(64);
    char*  zbase    = ws + o;
    int*   deg      = (int*)take((size_t)N*4);
    int*   cur      = (int*)take((size_t)N*4);
    size_t zbytes   = (size_t)((ws + o) - zbase);

    hipMemsetAsync(zbase, 0, zbytes, stream);
    sniff_kernel<<<1, 64, 0, stream>>>((const unsigned int*)x, mode);

    xconv_kernel<<<(N*INDIM + 255)/256, 256, 0, stream>>>(x, x_f, mode, N*INDIM);
    prep_kernel<<<(384*192 + 255)/256, 256, 0, stream>>>(
        w_in, b_in, tau_w1, tau_b1, tau_w2, tau_b2, wih, whh, bih, bhh, w_out, b_out,
        W2T_hi, W2T_lo, WinT_hi, WinT_lo, w_out_f, tau_w1_f, smallf, mode);

    dim3 hgrid((N + BM - 1)/BM, 6);
    h0_kernel<<<hgrid, 512, 0, stream>>>(x_f, WinT_hi, WinT_lo, smallf, h, N);
    tau_kernel<<<((size_t)N*64 + 255)/256, 256, 0, stream>>>(x_f, tau_w1_f, smallf, steps, N);
    bucket_kernel<<<1, 1024, 0, stream>>>(steps, bstart, order, N);
    pack_kernel<<<(N*HID + 255)/256, 256, 0, stream>>>(h, order, hHi, hLo, N);
    deg_kernel<<<(E + 255)/256, 256, 0, stream>>>(row, deg, E);
    scan_kernel<<<1, 1024, 0, stream>>>(deg, off, N);
    fill_kernel<<<(E + 255)/256, 256, 0, stream>>>(row, col, off, cur, csr_col, E);

    dim3 ggrid((N + BM - 1)/BM, 6);
    for (int t = 0; t < 5; t++) {
        agg_kernel<<<4096, 256, 0, stream>>>(h, off, csr_col, order, bstart, t, aggHi, aggLo);
        gru_kernel<<<ggrid, 512, 0, stream>>>(aggHi, aggLo, hHi, hLo, W2T_hi, W2T_lo,
                                              smallf, bstart, t, hnewP, N);
        commit_kernel<<<2048, 256, 0, stream>>>(h, hHi, hLo, hnewP, order, bstart, t);
    }

    out_kernel<<<(N*OUTDIM + 255)/256, 256, 0, stream>>>(h, w_out_f, smallf, d_out, mode, N);
}

// Round 10
// 605.358 us; speedup vs baseline: 3.6423x; 1.2549x over previous
//
#include <hip/hip_runtime.h>
#include <hip/hip_bf16.h>

#define HID 96
#define INDIM 128
#define OUTDIM 64
#define BM 128
#define GP 128   // partial/scatter grid blocks (fixed mapping)

typedef __attribute__((ext_vector_type(8))) short short8;
typedef __attribute__((ext_vector_type(4))) short short4_t;
typedef __attribute__((ext_vector_type(4))) float floatx4;
typedef unsigned short ushort_t;

__device__ __forceinline__ float ldmix(const void* p, long i, int mode) {
    return mode ? ((const float*)p)[i]
                : __bfloat162float(((const __hip_bfloat16*)p)[i]);
}

__device__ __forceinline__ void split_bf16(float v, __hip_bfloat16* hi, __hip_bfloat16* lo) {
    __hip_bfloat16 h = __float2bfloat16(v);
    *hi = h;
    *lo = __float2bfloat16(v - __bfloat162float(h));
}

__device__ __forceinline__ void split_us(float v, ushort_t* hi, ushort_t* lo) {
    __hip_bfloat16 h = __float2bfloat16(v);
    float hf = __bfloat162float(h);
    __hip_bfloat16 l = __float2bfloat16(v - hf);
    *hi = *(ushort_t*)&h;
    *lo = *(ushort_t*)&l;
}

// ---------------- dtype sniffer (parallel: 64 lanes x 64 words) ----------------
__global__ void sniff_kernel(const unsigned int* xw, int* mode) {
    int lane = threadIdx.x & 63;
    int cnt = 0;
    for (int i = lane; i < 4096; i += 64) {
        unsigned int low = xw[i] & 0xFFFFu;
        unsigned int e = (low >> 7) & 0xFFu;
        if (e >= 0xC0u) cnt++;
    }
    #pragma unroll
    for (int ofs = 32; ofs > 0; ofs >>= 1) cnt += __shfl_down(cnt, ofs);
    if (lane == 0) *mode = (cnt > 256) ? 1 : 0;  // 1 = fp32 inputs, 0 = bf16 inputs
}

// ---------------- x -> fp32 ----------------
__global__ void xconv_kernel(const void* x, float* __restrict__ x_f, const int* mode, int total) {
    int m = *mode;
    int tid = blockIdx.x*blockDim.x + threadIdx.x;
    if (tid < total) x_f[tid] = ldmix(x, tid, m);
}

// ---------------- weight prep ----------------
// smallf: [0..95] b_in, [96..383] bih, [384..671] bhh, [672..735] b_out,
//         [736..751] tau_w2, [752..767] tau_b1, [768] tau_b2
__global__ void prep_kernel(const void* w_in, const void* b_in, const void* tau_w1,
                            const void* tau_b1, const void* tau_w2, const void* tau_b2,
                            const void* wih, const void* whh, const void* bih, const void* bhh,
                            const void* w_out, const void* b_out,
                            __hip_bfloat16* W2T_hi, __hip_bfloat16* W2T_lo,
                            __hip_bfloat16* WinT_hi, __hip_bfloat16* WinT_lo,
                            float* w_out_f,
                            float* tau_w1_f, float* smallf, const int* mode) {
    int m = *mode;
    int tid = blockIdx.x*blockDim.x + threadIdx.x;
    if (tid < 384*192) {
        int c = tid / 192, k = tid % 192;
        int g = c / 96, jj = c % 96;
        float v = 0.f;
        if (k < 96) {
            if (g == 0)      v = ldmix(wih, (long)(jj)*96 + k, m);
            else if (g == 1) v = ldmix(wih, (long)(96+jj)*96 + k, m);
            else if (g == 2) v = ldmix(wih, (long)(192+jj)*96 + k, m);
        } else {
            int kk = k - 96;
            if (g == 0)      v = ldmix(whh, (long)(jj)*96 + kk, m);
            else if (g == 1) v = ldmix(whh, (long)(96+jj)*96 + kk, m);
            else if (g == 3) v = ldmix(whh, (long)(192+jj)*96 + kk, m);
        }
        split_bf16(v, &W2T_hi[tid], &W2T_lo[tid]);
    }
    if (tid < 96*128) {
        int j = tid >> 7, k = tid & 127;
        float v = ldmix(w_in, (long)k*96 + j, m);
        split_bf16(v, &WinT_hi[tid], &WinT_lo[tid]);
    }
    if (tid < HID*OUTDIM) w_out_f[tid]  = ldmix(w_out, tid, m);
    if (tid < INDIM*16)   tau_w1_f[tid] = ldmix(tau_w1, tid, m);
    if (tid < HID)    smallf[tid]       = ldmix(b_in, tid, m);
    if (tid < 3*HID){ smallf[96+tid]    = ldmix(bih, tid, m);
                      smallf[384+tid]   = ldmix(bhh, tid, m); }
    if (tid < OUTDIM) smallf[672+tid]   = ldmix(b_out, tid, m);
    if (tid < 16)   { smallf[736+tid]   = ldmix(tau_w2, tid, m);
                      smallf[752+tid]   = ldmix(tau_b1, tid, m); }
    if (tid == 0)     smallf[768]       = ldmix(tau_b2, 0, m);
}

// ---------------- h0 = relu(x @ w_in + b_in) via split-bf16 MFMA ----------------
__global__ void __launch_bounds__(512) h0_kernel(
        const float* __restrict__ x_f,
        const __hip_bfloat16* __restrict__ WinT_hi, const __hip_bfloat16* __restrict__ WinT_lo,
        const float* __restrict__ smallf, float* __restrict__ h, int N) {
    int row0 = blockIdx.x * BM;
    int jj0 = blockIdx.y * 16;

    __shared__ ushort_t Ah[128*136];
    __shared__ ushort_t Al[128*136];
    __shared__ ushort_t Wh[16*136];
    __shared__ ushort_t Wl[16*136];

    int tid = threadIdx.x;
    long limit = (long)N * INDIM;
    #pragma unroll
    for (int j = 0; j < 8; j++) {
        int e = (tid + j*512) * 4;
        int r = e >> 7, c = e & 127;
        long ge = (long)(row0 + r)*INDIM + c;
        floatx4 v = {0.f, 0.f, 0.f, 0.f};
        if (ge + 4 <= limit) v = *(const floatx4*)(x_f + ge);
        short4_t vh4, vl4;
        #pragma unroll
        for (int q = 0; q < 4; q++) {
            ushort_t hi, lo;
            split_us(v[q], &hi, &lo);
            vh4[q] = (short)hi; vl4[q] = (short)lo;
        }
        *(short4_t*)(&Ah[r*136 + c]) = vh4;
        *(short4_t*)(&Al[r*136 + c]) = vl4;
    }
    if (tid < 256) {
        int wrow = tid >> 4;
        int k = (tid & 15) * 8;
        long wi = (long)(jj0 + wrow)*INDIM + k;
        *(short8*)(&Wh[wrow*136 + k]) = *(const short8*)((const ushort_t*)WinT_hi + wi);
        *(short8*)(&Wl[wrow*136 + k]) = *(const short8*)((const ushort_t*)WinT_lo + wi);
    }
    __syncthreads();

    int lane = tid & 63;
    int w = tid >> 6;
    int m15 = lane & 15, quad = lane >> 4;
    floatx4 acc = {0.f, 0.f, 0.f, 0.f};
    int abase = (w*16 + m15)*136 + quad*8;
    #pragma unroll
    for (int ks = 0; ks < 4; ks++) {
        int k0 = ks*32;
        short8 ah = *(const short8*)(&Ah[abase + k0]);
        short8 al = *(const short8*)(&Al[abase + k0]);
        int wb = m15*136 + quad*8 + k0;
        short8 bh = *(const short8*)(&Wh[wb]);
        short8 bl = *(const short8*)(&Wl[wb]);
        acc = __builtin_amdgcn_mfma_f32_16x16x32_bf16(ah, bh, acc, 0, 0, 0);
        acc = __builtin_amdgcn_mfma_f32_16x16x32_bf16(al, bh, acc, 0, 0, 0);
        acc = __builtin_amdgcn_mfma_f32_16x16x32_bf16(ah, bl, acc, 0, 0, 0);
    }

    int jj = jj0 + m15;
    float b = smallf[jj];
    #pragma unroll
    for (int reg = 0; reg < 4; reg++) {
        int li = row0 + w*16 + quad*4 + reg;
        if (li < N) h[(long)li*HID + jj] = fmaxf(acc[reg] + b, 0.f);
    }
}

// ---------------- tau MLP -> steps (wave per node; no atomics) ----------------
__global__ void tau_kernel(const float* __restrict__ x_f, const float* __restrict__ tau_w1_f,
                           const float* __restrict__ smallf,
                           int* __restrict__ steps, int N) {
    int gtid = blockIdx.x*blockDim.x + threadIdx.x;
    int n = gtid >> 6;
    int lane = threadIdx.x & 63;
    if (n >= N) return;
    const float* xr = x_f + (size_t)n*INDIM;
    float x0 = xr[lane];
    float x1 = xr[64 + lane];
    const float* w0 = tau_w1_f + lane*16;
    const float* w1 = tau_w1_f + (64 + lane)*16;
    float acc[16];
    #pragma unroll
    for (int j = 0; j < 16; j++) acc[j] = x0*w0[j] + x1*w1[j];
    #pragma unroll
    for (int ofs = 32; ofs > 0; ofs >>= 1) {
        #pragma unroll
        for (int j = 0; j < 16; j++) acc[j] += __shfl_down(acc[j], ofs);
    }
    if (lane == 0) {
        float z = smallf[768];
        #pragma unroll
        for (int j = 0; j < 16; j++) z += fmaxf(acc[j] + smallf[752+j], 0.f) * smallf[736+j];
        float tau = fmaxf(z, 0.f) + log1pf(expf(-fabsf(z)));
        float inv = 1.0f / tau;
        int s;
        if (inv >= 5.0f) s = 5;
        else { s = (int)inv; if (s < 0) s = 0; if (s > 5) s = 5; }
        steps[n] = s;
    }
}

// ---------------- multi-block deterministic bucket+deg pipeline ----------------
// Fixed mapping: thread tg = b*256+t owns nodes [tg*C, tg*C+C), C = ceil(N/(GP*256)).
// partial: per-block bucket counts (6) + deg sum -> blksum[b*8 + {0..6}]
__global__ void partial_kernel(const int* __restrict__ steps, const int* __restrict__ deg,
                               int N, int C, int* __restrict__ blksum) {
    __shared__ int red[256*8];
    int tid = threadIdx.x;
    int tg = blockIdx.x*256 + tid;
    int start = tg*C, end = min(start + C, N);
    if (end < start) end = start;
    int cnt[7] = {0,0,0,0,0,0,0};
    for (int i = start; i < end; i++) { cnt[steps[i]]++; cnt[6] += deg[i]; }
    #pragma unroll
    for (int k = 0; k < 7; k++) red[tid*8 + k] = cnt[k];
    __syncthreads();
    for (int ofs = 128; ofs > 0; ofs >>= 1) {
        if (tid < ofs) {
            #pragma unroll
            for (int k = 0; k < 7; k++) red[tid*8 + k] += red[(tid+ofs)*8 + k];
        }
        __syncthreads();
    }
    if (tid < 7) blksum[blockIdx.x*8 + tid] = red[tid];
}

// base: totals -> bstart (descending buckets), per-block bases blkbase, off[N]=E
__global__ void base_kernel(const int* __restrict__ blksum, int* __restrict__ bstart,
                            int* __restrict__ blkbase, int* __restrict__ off, int N) {
    __shared__ int tot[8];
    __shared__ int sb[8];
    int tid = threadIdx.x;
    if (tid < 7) {
        int s = 0;
        for (int b = 0; b < GP; b++) s += blksum[b*8 + tid];
        tot[tid] = s;
    }
    __syncthreads();
    if (tid == 0) {
        int run = 0;
        for (int ss = 5; ss >= 0; --ss) { sb[ss] = run; bstart[ss] = run; run += tot[ss]; }
        bstart[6] = run;          // = N
        off[N] = tot[6];          // = E
        sb[6] = 0;
    }
    __syncthreads();
    if (tid < 7) {
        int run = sb[tid];
        for (int b = 0; b < GP; b++) { blkbase[b*8 + tid] = run; run += blksum[b*8 + tid]; }
    }
}

// scatter: stable order (bucket desc, node asc) + off = exclusive scan of deg
__global__ void scatter_kernel(const int* __restrict__ steps, const int* __restrict__ deg,
                               const int* __restrict__ blkbase, int N, int C,
                               int* __restrict__ order, int* __restrict__ off) {
    __shared__ int buf[256];
    int tid = threadIdx.x;
    int b = blockIdx.x;
    int tg = b*256 + tid;
    int start = tg*C, end = min(start + C, N);
    if (end < start) end = start;
    int cnt[7] = {0,0,0,0,0,0,0};
    for (int i = start; i < end; i++) { cnt[steps[i]]++; cnt[6] += deg[i]; }
    int mybase[7];
    #pragma unroll
    for (int k = 0; k < 7; k++) {
        buf[tid] = cnt[k];
        __syncthreads();
        for (int ofs = 1; ofs < 256; ofs <<= 1) {
            int t = (tid >= ofs) ? buf[tid - ofs] : 0;
            __syncthreads();
            buf[tid] += t;
            __syncthreads();
        }
        mybase[k] = blkbase[b*8 + k] + buf[tid] - cnt[k];
        __syncthreads();
    }
    for (int i = start; i < end; i++) {
        int s = steps[i];
        order[mybase[s]++] = i;
        off[i] = mybase[6];
        mybase[6] += deg[i];
    }
}

// ---------------- pack h into order-space (bf16 hi/lo planes) ----------------
__global__ void pack_kernel(const float* __restrict__ h, const int* __restrict__ order,
                            __hip_bfloat16* __restrict__ hHi, __hip_bfloat16* __restrict__ hLo, int N) {
    int tid = blockIdx.x*blockDim.x + threadIdx.x;
    if (tid >= N*HID) return;
    int li = tid / HID, f = tid % HID;
    int n = order[li];
    float v = h[(size_t)n*HID + f];
    split_bf16(v, &hHi[tid], &hLo[tid]);
}

// ---------------- CSR build ----------------
__global__ void deg_kernel(const int* __restrict__ row, int* deg, int E) {
    int e = blockIdx.x*blockDim.x + threadIdx.x;
    if (e < E) atomicAdd(&deg[row[e]], 1);
}

__global__ void fill_kernel(const int* __restrict__ row, const int* __restrict__ col,
                            const int* __restrict__ off, int* cur, int* __restrict__ csr_col, int E) {
    int e = blockIdx.x*blockDim.x + threadIdx.x;
    if (e >= E) return;
    int r = row[e];
    int p = atomicAdd(&cur[r], 1);
    csr_col[off[r] + p] = col[e];
}

// ---------------- aggregation -> packed bf16 hi/lo (4-way unrolled gathers) ----------------
__global__ void agg_kernel(const float* __restrict__ h, const int* __restrict__ off,
                           const int* __restrict__ csr_col, const int* __restrict__ order,
                           const int* __restrict__ bstart, int t,
                           __hip_bfloat16* __restrict__ aggHi, __hip_bfloat16* __restrict__ aggLo) {
    int K = bstart[t];
    int total = K * HID;
    int stride = gridDim.x * blockDim.x;
    for (int idx = blockIdx.x*blockDim.x + threadIdx.x; idx < total; idx += stride) {
        int li = idx / HID, f = idx % HID;
        int i = order[li];
        float hv = h[(size_t)i*HID + f];
        int e0 = off[i], e1 = off[i+1];
        float acc = 0.f;
        int e = e0;
        for (; e + 4 <= e1; e += 4) {
            int c0 = csr_col[e],   c1 = csr_col[e+1];
            int c2 = csr_col[e+2], c3 = csr_col[e+3];
            float v0 = h[(size_t)c0*HID + f];
            float v1 = h[(size_t)c1*HID + f];
            float v2 = h[(size_t)c2*HID + f];
            float v3 = h[(size_t)c3*HID + f];
            acc += fabsf(hv - v0) + fabsf(hv - v1) + fabsf(hv - v2) + fabsf(hv - v3);
        }
        for (; e < e1; e++) {
            int c = csr_col[e];
            acc += fabsf(hv - h[(size_t)c*HID + f]);
        }
        split_bf16(acc, &aggHi[idx], &aggLo[idx]);
    }
}

// ---------------- GRU via split-bf16 MFMA GEMM, fused epilogue ----------------
__global__ void __launch_bounds__(512) gru_kernel(
        const __hip_bfloat16* __restrict__ aggHi, const __hip_bfloat16* __restrict__ aggLo,
        const __hip_bfloat16* __restrict__ hHi,   const __hip_bfloat16* __restrict__ hLo,
        const __hip_bfloat16* __restrict__ WHi,   const __hip_bfloat16* __restrict__ WLo,
        const float* __restrict__ smallf, const int* __restrict__ bstart, int t,
        float* __restrict__ hnewP, int N) {
    int K = bstart[t];
    int row0 = blockIdx.x * BM;
    if (row0 >= K) return;
    int jj0 = blockIdx.y * 16;

    __shared__ ushort_t Ah[128*200];
    __shared__ ushort_t Al[128*200];
    __shared__ ushort_t Wh[64*200];
    __shared__ ushort_t Wl[64*200];

    int tid = threadIdx.x;
    const ushort_t* aH = (const ushort_t*)aggHi;
    const ushort_t* aL = (const ushort_t*)aggLo;
    const ushort_t* hH = (const ushort_t*)hHi;
    const ushort_t* hL = (const ushort_t*)hLo;
    const ushort_t* wH = (const ushort_t*)WHi;
    const ushort_t* wL = (const ushort_t*)WLo;
    long limit = (long)N * HID;
    #pragma unroll
    for (int j = 0; j < 3; j++) {
        int e = (tid + j*512) * 8;
        {
            int r = e / 96, c = e % 96;
            long ge = (long)(row0 + r)*96 + c;
            short8 vah = {0,0,0,0,0,0,0,0}, val = vah, vhh = vah, vhl = vah;
            if (ge + 8 <= limit) {
                vah = *(const short8*)(aH + ge);
                val = *(const short8*)(aL + ge);
                vhh = *(const short8*)(hH + ge);
                vhl = *(const short8*)(hL + ge);
            }
            *(short8*)(&Ah[r*200 + c])      = vah;
            *(short8*)(&Al[r*200 + c])      = val;
            *(short8*)(&Ah[r*200 + 96 + c]) = vhh;
            *(short8*)(&Al[r*200 + 96 + c]) = vhl;
        }
        {
            int wrow = e / 192, k = e % 192;
            int g = wrow >> 4, cc = wrow & 15;
            long wi = (long)(g*96 + jj0 + cc)*192 + k;
            *(short8*)(&Wh[wrow*200 + k]) = *(const short8*)(wH + wi);
            *(short8*)(&Wl[wrow*200 + k]) = *(const short8*)(wL + wi);
        }
    }
    __syncthreads();

    int lane = tid & 63;
    int w = tid >> 6;
    int m15 = lane & 15, quad = lane >> 4;
    floatx4 acc[4];
    #pragma unroll
    for (int g = 0; g < 4; g++) acc[g] = (floatx4){0.f, 0.f, 0.f, 0.f};

    int abase = (w*16 + m15)*200 + quad*8;
    #pragma unroll
    for (int ks = 0; ks < 6; ks++) {
        int k0 = ks*32;
        short8 ah = *(const short8*)(&Ah[abase + k0]);
        short8 al = *(const short8*)(&Al[abase + k0]);
        #pragma unroll
        for (int g = 0; g < 4; g++) {
            int wb = (g*16 + m15)*200 + quad*8 + k0;
            short8 bh = *(const short8*)(&Wh[wb]);
            short8 bl = *(const short8*)(&Wl[wb]);
            acc[g] = __builtin_amdgcn_mfma_f32_16x16x32_bf16(ah, bh, acc[g], 0, 0, 0);
            acc[g] = __builtin_amdgcn_mfma_f32_16x16x32_bf16(al, bh, acc[g], 0, 0, 0);
            acc[g] = __builtin_amdgcn_mfma_f32_16x16x32_bf16(ah, bl, acc[g], 0, 0, 0);
        }
    }

    int jj = jj0 + m15;
    float bir = smallf[96+jj],  biz = smallf[192+jj], bin = smallf[288+jj];
    float bhr = smallf[384+jj], bhz = smallf[480+jj], bhn = smallf[576+jj];
    #pragma unroll
    for (int reg = 0; reg < 4; reg++) {
        int li = row0 + w*16 + quad*4 + reg;
        if (li < K) {
            float rp = acc[0][reg] + bir + bhr;
            float zp = acc[1][reg] + biz + bhz;
            float ip = acc[2][reg] + bin;
            float hn = acc[3][reg] + bhn;
            float r  = 1.f/(1.f + expf(-rp));
            float z  = 1.f/(1.f + expf(-zp));
            float nn = tanhf(ip + r*hn);
            long idx = (long)li*HID + jj;
            float hold = __bfloat162float(hHi[idx]) + __bfloat162float(hLo[idx]);
            hnewP[idx] = (1.f - z)*nn + z*hold;
        }
    }
}

// ---------------- commit: active prefix -> h (node layout) + hi/lo planes ----------------
__global__ void commit_kernel(float* __restrict__ h,
                              __hip_bfloat16* __restrict__ hHi, __hip_bfloat16* __restrict__ hLo,
                              const float* __restrict__ hnewP,
                              const int* __restrict__ order, const int* __restrict__ bstart, int t) {
    int K = bstart[t];
    int total = K * HID;
    int stride = gridDim.x * blockDim.x;
    for (int idx = blockIdx.x*blockDim.x + threadIdx.x; idx < total; idx += stride) {
        int li = idx / HID, f = idx % HID;
        int i = order[li];
        float v = hnewP[idx];
        h[(size_t)i*HID + f] = v;
        split_bf16(v, &hHi[idx], &hLo[idx]);
    }
}

// ---------------- out = h @ w_out + b_out (dtype per mode) ----------------
__global__ void out_kernel(const float* __restrict__ h, const float* __restrict__ w_out_f,
                           const float* __restrict__ smallf, void* out, const int* mode, int N) {
    int tid = blockIdx.x*blockDim.x + threadIdx.x;
    if (tid >= N*OUTDIM) return;
    int n = tid / OUTDIM, o = tid % OUTDIM;
    float acc = smallf[672+o];
    const float* hr = h + (size_t)n*HID;
    #pragma unroll 8
    for (int k = 0; k < HID; k++) acc += hr[k] * w_out_f[k*OUTDIM + o];
    if (*mode) ((float*)out)[tid] = acc;
    else       ((__hip_bfloat16*)out)[tid] = __float2bfloat16(acc);
}

extern "C" void kernel_launch(void* const* d_in, const int* in_sizes, int n_in,
                              void* d_out, int out_size, void* d_ws, size_t ws_size,
                              hipStream_t stream) {
    const void* x      = d_in[0];
    const int*  ei     = (const int*)d_in[1];
    const void* w_in   = d_in[2],  *b_in   = d_in[3];
    const void* tau_w1 = d_in[4],  *tau_b1 = d_in[5];
    const void* tau_w2 = d_in[6],  *tau_b2 = d_in[7];
    const void* wih    = d_in[8],  *whh    = d_in[9];
    const void* bih    = d_in[10], *bhh    = d_in[11];
    const void* w_out  = d_in[12], *b_out  = d_in[13];

    int N = in_sizes[0] / INDIM;
    int E = in_sizes[1] / 2;
    const int* row = ei;
    const int* col = ei + E;

    char* ws = (char*)d_ws;
    size_t o = 0;
    auto take = [&](size_t bytes) -> char* {
        char* p = ws + o;
        o = (o + bytes + 255) & ~(size_t)255;
        return p;
    };
    float* x_f      = (float*)take((size_t)N*INDIM*4);   // reused as hnewP after h0/tau
    float* hnewP    = x_f;
    float* h        = (float*)take((size_t)N*HID*4);
    __hip_bfloat16* hHi   = (__hip_bfloat16*)take((size_t)N*HID*2);
    __hip_bfloat16* hLo   = (__hip_bfloat16*)take((size_t)N*HID*2);
    __hip_bfloat16* aggHi = (__hip_bfloat16*)take((size_t)N*HID*2);
    __hip_bfloat16* aggLo = (__hip_bfloat16*)take((size_t)N*HID*2);
    __hip_bfloat16* W2T_hi= (__hip_bfloat16*)take((size_t)384*192*2);
    __hip_bfloat16* W2T_lo= (__hip_bfloat16*)take((size_t)384*192*2);
    __hip_bfloat16* WinT_hi=(__hip_bfloat16*)take((size_t)96*128*2);
    __hip_bfloat16* WinT_lo=(__hip_bfloat16*)take((size_t)96*128*2);
    float* w_out_f  = (float*)take((size_t)HID*OUTDIM*4);
    float* tau_w1_f = (float*)take((size_t)INDIM*16*4);
    float* smallf   = (float*)take(1024*4);
    int*   off      = (int*)take((size_t)(N+1)*4);
    int*   csr_col  = (int*)take((size_t)E*4);
    int*   order    = (int*)take((size_t)N*4);
    int*   steps    = (int*)take((size_t)N*4);
    int*   bstart   = (int*)take(64);
    int*   mode     = (int*)take(64);
    int*   blksum   = (int*)take((size_t)GP*8*4);
    int*   blkbase  = (int*)take((size_t)GP*8*4);
    char*  zbase    = ws + o;
    int*   deg      = (int*)take((size_t)N*4);
    int*   cur      = (int*)take((size_t)N*4);
    size_t zbytes   = (size_t)((ws + o) - zbase);

    hipMemsetAsync(zbase, 0, zbytes, stream);
    sniff_kernel<<<1, 64, 0, stream>>>((const unsigned int*)x, mode);

    xconv_kernel<<<(N*INDIM + 255)/256, 256, 0, stream>>>(x, x_f, mode, N*INDIM);
    prep_kernel<<<(384*192 + 255)/256, 256, 0, stream>>>(
        w_in, b_in, tau_w1, tau_b1, tau_w2, tau_b2, wih, whh, bih, bhh, w_out, b_out,
        W2T_hi, W2T_lo, WinT_hi, WinT_lo, w_out_f, tau_w1_f, smallf, mode);

    dim3 hgrid((N + BM - 1)/BM, 6);
    h0_kernel<<<hgrid, 512, 0, stream>>>(x_f, WinT_hi, WinT_lo, smallf, h, N);
    tau_kernel<<<((size_t)N*64 + 255)/256, 256, 0, stream>>>(x_f, tau_w1_f, smallf, steps, N);
    deg_kernel<<<(E + 255)/256, 256, 0, stream>>>(row, deg, E);

    int C = (N + GP*256 - 1) / (GP*256);
    partial_kernel<<<GP, 256, 0, stream>>>(steps, deg, N, C, blksum);
    base_kernel<<<1, 64, 0, stream>>>(blksum, bstart, blkbase, off, N);
    scatter_kernel<<<GP, 256, 0, stream>>>(steps, deg, blkbase, N, C, order, off);

    pack_kernel<<<(N*HID + 255)/256, 256, 0, stream>>>(h, order, hHi, hLo, N);
    fill_kernel<<<(E + 255)/256, 256, 0, stream>>>(row, col, off, cur, csr_col, E);

    dim3 ggrid((N + BM - 1)/BM, 6);
    for (int t = 0; t < 5; t++) {
        agg_kernel<<<4096, 256, 0, stream>>>(h, off, csr_col, order, bstart, t, aggHi, aggLo);
        gru_kernel<<<ggrid, 512, 0, stream>>>(aggHi, aggLo, hHi, hLo, W2T_hi, W2T_lo,
                                              smallf, bstart, t, hnewP, N);
        commit_kernel<<<2048, 256, 0, stream>>>(h, hHi, hLo, hnewP, order, bstart, t);
    }

    out_kernel<<<(N*OUTDIM + 255)/256, 256, 0, stream>>>(h, w_out_f, smallf, d_out, mode, N);
}

// Round 11
// 557.134 us; speedup vs baseline: 3.9576x; 1.0866x over previous
//
#include <hip/hip_runtime.h>
#include <hip/hip_bf16.h>

#define HID 96
#define INDIM 128
#define OUTDIM 64
#define BM 128
#define GP 128   // partial/scatter grid blocks (fixed mapping)

typedef __attribute__((ext_vector_type(8))) short short8;
typedef __attribute__((ext_vector_type(4))) short short4_t;
typedef __attribute__((ext_vector_type(4))) float floatx4;
typedef unsigned short ushort_t;

__device__ __forceinline__ float ldmix(const void* p, long i, int mode) {
    return mode ? ((const float*)p)[i]
                : __bfloat162float(((const __hip_bfloat16*)p)[i]);
}

__device__ __forceinline__ void split_bf16(float v, __hip_bfloat16* hi, __hip_bfloat16* lo) {
    __hip_bfloat16 h = __float2bfloat16(v);
    *hi = h;
    *lo = __float2bfloat16(v - __bfloat162float(h));
}

__device__ __forceinline__ void split_us(float v, ushort_t* hi, ushort_t* lo) {
    __hip_bfloat16 h = __float2bfloat16(v);
    float hf = __bfloat162float(h);
    __hip_bfloat16 l = __float2bfloat16(v - hf);
    *hi = *(ushort_t*)&h;
    *lo = *(ushort_t*)&l;
}

// ---------------- dtype sniffer (parallel: 64 lanes x 64 words) ----------------
__global__ void sniff_kernel(const unsigned int* xw, int* mode) {
    int lane = threadIdx.x & 63;
    int cnt = 0;
    for (int i = lane; i < 4096; i += 64) {
        unsigned int low = xw[i] & 0xFFFFu;
        unsigned int e = (low >> 7) & 0xFFu;
        if (e >= 0xC0u) cnt++;
    }
    #pragma unroll
    for (int ofs = 32; ofs > 0; ofs >>= 1) cnt += __shfl_down(cnt, ofs);
    if (lane == 0) *mode = (cnt > 256) ? 1 : 0;  // 1 = fp32 inputs, 0 = bf16 inputs
}

// ---------------- x -> fp32 ----------------
__global__ void xconv_kernel(const void* x, float* __restrict__ x_f, const int* mode, int total) {
    int m = *mode;
    int tid = blockIdx.x*blockDim.x + threadIdx.x;
    if (tid < total) x_f[tid] = ldmix(x, tid, m);
}

// ---------------- weight prep ----------------
// smallf: [0..95] b_in, [96..383] bih, [384..671] bhh, [672..735] b_out,
//         [736..751] tau_w2, [752..767] tau_b1, [768] tau_b2
// WoutT hi/lo: [64 cols][96 k], WoutT[j][k] = w_out[k][j].
__global__ void prep_kernel(const void* w_in, const void* b_in, const void* tau_w1,
                            const void* tau_b1, const void* tau_w2, const void* tau_b2,
                            const void* wih, const void* whh, const void* bih, const void* bhh,
                            const void* w_out, const void* b_out,
                            __hip_bfloat16* W2T_hi, __hip_bfloat16* W2T_lo,
                            __hip_bfloat16* WinT_hi, __hip_bfloat16* WinT_lo,
                            __hip_bfloat16* WoutT_hi, __hip_bfloat16* WoutT_lo,
                            float* tau_w1_f, float* smallf, const int* mode) {
    int m = *mode;
    int tid = blockIdx.x*blockDim.x + threadIdx.x;
    if (tid < 384*192) {
        int c = tid / 192, k = tid % 192;
        int g = c / 96, jj = c % 96;
        float v = 0.f;
        if (k < 96) {
            if (g == 0)      v = ldmix(wih, (long)(jj)*96 + k, m);
            else if (g == 1) v = ldmix(wih, (long)(96+jj)*96 + k, m);
            else if (g == 2) v = ldmix(wih, (long)(192+jj)*96 + k, m);
        } else {
            int kk = k - 96;
            if (g == 0)      v = ldmix(whh, (long)(jj)*96 + kk, m);
            else if (g == 1) v = ldmix(whh, (long)(96+jj)*96 + kk, m);
            else if (g == 3) v = ldmix(whh, (long)(192+jj)*96 + kk, m);
        }
        split_bf16(v, &W2T_hi[tid], &W2T_lo[tid]);
    }
    if (tid < 96*128) {
        int j = tid >> 7, k = tid & 127;
        float v = ldmix(w_in, (long)k*96 + j, m);
        split_bf16(v, &WinT_hi[tid], &WinT_lo[tid]);
    }
    if (tid < 64*96) {
        int j = tid / 96, k = tid % 96;
        float v = ldmix(w_out, (long)k*OUTDIM + j, m);
        split_bf16(v, &WoutT_hi[tid], &WoutT_lo[tid]);
    }
    if (tid < INDIM*16)   tau_w1_f[tid] = ldmix(tau_w1, tid, m);
    if (tid < HID)    smallf[tid]       = ldmix(b_in, tid, m);
    if (tid < 3*HID){ smallf[96+tid]    = ldmix(bih, tid, m);
                      smallf[384+tid]   = ldmix(bhh, tid, m); }
    if (tid < OUTDIM) smallf[672+tid]   = ldmix(b_out, tid, m);
    if (tid < 16)   { smallf[736+tid]   = ldmix(tau_w2, tid, m);
                      smallf[752+tid]   = ldmix(tau_b1, tid, m); }
    if (tid == 0)     smallf[768]       = ldmix(tau_b2, 0, m);
}

// ---------------- h0 = relu(x @ w_in + b_in) via split-bf16 MFMA ----------------
__global__ void __launch_bounds__(512) h0_kernel(
        const float* __restrict__ x_f,
        const __hip_bfloat16* __restrict__ WinT_hi, const __hip_bfloat16* __restrict__ WinT_lo,
        const float* __restrict__ smallf, float* __restrict__ h, int N) {
    int row0 = blockIdx.x * BM;
    int jj0 = blockIdx.y * 16;

    __shared__ ushort_t Ah[128*136];
    __shared__ ushort_t Al[128*136];
    __shared__ ushort_t Wh[16*136];
    __shared__ ushort_t Wl[16*136];

    int tid = threadIdx.x;
    long limit = (long)N * INDIM;
    #pragma unroll
    for (int j = 0; j < 8; j++) {
        int e = (tid + j*512) * 4;
        int r = e >> 7, c = e & 127;
        long ge = (long)(row0 + r)*INDIM + c;
        floatx4 v = {0.f, 0.f, 0.f, 0.f};
        if (ge + 4 <= limit) v = *(const floatx4*)(x_f + ge);
        short4_t vh4, vl4;
        #pragma unroll
        for (int q = 0; q < 4; q++) {
            ushort_t hi, lo;
            split_us(v[q], &hi, &lo);
            vh4[q] = (short)hi; vl4[q] = (short)lo;
        }
        *(short4_t*)(&Ah[r*136 + c]) = vh4;
        *(short4_t*)(&Al[r*136 + c]) = vl4;
    }
    if (tid < 256) {
        int wrow = tid >> 4;
        int k = (tid & 15) * 8;
        long wi = (long)(jj0 + wrow)*INDIM + k;
        *(short8*)(&Wh[wrow*136 + k]) = *(const short8*)((const ushort_t*)WinT_hi + wi);
        *(short8*)(&Wl[wrow*136 + k]) = *(const short8*)((const ushort_t*)WinT_lo + wi);
    }
    __syncthreads();

    int lane = tid & 63;
    int w = tid >> 6;
    int m15 = lane & 15, quad = lane >> 4;
    floatx4 acc = {0.f, 0.f, 0.f, 0.f};
    int abase = (w*16 + m15)*136 + quad*8;
    #pragma unroll
    for (int ks = 0; ks < 4; ks++) {
        int k0 = ks*32;
        short8 ah = *(const short8*)(&Ah[abase + k0]);
        short8 al = *(const short8*)(&Al[abase + k0]);
        int wb = m15*136 + quad*8 + k0;
        short8 bh = *(const short8*)(&Wh[wb]);
        short8 bl = *(const short8*)(&Wl[wb]);
        acc = __builtin_amdgcn_mfma_f32_16x16x32_bf16(ah, bh, acc, 0, 0, 0);
        acc = __builtin_amdgcn_mfma_f32_16x16x32_bf16(al, bh, acc, 0, 0, 0);
        acc = __builtin_amdgcn_mfma_f32_16x16x32_bf16(ah, bl, acc, 0, 0, 0);
    }

    int jj = jj0 + m15;
    float b = smallf[jj];
    #pragma unroll
    for (int reg = 0; reg < 4; reg++) {
        int li = row0 + w*16 + quad*4 + reg;
        if (li < N) h[(long)li*HID + jj] = fmaxf(acc[reg] + b, 0.f);
    }
}

// ---------------- tau MLP -> steps (wave per node; no atomics) ----------------
__global__ void tau_kernel(const float* __restrict__ x_f, const float* __restrict__ tau_w1_f,
                           const float* __restrict__ smallf,
                           int* __restrict__ steps, int N) {
    int gtid = blockIdx.x*blockDim.x + threadIdx.x;
    int n = gtid >> 6;
    int lane = threadIdx.x & 63;
    if (n >= N) return;
    const float* xr = x_f + (size_t)n*INDIM;
    float x0 = xr[lane];
    float x1 = xr[64 + lane];
    const float* w0 = tau_w1_f + lane*16;
    const float* w1 = tau_w1_f + (64 + lane)*16;
    float acc[16];
    #pragma unroll
    for (int j = 0; j < 16; j++) acc[j] = x0*w0[j] + x1*w1[j];
    #pragma unroll
    for (int ofs = 32; ofs > 0; ofs >>= 1) {
        #pragma unroll
        for (int j = 0; j < 16; j++) acc[j] += __shfl_down(acc[j], ofs);
    }
    if (lane == 0) {
        float z = smallf[768];
        #pragma unroll
        for (int j = 0; j < 16; j++) z += fmaxf(acc[j] + smallf[752+j], 0.f) * smallf[736+j];
        float tau = fmaxf(z, 0.f) + log1pf(expf(-fabsf(z)));
        float inv = 1.0f / tau;
        int s;
        if (inv >= 5.0f) s = 5;
        else { s = (int)inv; if (s < 0) s = 0; if (s > 5) s = 5; }
        steps[n] = s;
    }
}

// ---------------- multi-block deterministic bucket+deg pipeline ----------------
__global__ void partial_kernel(const int* __restrict__ steps, const int* __restrict__ deg,
                               int N, int C, int* __restrict__ blksum) {
    __shared__ int red[256*8];
    int tid = threadIdx.x;
    int tg = blockIdx.x*256 + tid;
    int start = tg*C, end = min(start + C, N);
    if (end < start) end = start;
    int cnt[7] = {0,0,0,0,0,0,0};
    for (int i = start; i < end; i++) { cnt[steps[i]]++; cnt[6] += deg[i]; }
    #pragma unroll
    for (int k = 0; k < 7; k++) red[tid*8 + k] = cnt[k];
    __syncthreads();
    for (int ofs = 128; ofs > 0; ofs >>= 1) {
        if (tid < ofs) {
            #pragma unroll
            for (int k = 0; k < 7; k++) red[tid*8 + k] += red[(tid+ofs)*8 + k];
        }
        __syncthreads();
    }
    if (tid < 7) blksum[blockIdx.x*8 + tid] = red[tid];
}

__global__ void base_kernel(const int* __restrict__ blksum, int* __restrict__ bstart,
                            int* __restrict__ blkbase, int* __restrict__ off, int N) {
    __shared__ int tot[8];
    __shared__ int sb[8];
    int tid = threadIdx.x;
    if (tid < 7) {
        int s = 0;
        for (int b = 0; b < GP; b++) s += blksum[b*8 + tid];
        tot[tid] = s;
    }
    __syncthreads();
    if (tid == 0) {
        int run = 0;
        for (int ss = 5; ss >= 0; --ss) { sb[ss] = run; bstart[ss] = run; run += tot[ss]; }
        bstart[6] = run;          // = N
        off[N] = tot[6];          // = E
        sb[6] = 0;
    }
    __syncthreads();
    if (tid < 7) {
        int run = sb[tid];
        for (int b = 0; b < GP; b++) { blkbase[b*8 + tid] = run; run += blksum[b*8 + tid]; }
    }
}

__global__ void scatter_kernel(const int* __restrict__ steps, const int* __restrict__ deg,
                               const int* __restrict__ blkbase, int N, int C,
                               int* __restrict__ order, int* __restrict__ off) {
    __shared__ int buf[256];
    int tid = threadIdx.x;
    int b = blockIdx.x;
    int tg = b*256 + tid;
    int start = tg*C, end = min(start + C, N);
    if (end < start) end = start;
    int cnt[7] = {0,0,0,0,0,0,0};
    for (int i = start; i < end; i++) { cnt[steps[i]]++; cnt[6] += deg[i]; }
    int mybase[7];
    #pragma unroll
    for (int k = 0; k < 7; k++) {
        buf[tid] = cnt[k];
        __syncthreads();
        for (int ofs = 1; ofs < 256; ofs <<= 1) {
            int t = (tid >= ofs) ? buf[tid - ofs] : 0;
            __syncthreads();
            buf[tid] += t;
            __syncthreads();
        }
        mybase[k] = blkbase[b*8 + k] + buf[tid] - cnt[k];
        __syncthreads();
    }
    for (int i = start; i < end; i++) {
        int s = steps[i];
        order[mybase[s]++] = i;
        off[i] = mybase[6];
        mybase[6] += deg[i];
    }
}

// ---------------- pack h into order-space (bf16 hi/lo planes) ----------------
__global__ void pack_kernel(const float* __restrict__ h, const int* __restrict__ order,
                            __hip_bfloat16* __restrict__ hHi, __hip_bfloat16* __restrict__ hLo, int N) {
    int tid = blockIdx.x*blockDim.x + threadIdx.x;
    if (tid >= N*HID) return;
    int li = tid / HID, f = tid % HID;
    int n = order[li];
    float v = h[(size_t)n*HID + f];
    split_bf16(v, &hHi[tid], &hLo[tid]);
}

// ---------------- CSR build ----------------
__global__ void deg_kernel(const int* __restrict__ row, int* deg, int E) {
    int e = blockIdx.x*blockDim.x + threadIdx.x;
    if (e < E) atomicAdd(&deg[row[e]], 1);
}

__global__ void fill_kernel(const int* __restrict__ row, const int* __restrict__ col,
                            const int* __restrict__ off, int* cur, int* __restrict__ csr_col, int E) {
    int e = blockIdx.x*blockDim.x + threadIdx.x;
    if (e >= E) return;
    int r = row[e];
    int p = atomicAdd(&cur[r], 1);
    csr_col[off[r] + p] = col[e];
}

// ---------------- aggregation -> packed bf16 hi/lo (4-way unrolled gathers) ----------------
__global__ void agg_kernel(const float* __restrict__ h, const int* __restrict__ off,
                           const int* __restrict__ csr_col, const int* __restrict__ order,
                           const int* __restrict__ bstart, int t,
                           __hip_bfloat16* __restrict__ aggHi, __hip_bfloat16* __restrict__ aggLo) {
    int K = bstart[t];
    int total = K * HID;
    int stride = gridDim.x * blockDim.x;
    for (int idx = blockIdx.x*blockDim.x + threadIdx.x; idx < total; idx += stride) {
        int li = idx / HID, f = idx % HID;
        int i = order[li];
        float hv = h[(size_t)i*HID + f];
        int e0 = off[i], e1 = off[i+1];
        float acc = 0.f;
        int e = e0;
        for (; e + 4 <= e1; e += 4) {
            int c0 = csr_col[e],   c1 = csr_col[e+1];
            int c2 = csr_col[e+2], c3 = csr_col[e+3];
            float v0 = h[(size_t)c0*HID + f];
            float v1 = h[(size_t)c1*HID + f];
            float v2 = h[(size_t)c2*HID + f];
            float v3 = h[(size_t)c3*HID + f];
            acc += fabsf(hv - v0) + fabsf(hv - v1) + fabsf(hv - v2) + fabsf(hv - v3);
        }
        for (; e < e1; e++) {
            int c = csr_col[e];
            acc += fabsf(hv - h[(size_t)c*HID + f]);
        }
        split_bf16(acc, &aggHi[idx], &aggLo[idx]);
    }
}

// ---------------- GRU via split-bf16 MFMA GEMM, fused epilogue ----------------
__global__ void __launch_bounds__(512) gru_kernel(
        const __hip_bfloat16* __restrict__ aggHi, const __hip_bfloat16* __restrict__ aggLo,
        const __hip_bfloat16* __restrict__ hHi,   const __hip_bfloat16* __restrict__ hLo,
        const __hip_bfloat16* __restrict__ WHi,   const __hip_bfloat16* __restrict__ WLo,
        const float* __restrict__ smallf, const int* __restrict__ bstart, int t,
        float* __restrict__ hnewP, int N) {
    int K = bstart[t];
    int row0 = blockIdx.x * BM;
    if (row0 >= K) return;
    int jj0 = blockIdx.y * 16;

    __shared__ ushort_t Ah[128*200];
    __shared__ ushort_t Al[128*200];
    __shared__ ushort_t Wh[64*200];
    __shared__ ushort_t Wl[64*200];

    int tid = threadIdx.x;
    const ushort_t* aH = (const ushort_t*)aggHi;
    const ushort_t* aL = (const ushort_t*)aggLo;
    const ushort_t* hH = (const ushort_t*)hHi;
    const ushort_t* hL = (const ushort_t*)hLo;
    const ushort_t* wH = (const ushort_t*)WHi;
    const ushort_t* wL = (const ushort_t*)WLo;
    long limit = (long)N * HID;
    #pragma unroll
    for (int j = 0; j < 3; j++) {
        int e = (tid + j*512) * 8;
        {
            int r = e / 96, c = e % 96;
            long ge = (long)(row0 + r)*96 + c;
            short8 vah = {0,0,0,0,0,0,0,0}, val = vah, vhh = vah, vhl = vah;
            if (ge + 8 <= limit) {
                vah = *(const short8*)(aH + ge);
                val = *(const short8*)(aL + ge);
                vhh = *(const short8*)(hH + ge);
                vhl = *(const short8*)(hL + ge);
            }
            *(short8*)(&Ah[r*200 + c])      = vah;
            *(short8*)(&Al[r*200 + c])      = val;
            *(short8*)(&Ah[r*200 + 96 + c]) = vhh;
            *(short8*)(&Al[r*200 + 96 + c]) = vhl;
        }
        {
            int wrow = e / 192, k = e % 192;
            int g = wrow >> 4, cc = wrow & 15;
            long wi = (long)(g*96 + jj0 + cc)*192 + k;
            *(short8*)(&Wh[wrow*200 + k]) = *(const short8*)(wH + wi);
            *(short8*)(&Wl[wrow*200 + k]) = *(const short8*)(wL + wi);
        }
    }
    __syncthreads();

    int lane = tid & 63;
    int w = tid >> 6;
    int m15 = lane & 15, quad = lane >> 4;
    floatx4 acc[4];
    #pragma unroll
    for (int g = 0; g < 4; g++) acc[g] = (floatx4){0.f, 0.f, 0.f, 0.f};

    int abase = (w*16 + m15)*200 + quad*8;
    #pragma unroll
    for (int ks = 0; ks < 6; ks++) {
        int k0 = ks*32;
        short8 ah = *(const short8*)(&Ah[abase + k0]);
        short8 al = *(const short8*)(&Al[abase + k0]);
        #pragma unroll
        for (int g = 0; g < 4; g++) {
            int wb = (g*16 + m15)*200 + quad*8 + k0;
            short8 bh = *(const short8*)(&Wh[wb]);
            short8 bl = *(const short8*)(&Wl[wb]);
            acc[g] = __builtin_amdgcn_mfma_f32_16x16x32_bf16(ah, bh, acc[g], 0, 0, 0);
            acc[g] = __builtin_amdgcn_mfma_f32_16x16x32_bf16(al, bh, acc[g], 0, 0, 0);
            acc[g] = __builtin_amdgcn_mfma_f32_16x16x32_bf16(ah, bl, acc[g], 0, 0, 0);
        }
    }

    int jj = jj0 + m15;
    float bir = smallf[96+jj],  biz = smallf[192+jj], bin = smallf[288+jj];
    float bhr = smallf[384+jj], bhz = smallf[480+jj], bhn = smallf[576+jj];
    #pragma unroll
    for (int reg = 0; reg < 4; reg++) {
        int li = row0 + w*16 + quad*4 + reg;
        if (li < K) {
            float rp = acc[0][reg] + bir + bhr;
            float zp = acc[1][reg] + biz + bhz;
            float ip = acc[2][reg] + bin;
            float hn = acc[3][reg] + bhn;
            float r  = 1.f/(1.f + expf(-rp));
            float z  = 1.f/(1.f + expf(-zp));
            float nn = tanhf(ip + r*hn);
            long idx = (long)li*HID + jj;
            float hold = __bfloat162float(hHi[idx]) + __bfloat162float(hLo[idx]);
            hnewP[idx] = (1.f - z)*nn + z*hold;
        }
    }
}

// ---------------- commit: active prefix -> h (node layout) + hi/lo planes ----------------
__global__ void commit_kernel(float* __restrict__ h,
                              __hip_bfloat16* __restrict__ hHi, __hip_bfloat16* __restrict__ hLo,
                              const float* __restrict__ hnewP,
                              const int* __restrict__ order, const int* __restrict__ bstart, int t) {
    int K = bstart[t];
    int total = K * HID;
    int stride = gridDim.x * blockDim.x;
    for (int idx = blockIdx.x*blockDim.x + threadIdx.x; idx < total; idx += stride) {
        int li = idx / HID, f = idx % HID;
        int i = order[li];
        float v = hnewP[idx];
        h[(size_t)i*HID + f] = v;
        split_bf16(v, &hHi[idx], &hLo[idx]);
    }
}

// ---------------- out = h @ w_out + b_out via split-bf16 MFMA ----------------
// A = h (N x 96) split in-register; B = WoutT^T; 128 rows x 16-col stripe (grid.y=4).
__global__ void __launch_bounds__(512) out_kernel(
        const float* __restrict__ h,
        const __hip_bfloat16* __restrict__ WoutT_hi, const __hip_bfloat16* __restrict__ WoutT_lo,
        const float* __restrict__ smallf, void* out, const int* mode, int N) {
    int row0 = blockIdx.x * BM;
    int jj0 = blockIdx.y * 16;

    __shared__ ushort_t Ah[128*104];
    __shared__ ushort_t Al[128*104];
    __shared__ ushort_t Wh[16*104];
    __shared__ ushort_t Wl[16*104];

    int tid = threadIdx.x;
    long limit = (long)N * HID;
    #pragma unroll
    for (int j = 0; j < 6; j++) {
        int e = (tid + j*512) * 4;        // 12288 floats per tile
        int r = e / 96, c = e % 96;
        long ge = (long)(row0 + r)*HID + c;
        floatx4 v = {0.f, 0.f, 0.f, 0.f};
        if (ge + 4 <= limit) v = *(const floatx4*)(h + ge);
        short4_t vh4, vl4;
        #pragma unroll
        for (int q = 0; q < 4; q++) {
            ushort_t hi, lo;
            split_us(v[q], &hi, &lo);
            vh4[q] = (short)hi; vl4[q] = (short)lo;
        }
        *(short4_t*)(&Ah[r*104 + c]) = vh4;
        *(short4_t*)(&Al[r*104 + c]) = vl4;
    }
    if (tid < 192) {
        int wrow = tid / 12;
        int k = (tid % 12) * 8;
        long wi = (long)(jj0 + wrow)*HID + k;
        *(short8*)(&Wh[wrow*104 + k]) = *(const short8*)((const ushort_t*)WoutT_hi + wi);
        *(short8*)(&Wl[wrow*104 + k]) = *(const short8*)((const ushort_t*)WoutT_lo + wi);
    }
    __syncthreads();

    int lane = tid & 63;
    int w = tid >> 6;
    int m15 = lane & 15, quad = lane >> 4;
    floatx4 acc = {0.f, 0.f, 0.f, 0.f};
    int abase = (w*16 + m15)*104 + quad*8;
    #pragma unroll
    for (int ks = 0; ks < 3; ks++) {
        int k0 = ks*32;
        short8 ah = *(const short8*)(&Ah[abase + k0]);
        short8 al = *(const short8*)(&Al[abase + k0]);
        int wb = m15*104 + quad*8 + k0;
        short8 bh = *(const short8*)(&Wh[wb]);
        short8 bl = *(const short8*)(&Wl[wb]);
        acc = __builtin_amdgcn_mfma_f32_16x16x32_bf16(ah, bh, acc, 0, 0, 0);
        acc = __builtin_amdgcn_mfma_f32_16x16x32_bf16(al, bh, acc, 0, 0, 0);
        acc = __builtin_amdgcn_mfma_f32_16x16x32_bf16(ah, bl, acc, 0, 0, 0);
    }

    int jj = jj0 + m15;
    float b = smallf[672+jj];
    int m = *mode;
    #pragma unroll
    for (int reg = 0; reg < 4; reg++) {
        int li = row0 + w*16 + quad*4 + reg;
        if (li < N) {
            float v = acc[reg] + b;
            long oi = (long)li*OUTDIM + jj;
            if (m) ((float*)out)[oi] = v;
            else   ((__hip_bfloat16*)out)[oi] = __float2bfloat16(v);
        }
    }
}

extern "C" void kernel_launch(void* const* d_in, const int* in_sizes, int n_in,
                              void* d_out, int out_size, void* d_ws, size_t ws_size,
                              hipStream_t stream) {
    const void* x      = d_in[0];
    const int*  ei     = (const int*)d_in[1];
    const void* w_in   = d_in[2],  *b_in   = d_in[3];
    const void* tau_w1 = d_in[4],  *tau_b1 = d_in[5];
    const void* tau_w2 = d_in[6],  *tau_b2 = d_in[7];
    const void* wih    = d_in[8],  *whh    = d_in[9];
    const void* bih    = d_in[10], *bhh    = d_in[11];
    const void* w_out  = d_in[12], *b_out  = d_in[13];

    int N = in_sizes[0] / INDIM;
    int E = in_sizes[1] / 2;
    const int* row = ei;
    const int* col = ei + E;

    char* ws = (char*)d_ws;
    size_t o = 0;
    auto take = [&](size_t bytes) -> char* {
        char* p = ws + o;
        o = (o + bytes + 255) & ~(size_t)255;
        return p;
    };
    float* x_f      = (float*)take((size_t)N*INDIM*4);   // reused as hnewP after h0/tau
    float* hnewP    = x_f;
    float* h        = (float*)take((size_t)N*HID*4);
    __hip_bfloat16* hHi   = (__hip_bfloat16*)take((size_t)N*HID*2);
    __hip_bfloat16* hLo   = (__hip_bfloat16*)take((size_t)N*HID*2);
    __hip_bfloat16* aggHi = (__hip_bfloat16*)take((size_t)N*HID*2);
    __hip_bfloat16* aggLo = (__hip_bfloat16*)take((size_t)N*HID*2);
    __hip_bfloat16* W2T_hi= (__hip_bfloat16*)take((size_t)384*192*2);
    __hip_bfloat16* W2T_lo= (__hip_bfloat16*)take((size_t)384*192*2);
    __hip_bfloat16* WinT_hi=(__hip_bfloat16*)take((size_t)96*128*2);
    __hip_bfloat16* WinT_lo=(__hip_bfloat16*)take((size_t)96*128*2);
    __hip_bfloat16* WoutT_hi=(__hip_bfloat16*)take((size_t)64*96*2);
    __hip_bfloat16* WoutT_lo=(__hip_bfloat16*)take((size_t)64*96*2);
    float* tau_w1_f = (float*)take((size_t)INDIM*16*4);
    float* smallf   = (float*)take(1024*4);
    int*   off      = (int*)take((size_t)(N+1)*4);
    int*   csr_col  = (int*)take((size_t)E*4);
    int*   order    = (int*)take((size_t)N*4);
    int*   steps    = (int*)take((size_t)N*4);
    int*   bstart   = (int*)take(64);
    int*   mode     = (int*)take(64);
    int*   blksum   = (int*)take((size_t)GP*8*4);
    int*   blkbase  = (int*)take((size_t)GP*8*4);
    char*  zbase    = ws + o;
    int*   deg      = (int*)take((size_t)N*4);
    int*   cur      = (int*)take((size_t)N*4);
    size_t zbytes   = (size_t)((ws + o) - zbase);

    hipMemsetAsync(zbase, 0, zbytes, stream);
    sniff_kernel<<<1, 64, 0, stream>>>((const unsigned int*)x, mode);

    xconv_kernel<<<(N*INDIM + 255)/256, 256, 0, stream>>>(x, x_f, mode, N*INDIM);
    prep_kernel<<<(384*192 + 255)/256, 256, 0, stream>>>(
        w_in, b_in, tau_w1, tau_b1, tau_w2, tau_b2, wih, whh, bih, bhh, w_out, b_out,
        W2T_hi, W2T_lo, WinT_hi, WinT_lo, WoutT_hi, WoutT_lo, tau_w1_f, smallf, mode);

    dim3 hgrid((N + BM - 1)/BM, 6);
    h0_kernel<<<hgrid, 512, 0, stream>>>(x_f, WinT_hi, WinT_lo, smallf, h, N);
    tau_kernel<<<((size_t)N*64 + 255)/256, 256, 0, stream>>>(x_f, tau_w1_f, smallf, steps, N);
    deg_kernel<<<(E + 255)/256, 256, 0, stream>>>(row, deg, E);

    int C = (N + GP*256 - 1) / (GP*256);
    partial_kernel<<<GP, 256, 0, stream>>>(steps, deg, N, C, blksum);
    base_kernel<<<1, 64, 0, stream>>>(blksum, bstart, blkbase, off, N);
    scatter_kernel<<<GP, 256, 0, stream>>>(steps, deg, blkbase, N, C, order, off);

    pack_kernel<<<(N*HID + 255)/256, 256, 0, stream>>>(h, order, hHi, hLo, N);
    fill_kernel<<<(E + 255)/256, 256, 0, stream>>>(row, col, off, cur, csr_col, E);

    dim3 ggrid((N + BM - 1)/BM, 6);
    for (int t = 0; t < 5; t++) {
        agg_kernel<<<4096, 256, 0, stream>>>(h, off, csr_col, order, bstart, t, aggHi, aggLo);
        gru_kernel<<<ggrid, 512, 0, stream>>>(aggHi, aggLo, hHi, hLo, W2T_hi, W2T_lo,
                                              smallf, bstart, t, hnewP, N);
        commit_kernel<<<2048, 256, 0, stream>>>(h, hHi, hLo, hnewP, order, bstart, t);
    }

    dim3 ogrid((N + BM - 1)/BM, 4);
    out_kernel<<<ogrid, 512, 0, stream>>>(h, WoutT_hi, WoutT_lo, smallf, d_out, mode, N);
}

// Round 12
// 484.434 us; speedup vs baseline: 4.5515x; 1.1501x over previous
//
#include <hip/hip_runtime.h>
#include <hip/hip_bf16.h>

#define HID 96
#define INDIM 128
#define OUTDIM 64
#define BM 128
#define GP 128   // partial/scatter grid blocks (fixed mapping)

typedef __attribute__((ext_vector_type(8))) _Float16 half8;
typedef __attribute__((ext_vector_type(4))) _Float16 half4;
typedef __attribute__((ext_vector_type(4))) float floatx4;

__device__ __forceinline__ float ldmix(const void* p, long i, int mode) {
    return mode ? ((const float*)p)[i]
                : __bfloat162float(((const __hip_bfloat16*)p)[i]);
}

// ---------------- dtype sniffer (parallel: 64 lanes x 64 words) ----------------
__global__ void sniff_kernel(const unsigned int* xw, int* mode) {
    int lane = threadIdx.x & 63;
    int cnt = 0;
    for (int i = lane; i < 4096; i += 64) {
        unsigned int low = xw[i] & 0xFFFFu;
        unsigned int e = (low >> 7) & 0xFFu;
        if (e >= 0xC0u) cnt++;
    }
    #pragma unroll
    for (int ofs = 32; ofs > 0; ofs >>= 1) cnt += __shfl_down(cnt, ofs);
    if (lane == 0) *mode = (cnt > 256) ? 1 : 0;  // 1 = fp32 inputs, 0 = bf16 inputs
}

// ---------------- x -> fp32 ----------------
__global__ void xconv_kernel(const void* x, float* __restrict__ x_f, const int* mode, int total) {
    int m = *mode;
    int tid = blockIdx.x*blockDim.x + threadIdx.x;
    if (tid < total) x_f[tid] = ldmix(x, tid, m);
}

// ---------------- weight prep (fp16 planes) ----------------
// smallf: [0..95] b_in, [96..383] bih, [384..671] bhh, [672..735] b_out,
//         [736..751] tau_w2, [752..767] tau_b1, [768] tau_b2
// W2F: [384 cols][192 k]. col c = g*96+jj, gates g: 0=r,1=z,2=inn,3=hn.
// WinF: [96 cols][128 k]; WoutF: [64 cols][96 k].
__global__ void prep_kernel(const void* w_in, const void* b_in, const void* tau_w1,
                            const void* tau_b1, const void* tau_w2, const void* tau_b2,
                            const void* wih, const void* whh, const void* bih, const void* bhh,
                            const void* w_out, const void* b_out,
                            _Float16* W2F, _Float16* WinF, _Float16* WoutF,
                            float* tau_w1_f, float* smallf, const int* mode) {
    int m = *mode;
    int tid = blockIdx.x*blockDim.x + threadIdx.x;
    if (tid < 384*192) {
        int c = tid / 192, k = tid % 192;
        int g = c / 96, jj = c % 96;
        float v = 0.f;
        if (k < 96) {
            if (g == 0)      v = ldmix(wih, (long)(jj)*96 + k, m);
            else if (g == 1) v = ldmix(wih, (long)(96+jj)*96 + k, m);
            else if (g == 2) v = ldmix(wih, (long)(192+jj)*96 + k, m);
        } else {
            int kk = k - 96;
            if (g == 0)      v = ldmix(whh, (long)(jj)*96 + kk, m);
            else if (g == 1) v = ldmix(whh, (long)(96+jj)*96 + kk, m);
            else if (g == 3) v = ldmix(whh, (long)(192+jj)*96 + kk, m);
        }
        W2F[tid] = (_Float16)v;
    }
    if (tid < 96*128) {
        int j = tid >> 7, k = tid & 127;
        WinF[tid] = (_Float16)ldmix(w_in, (long)k*96 + j, m);
    }
    if (tid < 64*96) {
        int j = tid / 96, k = tid % 96;
        WoutF[tid] = (_Float16)ldmix(w_out, (long)k*OUTDIM + j, m);
    }
    if (tid < INDIM*16)   tau_w1_f[tid] = ldmix(tau_w1, tid, m);
    if (tid < HID)    smallf[tid]       = ldmix(b_in, tid, m);
    if (tid < 3*HID){ smallf[96+tid]    = ldmix(bih, tid, m);
                      smallf[384+tid]   = ldmix(bhh, tid, m); }
    if (tid < OUTDIM) smallf[672+tid]   = ldmix(b_out, tid, m);
    if (tid < 16)   { smallf[736+tid]   = ldmix(tau_w2, tid, m);
                      smallf[752+tid]   = ldmix(tau_b1, tid, m); }
    if (tid == 0)     smallf[768]       = ldmix(tau_b2, 0, m);
}

// ---------------- h0 = relu(x @ w_in + b_in) via fp16 MFMA -> hN (node layout, fp16) ----------------
__global__ void __launch_bounds__(512) h0_kernel(
        const float* __restrict__ x_f, const _Float16* __restrict__ WinF,
        const float* __restrict__ smallf, _Float16* __restrict__ hN, int N) {
    int row0 = blockIdx.x * BM;
    int jj0 = blockIdx.y * 16;

    __shared__ _Float16 Ah[128*136];
    __shared__ _Float16 Wh[16*136];

    int tid = threadIdx.x;
    long limit = (long)N * INDIM;
    #pragma unroll
    for (int j = 0; j < 8; j++) {
        int e = (tid + j*512) * 4;
        int r = e >> 7, c = e & 127;
        long ge = (long)(row0 + r)*INDIM + c;
        floatx4 v = {0.f, 0.f, 0.f, 0.f};
        if (ge + 4 <= limit) v = *(const floatx4*)(x_f + ge);
        half4 vh;
        #pragma unroll
        for (int q = 0; q < 4; q++) vh[q] = (_Float16)v[q];
        *(half4*)(&Ah[r*136 + c]) = vh;
    }
    if (tid < 256) {
        int wrow = tid >> 4;
        int k = (tid & 15) * 8;
        *(half8*)(&Wh[wrow*136 + k]) = *(const half8*)(WinF + (long)(jj0 + wrow)*INDIM + k);
    }
    __syncthreads();

    int lane = tid & 63;
    int w = tid >> 6;
    int m15 = lane & 15, quad = lane >> 4;
    floatx4 acc = {0.f, 0.f, 0.f, 0.f};
    int abase = (w*16 + m15)*136 + quad*8;
    #pragma unroll
    for (int ks = 0; ks < 4; ks++) {
        int k0 = ks*32;
        half8 a = *(const half8*)(&Ah[abase + k0]);
        half8 b = *(const half8*)(&Wh[m15*136 + quad*8 + k0]);
        acc = __builtin_amdgcn_mfma_f32_16x16x32_f16(a, b, acc, 0, 0, 0);
    }

    int jj = jj0 + m15;
    float b = smallf[jj];
    #pragma unroll
    for (int reg = 0; reg < 4; reg++) {
        int li = row0 + w*16 + quad*4 + reg;
        if (li < N) hN[(long)li*HID + jj] = (_Float16)fmaxf(acc[reg] + b, 0.f);
    }
}

// ---------------- tau MLP -> steps (fp32, wave per node) ----------------
__global__ void tau_kernel(const float* __restrict__ x_f, const float* __restrict__ tau_w1_f,
                           const float* __restrict__ smallf,
                           int* __restrict__ steps, int N) {
    int gtid = blockIdx.x*blockDim.x + threadIdx.x;
    int n = gtid >> 6;
    int lane = threadIdx.x & 63;
    if (n >= N) return;
    const float* xr = x_f + (size_t)n*INDIM;
    float x0 = xr[lane];
    float x1 = xr[64 + lane];
    const float* w0 = tau_w1_f + lane*16;
    const float* w1 = tau_w1_f + (64 + lane)*16;
    float acc[16];
    #pragma unroll
    for (int j = 0; j < 16; j++) acc[j] = x0*w0[j] + x1*w1[j];
    #pragma unroll
    for (int ofs = 32; ofs > 0; ofs >>= 1) {
        #pragma unroll
        for (int j = 0; j < 16; j++) acc[j] += __shfl_down(acc[j], ofs);
    }
    if (lane == 0) {
        float z = smallf[768];
        #pragma unroll
        for (int j = 0; j < 16; j++) z += fmaxf(acc[j] + smallf[752+j], 0.f) * smallf[736+j];
        float tau = fmaxf(z, 0.f) + log1pf(expf(-fabsf(z)));
        float inv = 1.0f / tau;
        int s;
        if (inv >= 5.0f) s = 5;
        else { s = (int)inv; if (s < 0) s = 0; if (s > 5) s = 5; }
        steps[n] = s;
    }
}

// ---------------- multi-block deterministic bucket+deg pipeline ----------------
__global__ void partial_kernel(const int* __restrict__ steps, const int* __restrict__ deg,
                               int N, int C, int* __restrict__ blksum) {
    __shared__ int red[256*8];
    int tid = threadIdx.x;
    int tg = blockIdx.x*256 + tid;
    int start = tg*C, end = min(start + C, N);
    if (end < start) end = start;
    int cnt[7] = {0,0,0,0,0,0,0};
    for (int i = start; i < end; i++) { cnt[steps[i]]++; cnt[6] += deg[i]; }
    #pragma unroll
    for (int k = 0; k < 7; k++) red[tid*8 + k] = cnt[k];
    __syncthreads();
    for (int ofs = 128; ofs > 0; ofs >>= 1) {
        if (tid < ofs) {
            #pragma unroll
            for (int k = 0; k < 7; k++) red[tid*8 + k] += red[(tid+ofs)*8 + k];
        }
        __syncthreads();
    }
    if (tid < 7) blksum[blockIdx.x*8 + tid] = red[tid];
}

__global__ void base_kernel(const int* __restrict__ blksum, int* __restrict__ bstart,
                            int* __restrict__ blkbase, int* __restrict__ off, int N) {
    __shared__ int tot[8];
    __shared__ int sb[8];
    int tid = threadIdx.x;
    if (tid < 7) {
        int s = 0;
        for (int b = 0; b < GP; b++) s += blksum[b*8 + tid];
        tot[tid] = s;
    }
    __syncthreads();
    if (tid == 0) {
        int run = 0;
        for (int ss = 5; ss >= 0; --ss) { sb[ss] = run; bstart[ss] = run; run += tot[ss]; }
        bstart[6] = run;          // = N
        off[N] = tot[6];          // = E
        sb[6] = 0;
    }
    __syncthreads();
    if (tid < 7) {
        int run = sb[tid];
        for (int b = 0; b < GP; b++) { blkbase[b*8 + tid] = run; run += blksum[b*8 + tid]; }
    }
}

__global__ void scatter_kernel(const int* __restrict__ steps, const int* __restrict__ deg,
                               const int* __restrict__ blkbase, int N, int C,
                               int* __restrict__ order, int* __restrict__ off) {
    __shared__ int buf[256];
    int tid = threadIdx.x;
    int b = blockIdx.x;
    int tg = b*256 + tid;
    int start = tg*C, end = min(start + C, N);
    if (end < start) end = start;
    int cnt[7] = {0,0,0,0,0,0,0};
    for (int i = start; i < end; i++) { cnt[steps[i]]++; cnt[6] += deg[i]; }
    int mybase[7];
    #pragma unroll
    for (int k = 0; k < 7; k++) {
        buf[tid] = cnt[k];
        __syncthreads();
        for (int ofs = 1; ofs < 256; ofs <<= 1) {
            int t = (tid >= ofs) ? buf[tid - ofs] : 0;
            __syncthreads();
            buf[tid] += t;
            __syncthreads();
        }
        mybase[k] = blkbase[b*8 + k] + buf[tid] - cnt[k];
        __syncthreads();
    }
    for (int i = start; i < end; i++) {
        int s = steps[i];
        order[mybase[s]++] = i;
        off[i] = mybase[6];
        mybase[6] += deg[i];
    }
}

// ---------------- pack hN into order-space fp16 plane ----------------
__global__ void pack_kernel(const _Float16* __restrict__ hN, const int* __restrict__ order,
                            _Float16* __restrict__ hF, int N) {
    int tid = blockIdx.x*blockDim.x + threadIdx.x;
    if (tid >= N*HID) return;
    int li = tid / HID, f = tid % HID;
    int n = order[li];
    hF[tid] = hN[(size_t)n*HID + f];
}

// ---------------- CSR build ----------------
__global__ void deg_kernel(const int* __restrict__ row, int* deg, int E) {
    int e = blockIdx.x*blockDim.x + threadIdx.x;
    if (e < E) atomicAdd(&deg[row[e]], 1);
}

__global__ void fill_kernel(const int* __restrict__ row, const int* __restrict__ col,
                            const int* __restrict__ off, int* cur, int* __restrict__ csr_col, int E) {
    int e = blockIdx.x*blockDim.x + threadIdx.x;
    if (e >= E) return;
    int r = row[e];
    int p = atomicAdd(&cur[r], 1);
    csr_col[off[r] + p] = col[e];
}

// ---------------- aggregation: fp16 gathers, fp32 accumulate -> packed fp16 aggF ----------------
__global__ void agg_kernel(const _Float16* __restrict__ hN, const int* __restrict__ off,
                           const int* __restrict__ csr_col, const int* __restrict__ order,
                           const int* __restrict__ bstart, int t, _Float16* __restrict__ aggF) {
    int K = bstart[t];
    int total = K * HID;
    int stride = gridDim.x * blockDim.x;
    for (int idx = blockIdx.x*blockDim.x + threadIdx.x; idx < total; idx += stride) {
        int li = idx / HID, f = idx % HID;
        int i = order[li];
        float hv = (float)hN[(size_t)i*HID + f];
        int e0 = off[i], e1 = off[i+1];
        float acc = 0.f;
        int e = e0;
        for (; e + 4 <= e1; e += 4) {
            int c0 = csr_col[e],   c1 = csr_col[e+1];
            int c2 = csr_col[e+2], c3 = csr_col[e+3];
            float v0 = (float)hN[(size_t)c0*HID + f];
            float v1 = (float)hN[(size_t)c1*HID + f];
            float v2 = (float)hN[(size_t)c2*HID + f];
            float v3 = (float)hN[(size_t)c3*HID + f];
            acc += fabsf(hv - v0) + fabsf(hv - v1) + fabsf(hv - v2) + fabsf(hv - v3);
        }
        for (; e < e1; e++) {
            int c = csr_col[e];
            acc += fabsf(hv - (float)hN[(size_t)c*HID + f]);
        }
        aggF[idx] = (_Float16)acc;
    }
}

// ---------------- GRU via fp16 MFMA GEMM, fused epilogue ----------------
// A = [aggF | hF] (K x 192) packed fp16; B = W2F^T (192 x 384). 128 rows x 16-jj stripe.
__global__ void __launch_bounds__(512) gru_kernel(
        const _Float16* __restrict__ aggF, const _Float16* __restrict__ hF,
        const _Float16* __restrict__ W2F,
        const float* __restrict__ smallf, const int* __restrict__ bstart, int t,
        float* __restrict__ hnewP, int N) {
    int K = bstart[t];
    int row0 = blockIdx.x * BM;
    if (row0 >= K) return;
    int jj0 = blockIdx.y * 16;

    __shared__ _Float16 Ah[128*200];   // [agg|h] 128 x (192+8)
    __shared__ _Float16 Wh[64*200];    // 64 cols x (192+8)

    int tid = threadIdx.x;
    long limit = (long)N * HID;
    #pragma unroll
    for (int j = 0; j < 3; j++) {
        int e = (tid + j*512) * 8;
        {
            int r = e / 96, c = e % 96;
            long ge = (long)(row0 + r)*96 + c;
            half8 va = {0,0,0,0,0,0,0,0}, vh = va;
            if (ge + 8 <= limit) {
                va = *(const half8*)(aggF + ge);
                vh = *(const half8*)(hF + ge);
            }
            *(half8*)(&Ah[r*200 + c])      = va;
            *(half8*)(&Ah[r*200 + 96 + c]) = vh;
        }
        {
            int wrow = e / 192, k = e % 192;
            int g = wrow >> 4, cc = wrow & 15;
            *(half8*)(&Wh[wrow*200 + k]) = *(const half8*)(W2F + (long)(g*96 + jj0 + cc)*192 + k);
        }
    }
    __syncthreads();

    int lane = tid & 63;
    int w = tid >> 6;
    int m15 = lane & 15, quad = lane >> 4;
    floatx4 acc[4];
    #pragma unroll
    for (int g = 0; g < 4; g++) acc[g] = (floatx4){0.f, 0.f, 0.f, 0.f};

    int abase = (w*16 + m15)*200 + quad*8;
    #pragma unroll
    for (int ks = 0; ks < 6; ks++) {
        int k0 = ks*32;
        half8 a = *(const half8*)(&Ah[abase + k0]);
        #pragma unroll
        for (int g = 0; g < 4; g++) {
            half8 b = *(const half8*)(&Wh[(g*16 + m15)*200 + quad*8 + k0]);
            acc[g] = __builtin_amdgcn_mfma_f32_16x16x32_f16(a, b, acc[g], 0, 0, 0);
        }
    }

    int jj = jj0 + m15;
    float bir = smallf[96+jj],  biz = smallf[192+jj], bin = smallf[288+jj];
    float bhr = smallf[384+jj], bhz = smallf[480+jj], bhn = smallf[576+jj];
    #pragma unroll
    for (int reg = 0; reg < 4; reg++) {
        int li = row0 + w*16 + quad*4 + reg;
        if (li < K) {
            float rp = acc[0][reg] + bir + bhr;
            float zp = acc[1][reg] + biz + bhz;
            float ip = acc[2][reg] + bin;
            float hn = acc[3][reg] + bhn;
            float r  = 1.f/(1.f + expf(-rp));
            float z  = 1.f/(1.f + expf(-zp));
            float nn = tanhf(ip + r*hn);
            long idx = (long)li*HID + jj;
            float hold = (float)hF[idx];
            hnewP[idx] = (1.f - z)*nn + z*hold;
        }
    }
}

// ---------------- commit: active prefix -> hN (node) + hF (packed) ----------------
__global__ void commit_kernel(_Float16* __restrict__ hN, _Float16* __restrict__ hF,
                              const float* __restrict__ hnewP,
                              const int* __restrict__ order, const int* __restrict__ bstart, int t) {
    int K = bstart[t];
    int total = K * HID;
    int stride = gridDim.x * blockDim.x;
    for (int idx = blockIdx.x*blockDim.x + threadIdx.x; idx < total; idx += stride) {
        int li = idx / HID, f = idx % HID;
        int i = order[li];
        _Float16 v = (_Float16)hnewP[idx];
        hN[(size_t)i*HID + f] = v;
        hF[idx] = v;
    }
}

// ---------------- out = h @ w_out + b_out via fp16 MFMA ----------------
__global__ void __launch_bounds__(512) out_kernel(
        const _Float16* __restrict__ hN, const _Float16* __restrict__ WoutF,
        const float* __restrict__ smallf, void* out, const int* mode, int N) {
    int row0 = blockIdx.x * BM;
    int jj0 = blockIdx.y * 16;

    __shared__ _Float16 Ah[128*104];
    __shared__ _Float16 Wh[16*104];

    int tid = threadIdx.x;
    long limit = (long)N * HID;
    #pragma unroll
    for (int j = 0; j < 3; j++) {
        int e = (tid + j*512) * 8;        // 12288 elems per tile
        int r = e / 96, c = e % 96;
        long ge = (long)(row0 + r)*HID + c;
        half8 v = {0,0,0,0,0,0,0,0};
        if (ge + 8 <= limit) v = *(const half8*)(hN + ge);
        *(half8*)(&Ah[r*104 + c]) = v;
    }
    if (tid < 192) {
        int wrow = tid / 12;
        int k = (tid % 12) * 8;
        *(half8*)(&Wh[wrow*104 + k]) = *(const half8*)(WoutF + (long)(jj0 + wrow)*HID + k);
    }
    __syncthreads();

    int lane = tid & 63;
    int w = tid >> 6;
    int m15 = lane & 15, quad = lane >> 4;
    floatx4 acc = {0.f, 0.f, 0.f, 0.f};
    int abase = (w*16 + m15)*104 + quad*8;
    #pragma unroll
    for (int ks = 0; ks < 3; ks++) {
        int k0 = ks*32;
        half8 a = *(const half8*)(&Ah[abase + k0]);
        half8 b = *(const half8*)(&Wh[m15*104 + quad*8 + k0]);
        acc = __builtin_amdgcn_mfma_f32_16x16x32_f16(a, b, acc, 0, 0, 0);
    }

    int jj = jj0 + m15;
    float b = smallf[672+jj];
    int m = *mode;
    #pragma unroll
    for (int reg = 0; reg < 4; reg++) {
        int li = row0 + w*16 + quad*4 + reg;
        if (li < N) {
            float v = acc[reg] + b;
            long oi = (long)li*OUTDIM + jj;
            if (m) ((float*)out)[oi] = v;
            else   ((__hip_bfloat16*)out)[oi] = __float2bfloat16(v);
        }
    }
}

extern "C" void kernel_launch(void* const* d_in, const int* in_sizes, int n_in,
                              void* d_out, int out_size, void* d_ws, size_t ws_size,
                              hipStream_t stream) {
    const void* x      = d_in[0];
    const int*  ei     = (const int*)d_in[1];
    const void* w_in   = d_in[2],  *b_in   = d_in[3];
    const void* tau_w1 = d_in[4],  *tau_b1 = d_in[5];
    const void* tau_w2 = d_in[6],  *tau_b2 = d_in[7];
    const void* wih    = d_in[8],  *whh    = d_in[9];
    const void* bih    = d_in[10], *bhh    = d_in[11];
    const void* w_out  = d_in[12], *b_out  = d_in[13];

    int N = in_sizes[0] / INDIM;
    int E = in_sizes[1] / 2;
    const int* row = ei;
    const int* col = ei + E;

    char* ws = (char*)d_ws;
    size_t o = 0;
    auto take = [&](size_t bytes) -> char* {
        char* p = ws + o;
        o = (o + bytes + 255) & ~(size_t)255;
        return p;
    };
    float* x_f      = (float*)take((size_t)N*INDIM*4);   // reused as hnewP after h0/tau
    float* hnewP    = x_f;
    _Float16* hN    = (_Float16*)take((size_t)N*HID*2);
    _Float16* hF    = (_Float16*)take((size_t)N*HID*2);
    _Float16* aggF  = (_Float16*)take((size_t)N*HID*2);
    _Float16* W2F   = (_Float16*)take((size_t)384*192*2);
    _Float16* WinF  = (_Float16*)take((size_t)96*128*2);
    _Float16* WoutF = (_Float16*)take((size_t)64*96*2);
    float* tau_w1_f = (float*)take((size_t)INDIM*16*4);
    float* smallf   = (float*)take(1024*4);
    int*   off      = (int*)take((size_t)(N+1)*4);
    int*   csr_col  = (int*)take((size_t)E*4);
    int*   order    = (int*)take((size_t)N*4);
    int*   steps    = (int*)take((size_t)N*4);
    int*   bstart   = (int*)take(64);
    int*   mode     = (int*)take(64);
    int*   blksum   = (int*)take((size_t)GP*8*4);
    int*   blkbase  = (int*)take((size_t)GP*8*4);
    char*  zbase    = ws + o;
    int*   deg      = (int*)take((size_t)N*4);
    int*   cur      = (int*)take((size_t)N*4);
    size_t zbytes   = (size_t)((ws + o) - zbase);

    hipMemsetAsync(zbase, 0, zbytes, stream);
    sniff_kernel<<<1, 64, 0, stream>>>((const unsigned int*)x, mode);

    xconv_kernel<<<(N*INDIM + 255)/256, 256, 0, stream>>>(x, x_f, mode, N*INDIM);
    prep_kernel<<<(384*192 + 255)/256, 256, 0, stream>>>(
        w_in, b_in, tau_w1, tau_b1, tau_w2, tau_b2, wih, whh, bih, bhh, w_out, b_out,
        W2F, WinF, WoutF, tau_w1_f, smallf, mode);

    dim3 hgrid((N + BM - 1)/BM, 6);
    h0_kernel<<<hgrid, 512, 0, stream>>>(x_f, WinF, smallf, hN, N);
    tau_kernel<<<((size_t)N*64 + 255)/256, 256, 0, stream>>>(x_f, tau_w1_f, smallf, steps, N);
    deg_kernel<<<(E + 255)/256, 256, 0, stream>>>(row, deg, E);

    int C = (N + GP*256 - 1) / (GP*256);
    partial_kernel<<<GP, 256, 0, stream>>>(steps, deg, N, C, blksum);
    base_kernel<<<1, 64, 0, stream>>>(blksum, bstart, blkbase, off, N);
    scatter_kernel<<<GP, 256, 0, stream>>>(steps, deg, blkbase, N, C, order, off);

    pack_kernel<<<(N*HID + 255)/256, 256, 0, stream>>>(hN, order, hF, N);
    fill_kernel<<<(E + 255)/256, 256, 0, stream>>>(row, col, off, cur, csr_col, E);

    dim3 ggrid((N + BM - 1)/BM, 6);
    for (int t = 0; t < 5; t++) {
        agg_kernel<<<4096, 256, 0, stream>>>(hN, off, csr_col, order, bstart, t, aggF);
        gru_kernel<<<ggrid, 512, 0, stream>>>(aggF, hF, W2F, smallf, bstart, t, hnewP, N);
        commit_kernel<<<2048, 256, 0, stream>>>(hN, hF, hnewP, order, bstart, t);
    }

    dim3 ogrid((N + BM - 1)/BM, 4);
    out_kernel<<<ogrid, 512, 0, stream>>>(hN, WoutF, smallf, d_out, mode, N);
}

// Round 13
// 480.384 us; speedup vs baseline: 4.5899x; 1.0084x over previous
//
#include <hip/hip_runtime.h>
#include <hip/hip_bf16.h>

#define HID 96
#define INDIM 128
#define OUTDIM 64
#define BM 128
#define GP 128   // partial/scatter grid blocks (fixed mapping)

typedef __attribute__((ext_vector_type(8))) _Float16 half8;
typedef __attribute__((ext_vector_type(4))) _Float16 half4;
typedef __attribute__((ext_vector_type(4))) float floatx4;

__device__ __forceinline__ float ldmix(const void* p, long i, int mode) {
    return mode ? ((const float*)p)[i]
                : __bfloat162float(((const __hip_bfloat16*)p)[i]);
}

// ---------------- dtype sniffer (parallel: 64 lanes x 64 words) ----------------
__global__ void sniff_kernel(const unsigned int* xw, int* mode) {
    int lane = threadIdx.x & 63;
    int cnt = 0;
    for (int i = lane; i < 4096; i += 64) {
        unsigned int low = xw[i] & 0xFFFFu;
        unsigned int e = (low >> 7) & 0xFFu;
        if (e >= 0xC0u) cnt++;
    }
    #pragma unroll
    for (int ofs = 32; ofs > 0; ofs >>= 1) cnt += __shfl_down(cnt, ofs);
    if (lane == 0) *mode = (cnt > 256) ? 1 : 0;  // 1 = fp32 inputs, 0 = bf16 inputs
}

// ---------------- weight prep (fp16 planes) ----------------
// smallf: [0..95] b_in, [96..383] bih, [384..671] bhh, [672..735] b_out,
//         [736..751] tau_w2, [752..767] tau_b1, [768] tau_b2
__global__ void prep_kernel(const void* w_in, const void* b_in, const void* tau_w1,
                            const void* tau_b1, const void* tau_w2, const void* tau_b2,
                            const void* wih, const void* whh, const void* bih, const void* bhh,
                            const void* w_out, const void* b_out,
                            _Float16* W2F, _Float16* WinF, _Float16* WoutF,
                            float* tau_w1_f, float* smallf, const int* mode) {
    int m = *mode;
    int tid = blockIdx.x*blockDim.x + threadIdx.x;
    if (tid < 384*192) {
        int c = tid / 192, k = tid % 192;
        int g = c / 96, jj = c % 96;
        float v = 0.f;
        if (k < 96) {
            if (g == 0)      v = ldmix(wih, (long)(jj)*96 + k, m);
            else if (g == 1) v = ldmix(wih, (long)(96+jj)*96 + k, m);
            else if (g == 2) v = ldmix(wih, (long)(192+jj)*96 + k, m);
        } else {
            int kk = k - 96;
            if (g == 0)      v = ldmix(whh, (long)(jj)*96 + kk, m);
            else if (g == 1) v = ldmix(whh, (long)(96+jj)*96 + kk, m);
            else if (g == 3) v = ldmix(whh, (long)(192+jj)*96 + kk, m);
        }
        W2F[tid] = (_Float16)v;
    }
    if (tid < 96*128) {
        int j = tid >> 7, k = tid & 127;
        WinF[tid] = (_Float16)ldmix(w_in, (long)k*96 + j, m);
    }
    if (tid < 64*96) {
        int j = tid / 96, k = tid % 96;
        WoutF[tid] = (_Float16)ldmix(w_out, (long)k*OUTDIM + j, m);
    }
    if (tid < INDIM*16)   tau_w1_f[tid] = ldmix(tau_w1, tid, m);
    if (tid < HID)    smallf[tid]       = ldmix(b_in, tid, m);
    if (tid < 3*HID){ smallf[96+tid]    = ldmix(bih, tid, m);
                      smallf[384+tid]   = ldmix(bhh, tid, m); }
    if (tid < OUTDIM) smallf[672+tid]   = ldmix(b_out, tid, m);
    if (tid < 16)   { smallf[736+tid]   = ldmix(tau_w2, tid, m);
                      smallf[752+tid]   = ldmix(tau_b1, tid, m); }
    if (tid == 0)     smallf[768]       = ldmix(tau_b2, 0, m);
}

// ---------------- h0 = relu(x @ w_in + b_in) via fp16 MFMA -> hN (node layout, fp16) ----------------
__global__ void __launch_bounds__(512) h0_kernel(
        const void* __restrict__ x, const _Float16* __restrict__ WinF,
        const float* __restrict__ smallf, const int* __restrict__ mode,
        _Float16* __restrict__ hN, int N) {
    int row0 = blockIdx.x * BM;
    int jj0 = blockIdx.y * 16;

    __shared__ _Float16 Ah[128*136];
    __shared__ _Float16 Wh[16*136];

    int tid = threadIdx.x;
    int m = *mode;
    long limit = (long)N * INDIM;
    #pragma unroll
    for (int j = 0; j < 8; j++) {
        int e = (tid + j*512) * 4;
        int r = e >> 7, c = e & 127;
        long ge = (long)(row0 + r)*INDIM + c;
        half4 vh = {0, 0, 0, 0};
        if (ge + 4 <= limit) {
            if (m) {
                floatx4 v = *(const floatx4*)((const float*)x + ge);
                #pragma unroll
                for (int q = 0; q < 4; q++) vh[q] = (_Float16)v[q];
            } else {
                const __hip_bfloat16* p = (const __hip_bfloat16*)x + ge;
                #pragma unroll
                for (int q = 0; q < 4; q++) vh[q] = (_Float16)__bfloat162float(p[q]);
            }
        }
        *(half4*)(&Ah[r*136 + c]) = vh;
    }
    if (tid < 256) {
        int wrow = tid >> 4;
        int k = (tid & 15) * 8;
        *(half8*)(&Wh[wrow*136 + k]) = *(const half8*)(WinF + (long)(jj0 + wrow)*INDIM + k);
    }
    __syncthreads();

    int lane = tid & 63;
    int w = tid >> 6;
    int m15 = lane & 15, quad = lane >> 4;
    floatx4 acc = {0.f, 0.f, 0.f, 0.f};
    int abase = (w*16 + m15)*136 + quad*8;
    #pragma unroll
    for (int ks = 0; ks < 4; ks++) {
        int k0 = ks*32;
        half8 a = *(const half8*)(&Ah[abase + k0]);
        half8 b = *(const half8*)(&Wh[m15*136 + quad*8 + k0]);
        acc = __builtin_amdgcn_mfma_f32_16x16x32_f16(a, b, acc, 0, 0, 0);
    }

    int jj = jj0 + m15;
    float b = smallf[jj];
    #pragma unroll
    for (int reg = 0; reg < 4; reg++) {
        int li = row0 + w*16 + quad*4 + reg;
        if (li < N) hN[(long)li*HID + jj] = (_Float16)fmaxf(acc[reg] + b, 0.f);
    }
}

// ---------------- tau MLP -> steps (fp32, wave per node, fold-reduction) ----------------
__global__ void tau_kernel(const void* __restrict__ x, const float* __restrict__ tau_w1_f,
                           const float* __restrict__ smallf, const int* __restrict__ mode,
                           int* __restrict__ steps, int N) {
    int gtid = blockIdx.x*blockDim.x + threadIdx.x;
    int n = gtid >> 6;
    int lane = threadIdx.x & 63;
    if (n >= N) return;
    int m = *mode;
    float x0, x1;
    if (m) {
        const float* xr = (const float*)x + (size_t)n*INDIM + 2*lane;
        x0 = xr[0]; x1 = xr[1];
    } else {
        const __hip_bfloat16* xr = (const __hip_bfloat16*)x + (size_t)n*INDIM + 2*lane;
        x0 = __bfloat162float(xr[0]); x1 = __bfloat162float(xr[1]);
    }
    const float* w0 = tau_w1_f + (2*lane)*16;
    const float* w1 = w0 + 16;
    float acc[16];
    #pragma unroll
    for (int j = 0; j < 16; j++) acc[j] = x0*w0[j] + x1*w1[j];
    // fold-reduce: halve accumulator count while reducing over lane bits 0..3
    #pragma unroll
    for (int step = 0; step < 4; step++) {
        int mask = 1 << step;
        int c = 8 >> step;
        #pragma unroll
        for (int j = 0; j < 8; j++) {
            if (j < c) {
                float send = (lane & mask) ? acc[j] : acc[j + c];
                float keep = (lane & mask) ? acc[j + c] : acc[j];
                acc[j] = keep + __shfl_xor(send, mask);
            }
        }
    }
    // full-wave reduce over lane bits 4,5
    acc[0] += __shfl_xor(acc[0], 16);
    acc[0] += __shfl_xor(acc[0], 32);
    // lane holds S[j], j = bitrev4(lane&15)
    int l = lane & 15;
    int j = ((l & 1) << 3) | ((l & 2) << 1) | ((l & 4) >> 1) | ((l & 8) >> 3);
    float term = fmaxf(acc[0] + smallf[752 + j], 0.f) * smallf[736 + j];
    #pragma unroll
    for (int mask = 1; mask <= 8; mask <<= 1) term += __shfl_xor(term, mask);
    if (lane == 0) {
        float z = term + smallf[768];
        float tau = fmaxf(z, 0.f) + log1pf(expf(-fabsf(z)));   // stable softplus
        float inv = 1.0f / tau;
        int s;
        if (inv >= 5.0f) s = 5;
        else { s = (int)inv; if (s < 0) s = 0; if (s > 5) s = 5; }
        steps[n] = s;
    }
}

// ---------------- multi-block deterministic bucket+deg pipeline ----------------
__global__ void partial_kernel(const int* __restrict__ steps, const int* __restrict__ deg,
                               int N, int C, int* __restrict__ blksum) {
    __shared__ int red[256*8];
    int tid = threadIdx.x;
    int tg = blockIdx.x*256 + tid;
    int start = tg*C, end = min(start + C, N);
    if (end < start) end = start;
    int cnt[7] = {0,0,0,0,0,0,0};
    for (int i = start; i < end; i++) { cnt[steps[i]]++; cnt[6] += deg[i]; }
    #pragma unroll
    for (int k = 0; k < 7; k++) red[tid*8 + k] = cnt[k];
    __syncthreads();
    for (int ofs = 128; ofs > 0; ofs >>= 1) {
        if (tid < ofs) {
            #pragma unroll
            for (int k = 0; k < 7; k++) red[tid*8 + k] += red[(tid+ofs)*8 + k];
        }
        __syncthreads();
    }
    if (tid < 7) blksum[blockIdx.x*8 + tid] = red[tid];
}

__global__ void base_kernel(const int* __restrict__ blksum, int* __restrict__ bstart,
                            int* __restrict__ blkbase, int* __restrict__ off, int N) {
    __shared__ int tot[8];
    __shared__ int sb[8];
    int tid = threadIdx.x;
    if (tid < 7) {
        int s = 0;
        for (int b = 0; b < GP; b++) s += blksum[b*8 + tid];
        tot[tid] = s;
    }
    __syncthreads();
    if (tid == 0) {
        int run = 0;
        for (int ss = 5; ss >= 0; --ss) { sb[ss] = run; bstart[ss] = run; run += tot[ss]; }
        bstart[6] = run;          // = N
        off[N] = tot[6];          // = E
        sb[6] = 0;
    }
    __syncthreads();
    if (tid < 7) {
        int run = sb[tid];
        for (int b = 0; b < GP; b++) { blkbase[b*8 + tid] = run; run += blksum[b*8 + tid]; }
    }
}

__global__ void scatter_kernel(const int* __restrict__ steps, const int* __restrict__ deg,
                               const int* __restrict__ blkbase, int N, int C,
                               int* __restrict__ order, int* __restrict__ off) {
    __shared__ int buf[256];
    int tid = threadIdx.x;
    int b = blockIdx.x;
    int tg = b*256 + tid;
    int start = tg*C, end = min(start + C, N);
    if (end < start) end = start;
    int cnt[7] = {0,0,0,0,0,0,0};
    for (int i = start; i < end; i++) { cnt[steps[i]]++; cnt[6] += deg[i]; }
    int mybase[7];
    #pragma unroll
    for (int k = 0; k < 7; k++) {
        buf[tid] = cnt[k];
        __syncthreads();
        for (int ofs = 1; ofs < 256; ofs <<= 1) {
            int t = (tid >= ofs) ? buf[tid - ofs] : 0;
            __syncthreads();
            buf[tid] += t;
            __syncthreads();
        }
        mybase[k] = blkbase[b*8 + k] + buf[tid] - cnt[k];
        __syncthreads();
    }
    for (int i = start; i < end; i++) {
        int s = steps[i];
        order[mybase[s]++] = i;
        off[i] = mybase[6];
        mybase[6] += deg[i];
    }
}

// ---------------- pack hN into order-space fp16 plane ----------------
__global__ void pack_kernel(const _Float16* __restrict__ hN, const int* __restrict__ order,
                            _Float16* __restrict__ hF, int N) {
    int tid = blockIdx.x*blockDim.x + threadIdx.x;
    if (tid >= N*HID) return;
    int li = tid / HID, f = tid % HID;
    int n = order[li];
    hF[tid] = hN[(size_t)n*HID + f];
}

// ---------------- CSR build ----------------
__global__ void deg_kernel(const int* __restrict__ row, int* deg, int E) {
    int e = blockIdx.x*blockDim.x + threadIdx.x;
    if (e < E) atomicAdd(&deg[row[e]], 1);
}

__global__ void fill_kernel(const int* __restrict__ row, const int* __restrict__ col,
                            const int* __restrict__ off, int* cur, int* __restrict__ csr_col, int E) {
    int e = blockIdx.x*blockDim.x + threadIdx.x;
    if (e >= E) return;
    int r = row[e];
    int p = atomicAdd(&cur[r], 1);
    csr_col[off[r] + p] = col[e];
}

// ---------------- aggregation: fp16 gathers, fp32 accumulate -> packed fp16 aggF ----------------
__global__ void agg_kernel(const _Float16* __restrict__ hN, const int* __restrict__ off,
                           const int* __restrict__ csr_col, const int* __restrict__ order,
                           const int* __restrict__ bstart, int t, _Float16* __restrict__ aggF) {
    int K = bstart[t];
    int total = K * HID;
    int stride = gridDim.x * blockDim.x;
    for (int idx = blockIdx.x*blockDim.x + threadIdx.x; idx < total; idx += stride) {
        int li = idx / HID, f = idx % HID;
        int i = order[li];
        float hv = (float)hN[(size_t)i*HID + f];
        int e0 = off[i], e1 = off[i+1];
        float acc = 0.f;
        int e = e0;
        for (; e + 4 <= e1; e += 4) {
            int c0 = csr_col[e],   c1 = csr_col[e+1];
            int c2 = csr_col[e+2], c3 = csr_col[e+3];
            float v0 = (float)hN[(size_t)c0*HID + f];
            float v1 = (float)hN[(size_t)c1*HID + f];
            float v2 = (float)hN[(size_t)c2*HID + f];
            float v3 = (float)hN[(size_t)c3*HID + f];
            acc += fabsf(hv - v0) + fabsf(hv - v1) + fabsf(hv - v2) + fabsf(hv - v3);
        }
        for (; e < e1; e++) {
            int c = csr_col[e];
            acc += fabsf(hv - (float)hN[(size_t)c*HID + f]);
        }
        aggF[idx] = (_Float16)acc;
    }
}

// ---------------- GRU via fp16 MFMA GEMM, fused epilogue + direct commit ----------------
// A = [aggF | hFin] (K x 192) packed fp16; B = W2F^T (192 x 384). 128 rows x 16-jj stripe.
// Writes hFout (packed) and hN (node layout) directly — no separate commit pass.
__global__ void __launch_bounds__(512) gru_kernel(
        const _Float16* __restrict__ aggF, const _Float16* __restrict__ hFin,
        const _Float16* __restrict__ W2F,
        const float* __restrict__ smallf, const int* __restrict__ bstart, int t,
        const int* __restrict__ order, _Float16* __restrict__ hN,
        _Float16* __restrict__ hFout, int N) {
    int K = bstart[t];
    int row0 = blockIdx.x * BM;
    if (row0 >= K) return;
    int jj0 = blockIdx.y * 16;

    __shared__ _Float16 Ah[128*200];   // [agg|h] 128 x (192+8)
    __shared__ _Float16 Wh[64*200];    // 64 cols x (192+8)

    int tid = threadIdx.x;
    long limit = (long)N * HID;
    #pragma unroll
    for (int j = 0; j < 3; j++) {
        int e = (tid + j*512) * 8;
        {
            int r = e / 96, c = e % 96;
            long ge = (long)(row0 + r)*96 + c;
            half8 va = {0,0,0,0,0,0,0,0}, vh = va;
            if (ge + 8 <= limit) {
                va = *(const half8*)(aggF + ge);
                vh = *(const half8*)(hFin + ge);
            }
            *(half8*)(&Ah[r*200 + c])      = va;
            *(half8*)(&Ah[r*200 + 96 + c]) = vh;
        }
        {
            int wrow = e / 192, k = e % 192;
            int g = wrow >> 4, cc = wrow & 15;
            *(half8*)(&Wh[wrow*200 + k]) = *(const half8*)(W2F + (long)(g*96 + jj0 + cc)*192 + k);
        }
    }
    __syncthreads();

    int lane = tid & 63;
    int w = tid >> 6;
    int m15 = lane & 15, quad = lane >> 4;
    floatx4 acc[4];
    #pragma unroll
    for (int g = 0; g < 4; g++) acc[g] = (floatx4){0.f, 0.f, 0.f, 0.f};

    int abase = (w*16 + m15)*200 + quad*8;
    #pragma unroll
    for (int ks = 0; ks < 6; ks++) {
        int k0 = ks*32;
        half8 a = *(const half8*)(&Ah[abase + k0]);
        #pragma unroll
        for (int g = 0; g < 4; g++) {
            half8 b = *(const half8*)(&Wh[(g*16 + m15)*200 + quad*8 + k0]);
            acc[g] = __builtin_amdgcn_mfma_f32_16x16x32_f16(a, b, acc[g], 0, 0, 0);
        }
    }

    int jj = jj0 + m15;
    float bir = smallf[96+jj],  biz = smallf[192+jj], bin = smallf[288+jj];
    float bhr = smallf[384+jj], bhz = smallf[480+jj], bhn = smallf[576+jj];
    #pragma unroll
    for (int reg = 0; reg < 4; reg++) {
        int li = row0 + w*16 + quad*4 + reg;
        if (li < K) {
            float rp = acc[0][reg] + bir + bhr;
            float zp = acc[1][reg] + biz + bhz;
            float ip = acc[2][reg] + bin;
            float hn = acc[3][reg] + bhn;
            float r  = 1.f/(1.f + expf(-rp));
            float z  = 1.f/(1.f + expf(-zp));
            float nn = tanhf(ip + r*hn);
            int tr = w*16 + quad*4 + reg;             // row within tile
            float hold = (float)Ah[tr*200 + 96 + jj]; // h_old from LDS A-tile
            _Float16 v16 = (_Float16)((1.f - z)*nn + z*hold);
            int node = order[li];
            hN[(long)node*HID + jj] = v16;
            hFout[(long)li*HID + jj] = v16;
        }
    }
}

// ---------------- out = h @ w_out + b_out via fp16 MFMA ----------------
__global__ void __launch_bounds__(512) out_kernel(
        const _Float16* __restrict__ hN, const _Float16* __restrict__ WoutF,
        const float* __restrict__ smallf, void* out, const int* mode, int N) {
    int row0 = blockIdx.x * BM;
    int jj0 = blockIdx.y * 16;

    __shared__ _Float16 Ah[128*104];
    __shared__ _Float16 Wh[16*104];

    int tid = threadIdx.x;
    long limit = (long)N * HID;
    #pragma unroll
    for (int j = 0; j < 3; j++) {
        int e = (tid + j*512) * 8;        // 12288 elems per tile
        int r = e / 96, c = e % 96;
        long ge = (long)(row0 + r)*HID + c;
        half8 v = {0,0,0,0,0,0,0,0};
        if (ge + 8 <= limit) v = *(const half8*)(hN + ge);
        *(half8*)(&Ah[r*104 + c]) = v;
    }
    if (tid < 192) {
        int wrow = tid / 12;
        int k = (tid % 12) * 8;
        *(half8*)(&Wh[wrow*104 + k]) = *(const half8*)(WoutF + (long)(jj0 + wrow)*HID + k);
    }
    __syncthreads();

    int lane = tid & 63;
    int w = tid >> 6;
    int m15 = lane & 15, quad = lane >> 4;
    floatx4 acc = {0.f, 0.f, 0.f, 0.f};
    int abase = (w*16 + m15)*104 + quad*8;
    #pragma unroll
    for (int ks = 0; ks < 3; ks++) {
        int k0 = ks*32;
        half8 a = *(const half8*)(&Ah[abase + k0]);
        half8 b = *(const half8*)(&Wh[m15*104 + quad*8 + k0]);
        acc = __builtin_amdgcn_mfma_f32_16x16x32_f16(a, b, acc, 0, 0, 0);
    }

    int jj = jj0 + m15;
    float b = smallf[672+jj];
    int m = *mode;
    #pragma unroll
    for (int reg = 0; reg < 4; reg++) {
        int li = row0 + w*16 + quad*4 + reg;
        if (li < N) {
            float v = acc[reg] + b;
            long oi = (long)li*OUTDIM + jj;
            if (m) ((float*)out)[oi] = v;
            else   ((__hip_bfloat16*)out)[oi] = __float2bfloat16(v);
        }
    }
}

extern "C" void kernel_launch(void* const* d_in, const int* in_sizes, int n_in,
                              void* d_out, int out_size, void* d_ws, size_t ws_size,
                              hipStream_t stream) {
    const void* x      = d_in[0];
    const int*  ei     = (const int*)d_in[1];
    const void* w_in   = d_in[2],  *b_in   = d_in[3];
    const void* tau_w1 = d_in[4],  *tau_b1 = d_in[5];
    const void* tau_w2 = d_in[6],  *tau_b2 = d_in[7];
    const void* wih    = d_in[8],  *whh    = d_in[9];
    const void* bih    = d_in[10], *bhh    = d_in[11];
    const void* w_out  = d_in[12], *b_out  = d_in[13];

    int N = in_sizes[0] / INDIM;
    int E = in_sizes[1] / 2;
    const int* row = ei;
    const int* col = ei + E;

    char* ws = (char*)d_ws;
    size_t o = 0;
    auto take = [&](size_t bytes) -> char* {
        char* p = ws + o;
        o = (o + bytes + 255) & ~(size_t)255;
        return p;
    };
    _Float16* hN    = (_Float16*)take((size_t)N*HID*2);
    _Float16* hFa   = (_Float16*)take((size_t)N*HID*2);
    _Float16* hFb   = (_Float16*)take((size_t)N*HID*2);
    _Float16* aggF  = (_Float16*)take((size_t)N*HID*2);
    _Float16* W2F   = (_Float16*)take((size_t)384*192*2);
    _Float16* WinF  = (_Float16*)take((size_t)96*128*2);
    _Float16* WoutF = (_Float16*)take((size_t)64*96*2);
    float* tau_w1_f = (float*)take((size_t)INDIM*16*4);
    float* smallf   = (float*)take(1024*4);
    int*   off      = (int*)take((size_t)(N+1)*4);
    int*   csr_col  = (int*)take((size_t)E*4);
    int*   order    = (int*)take((size_t)N*4);
    int*   steps    = (int*)take((size_t)N*4);
    int*   bstart   = (int*)take(64);
    int*   mode     = (int*)take(64);
    int*   blksum   = (int*)take((size_t)GP*8*4);
    int*   blkbase  = (int*)take((size_t)GP*8*4);
    char*  zbase    = ws + o;
    int*   deg      = (int*)take((size_t)N*4);
    int*   cur      = (int*)take((size_t)N*4);
    size_t zbytes   = (size_t)((ws + o) - zbase);

    hipMemsetAsync(zbase, 0, zbytes, stream);
    sniff_kernel<<<1, 64, 0, stream>>>((const unsigned int*)x, mode);

    prep_kernel<<<(384*192 + 255)/256, 256, 0, stream>>>(
        w_in, b_in, tau_w1, tau_b1, tau_w2, tau_b2, wih, whh, bih, bhh, w_out, b_out,
        W2F, WinF, WoutF, tau_w1_f, smallf, mode);

    dim3 hgrid((N + BM - 1)/BM, 6);
    h0_kernel<<<hgrid, 512, 0, stream>>>(x, WinF, smallf, mode, hN, N);
    tau_kernel<<<((size_t)N*64 + 255)/256, 256, 0, stream>>>(x, tau_w1_f, smallf, mode, steps, N);
    deg_kernel<<<(E + 255)/256, 256, 0, stream>>>(row, deg, E);

    int C = (N + GP*256 - 1) / (GP*256);
    partial_kernel<<<GP, 256, 0, stream>>>(steps, deg, N, C, blksum);
    base_kernel<<<1, 64, 0, stream>>>(blksum, bstart, blkbase, off, N);
    scatter_kernel<<<GP, 256, 0, stream>>>(steps, deg, blkbase, N, C, order, off);

    pack_kernel<<<(N*HID + 255)/256, 256, 0, stream>>>(hN, order, hFa, N);
    fill_kernel<<<(E + 255)/256, 256, 0, stream>>>(row, col, off, cur, csr_col, E);

    dim3 ggrid((N + BM - 1)/BM, 6);
    _Float16* hin = hFa;
    _Float16* hout = hFb;
    for (int t = 0; t < 5; t++) {
        agg_kernel<<<4096, 256, 0, stream>>>(hN, off, csr_col, order, bstart, t, aggF);
        gru_kernel<<<ggrid, 512, 0, stream>>>(aggF, hin, W2F, smallf, bstart, t,
                                              order, hN, hout, N);
        _Float16* tmp = hin; hin = hout; hout = tmp;
    }

    dim3 ogrid((N + BM - 1)/BM, 4);
    out_kernel<<<ogrid, 512, 0, stream>>>(hN, WoutF, smallf, d_out, mode, N);
}

// Round 14
// 442.908 us; speedup vs baseline: 4.9782x; 1.0846x over previous
//
#include <hip/hip_runtime.h>
#include <hip/hip_bf16.h>

#define HID 96
#define INDIM 128
#define OUTDIM 64
#define BM 128
#define GP 128   // partial/scatter grid blocks (fixed mapping)

typedef __attribute__((ext_vector_type(8))) _Float16 half8;
typedef __attribute__((ext_vector_type(4))) _Float16 half4;
typedef __attribute__((ext_vector_type(4))) float floatx4;

__device__ __forceinline__ float ldmix(const void* p, long i, int mode) {
    return mode ? ((const float*)p)[i]
                : __bfloat162float(((const __hip_bfloat16*)p)[i]);
}

// ---------------- dtype sniffer (parallel: 64 lanes x 64 words) ----------------
__global__ void sniff_kernel(const unsigned int* xw, int* mode) {
    int lane = threadIdx.x & 63;
    int cnt = 0;
    for (int i = lane; i < 4096; i += 64) {
        unsigned int low = xw[i] & 0xFFFFu;
        unsigned int e = (low >> 7) & 0xFFu;
        if (e >= 0xC0u) cnt++;
    }
    #pragma unroll
    for (int ofs = 32; ofs > 0; ofs >>= 1) cnt += __shfl_down(cnt, ofs);
    if (lane == 0) *mode = (cnt > 256) ? 1 : 0;  // 1 = fp32 inputs, 0 = bf16 inputs
}

// ---------------- weight prep (fp16 planes) ----------------
// smallf: [0..95] b_in, [96..383] bih, [384..671] bhh, [672..735] b_out,
//         [736..751] tau_w2, [752..767] tau_b1, [768] tau_b2
__global__ void prep_kernel(const void* w_in, const void* b_in, const void* tau_w1,
                            const void* tau_b1, const void* tau_w2, const void* tau_b2,
                            const void* wih, const void* whh, const void* bih, const void* bhh,
                            const void* w_out, const void* b_out,
                            _Float16* W2F, _Float16* WinF, _Float16* WoutF,
                            float* tau_w1_f, float* smallf, const int* mode) {
    int m = *mode;
    int tid = blockIdx.x*blockDim.x + threadIdx.x;
    if (tid < 384*192) {
        int c = tid / 192, k = tid % 192;
        int g = c / 96, jj = c % 96;
        float v = 0.f;
        if (k < 96) {
            if (g == 0)      v = ldmix(wih, (long)(jj)*96 + k, m);
            else if (g == 1) v = ldmix(wih, (long)(96+jj)*96 + k, m);
            else if (g == 2) v = ldmix(wih, (long)(192+jj)*96 + k, m);
        } else {
            int kk = k - 96;
            if (g == 0)      v = ldmix(whh, (long)(jj)*96 + kk, m);
            else if (g == 1) v = ldmix(whh, (long)(96+jj)*96 + kk, m);
            else if (g == 3) v = ldmix(whh, (long)(192+jj)*96 + kk, m);
        }
        W2F[tid] = (_Float16)v;
    }
    if (tid < 96*128) {
        int j = tid >> 7, k = tid & 127;
        WinF[tid] = (_Float16)ldmix(w_in, (long)k*96 + j, m);
    }
    if (tid < 64*96) {
        int j = tid / 96, k = tid % 96;
        WoutF[tid] = (_Float16)ldmix(w_out, (long)k*OUTDIM + j, m);
    }
    if (tid < INDIM*16)   tau_w1_f[tid] = ldmix(tau_w1, tid, m);
    if (tid < HID)    smallf[tid]       = ldmix(b_in, tid, m);
    if (tid < 3*HID){ smallf[96+tid]    = ldmix(bih, tid, m);
                      smallf[384+tid]   = ldmix(bhh, tid, m); }
    if (tid < OUTDIM) smallf[672+tid]   = ldmix(b_out, tid, m);
    if (tid < 16)   { smallf[736+tid]   = ldmix(tau_w2, tid, m);
                      smallf[752+tid]   = ldmix(tau_b1, tid, m); }
    if (tid == 0)     smallf[768]       = ldmix(tau_b2, 0, m);
}

// ---------------- h0 = relu(x @ w_in + b_in) via fp16 MFMA -> hN (node layout, fp16) ----------------
__global__ void __launch_bounds__(512) h0_kernel(
        const void* __restrict__ x, const _Float16* __restrict__ WinF,
        const float* __restrict__ smallf, const int* __restrict__ mode,
        _Float16* __restrict__ hN, int N) {
    int row0 = blockIdx.x * BM;
    int jj0 = blockIdx.y * 16;

    __shared__ _Float16 Ah[128*136];
    __shared__ _Float16 Wh[16*136];

    int tid = threadIdx.x;
    int m = *mode;
    long limit = (long)N * INDIM;
    #pragma unroll
    for (int j = 0; j < 8; j++) {
        int e = (tid + j*512) * 4;
        int r = e >> 7, c = e & 127;
        long ge = (long)(row0 + r)*INDIM + c;
        half4 vh = {0, 0, 0, 0};
        if (ge + 4 <= limit) {
            if (m) {
                floatx4 v = *(const floatx4*)((const float*)x + ge);
                #pragma unroll
                for (int q = 0; q < 4; q++) vh[q] = (_Float16)v[q];
            } else {
                const __hip_bfloat16* p = (const __hip_bfloat16*)x + ge;
                #pragma unroll
                for (int q = 0; q < 4; q++) vh[q] = (_Float16)__bfloat162float(p[q]);
            }
        }
        *(half4*)(&Ah[r*136 + c]) = vh;
    }
    if (tid < 256) {
        int wrow = tid >> 4;
        int k = (tid & 15) * 8;
        *(half8*)(&Wh[wrow*136 + k]) = *(const half8*)(WinF + (long)(jj0 + wrow)*INDIM + k);
    }
    __syncthreads();

    int lane = tid & 63;
    int w = tid >> 6;
    int m15 = lane & 15, quad = lane >> 4;
    floatx4 acc = {0.f, 0.f, 0.f, 0.f};
    int abase = (w*16 + m15)*136 + quad*8;
    #pragma unroll
    for (int ks = 0; ks < 4; ks++) {
        int k0 = ks*32;
        half8 a = *(const half8*)(&Ah[abase + k0]);
        half8 b = *(const half8*)(&Wh[m15*136 + quad*8 + k0]);
        acc = __builtin_amdgcn_mfma_f32_16x16x32_f16(a, b, acc, 0, 0, 0);
    }

    int jj = jj0 + m15;
    float b = smallf[jj];
    #pragma unroll
    for (int reg = 0; reg < 4; reg++) {
        int li = row0 + w*16 + quad*4 + reg;
        if (li < N) hN[(long)li*HID + jj] = (_Float16)fmaxf(acc[reg] + b, 0.f);
    }
}

// ---------------- tau MLP -> steps (node-per-thread, LDS-staged x, zero shuffles) ----------------
__global__ void __launch_bounds__(128) tau_kernel(
        const void* __restrict__ x, const float* __restrict__ tau_w1_f,
        const float* __restrict__ smallf, const int* __restrict__ mode,
        int* __restrict__ steps, int N) {
    __shared__ float xs[128*129];    // 129-pad: rows on consecutive banks
    __shared__ float ws[2048];       // tau_w1 [128][16]
    __shared__ float wb[34];         // b1[16], w2[16], b2

    int tid = threadIdx.x;
    int row0 = blockIdx.x * 128;
    int m = *mode;

    // stage weights
    #pragma unroll
    for (int j = 0; j < 16; j++) ws[tid + j*128] = tau_w1_f[tid + j*128];
    if (tid < 16) { wb[tid] = smallf[752 + tid]; wb[16 + tid] = smallf[736 + tid]; }
    if (tid == 32) wb[32] = smallf[768];

    // stage x tile: iteration j loads row (row0+j), thread t -> column t (coalesced)
    for (int j = 0; j < 128; j++) {
        int n = row0 + j;
        float v = 0.f;
        if (n < N) {
            long ge = (long)n*INDIM + tid;
            v = m ? ((const float*)x)[ge]
                  : __bfloat162float(((const __hip_bfloat16*)x)[ge]);
        }
        xs[j*129 + tid] = v;
    }
    __syncthreads();

    int n = row0 + tid;
    float acc[16];
    #pragma unroll
    for (int j = 0; j < 16; j++) acc[j] = 0.f;
    const float* xr = &xs[tid*129];
    for (int k = 0; k < 128; k++) {
        float xv = xr[k];
        const float* w = &ws[k*16];
        #pragma unroll
        for (int j = 0; j < 16; j++) acc[j] += xv * w[j];
    }
    float z = wb[32];
    #pragma unroll
    for (int j = 0; j < 16; j++) z += fmaxf(acc[j] + wb[j], 0.f) * wb[16 + j];
    float tau = fmaxf(z, 0.f) + log1pf(expf(-fabsf(z)));   // stable softplus
    float inv = 1.0f / tau;
    int s;
    if (inv >= 5.0f) s = 5;
    else { s = (int)inv; if (s < 0) s = 0; if (s > 5) s = 5; }
    if (n < N) steps[n] = s;
}

// ---------------- multi-block deterministic bucket+deg pipeline ----------------
__global__ void partial_kernel(const int* __restrict__ steps, const int* __restrict__ deg,
                               int N, int C, int* __restrict__ blksum) {
    __shared__ int red[256*8];
    int tid = threadIdx.x;
    int tg = blockIdx.x*256 + tid;
    int start = tg*C, end = min(start + C, N);
    if (end < start) end = start;
    int cnt[7] = {0,0,0,0,0,0,0};
    for (int i = start; i < end; i++) { cnt[steps[i]]++; cnt[6] += deg[i]; }
    #pragma unroll
    for (int k = 0; k < 7; k++) red[tid*8 + k] = cnt[k];
    __syncthreads();
    for (int ofs = 128; ofs > 0; ofs >>= 1) {
        if (tid < ofs) {
            #pragma unroll
            for (int k = 0; k < 7; k++) red[tid*8 + k] += red[(tid+ofs)*8 + k];
        }
        __syncthreads();
    }
    if (tid < 7) blksum[blockIdx.x*8 + tid] = red[tid];
}

__global__ void base_kernel(const int* __restrict__ blksum, int* __restrict__ bstart,
                            int* __restrict__ blkbase, int* __restrict__ off, int N) {
    __shared__ int tot[8];
    __shared__ int sb[8];
    int tid = threadIdx.x;
    if (tid < 7) {
        int s = 0;
        for (int b = 0; b < GP; b++) s += blksum[b*8 + tid];
        tot[tid] = s;
    }
    __syncthreads();
    if (tid == 0) {
        int run = 0;
        for (int ss = 5; ss >= 0; --ss) { sb[ss] = run; bstart[ss] = run; run += tot[ss]; }
        bstart[6] = run;          // = N
        off[N] = tot[6];          // = E
        sb[6] = 0;
    }
    __syncthreads();
    if (tid < 7) {
        int run = sb[tid];
        for (int b = 0; b < GP; b++) { blkbase[b*8 + tid] = run; run += blksum[b*8 + tid]; }
    }
}

__global__ void scatter_kernel(const int* __restrict__ steps, const int* __restrict__ deg,
                               const int* __restrict__ blkbase, int N, int C,
                               int* __restrict__ order, int* __restrict__ off) {
    __shared__ int buf[256];
    int tid = threadIdx.x;
    int b = blockIdx.x;
    int tg = b*256 + tid;
    int start = tg*C, end = min(start + C, N);
    if (end < start) end = start;
    int cnt[7] = {0,0,0,0,0,0,0};
    for (int i = start; i < end; i++) { cnt[steps[i]]++; cnt[6] += deg[i]; }
    int mybase[7];
    #pragma unroll
    for (int k = 0; k < 7; k++) {
        buf[tid] = cnt[k];
        __syncthreads();
        for (int ofs = 1; ofs < 256; ofs <<= 1) {
            int t = (tid >= ofs) ? buf[tid - ofs] : 0;
            __syncthreads();
            buf[tid] += t;
            __syncthreads();
        }
        mybase[k] = blkbase[b*8 + k] + buf[tid] - cnt[k];
        __syncthreads();
    }
    for (int i = start; i < end; i++) {
        int s = steps[i];
        order[mybase[s]++] = i;
        off[i] = mybase[6];
        mybase[6] += deg[i];
    }
}

// ---------------- pack hN into order-space fp16 plane ----------------
__global__ void pack_kernel(const _Float16* __restrict__ hN, const int* __restrict__ order,
                            _Float16* __restrict__ hF, int N) {
    int tid = blockIdx.x*blockDim.x + threadIdx.x;
    if (tid >= N*HID) return;
    int li = tid / HID, f = tid % HID;
    int n = order[li];
    hF[tid] = hN[(size_t)n*HID + f];
}

// ---------------- CSR build ----------------
__global__ void deg_kernel(const int* __restrict__ row, int* deg, int E) {
    int e = blockIdx.x*blockDim.x + threadIdx.x;
    if (e < E) atomicAdd(&deg[row[e]], 1);
}

__global__ void fill_kernel(const int* __restrict__ row, const int* __restrict__ col,
                            const int* __restrict__ off, int* cur, int* __restrict__ csr_col, int E) {
    int e = blockIdx.x*blockDim.x + threadIdx.x;
    if (e >= E) return;
    int r = row[e];
    int p = atomicAdd(&cur[r], 1);
    csr_col[off[r] + p] = col[e];
}

// ---------------- aggregation: fp16 gathers, fp32 accumulate -> packed fp16 aggF ----------------
__global__ void agg_kernel(const _Float16* __restrict__ hN, const int* __restrict__ off,
                           const int* __restrict__ csr_col, const int* __restrict__ order,
                           const int* __restrict__ bstart, int t, _Float16* __restrict__ aggF) {
    int K = bstart[t];
    int total = K * HID;
    int stride = gridDim.x * blockDim.x;
    for (int idx = blockIdx.x*blockDim.x + threadIdx.x; idx < total; idx += stride) {
        int li = idx / HID, f = idx % HID;
        int i = order[li];
        float hv = (float)hN[(size_t)i*HID + f];
        int e0 = off[i], e1 = off[i+1];
        float acc = 0.f;
        int e = e0;
        for (; e + 4 <= e1; e += 4) {
            int c0 = csr_col[e],   c1 = csr_col[e+1];
            int c2 = csr_col[e+2], c3 = csr_col[e+3];
            float v0 = (float)hN[(size_t)c0*HID + f];
            float v1 = (float)hN[(size_t)c1*HID + f];
            float v2 = (float)hN[(size_t)c2*HID + f];
            float v3 = (float)hN[(size_t)c3*HID + f];
            acc += fabsf(hv - v0) + fabsf(hv - v1) + fabsf(hv - v2) + fabsf(hv - v3);
        }
        for (; e < e1; e++) {
            int c = csr_col[e];
            acc += fabsf(hv - (float)hN[(size_t)c*HID + f]);
        }
        aggF[idx] = (_Float16)acc;
    }
}

// ---------------- GRU via fp16 MFMA GEMM, fused epilogue + direct commit ----------------
__global__ void __launch_bounds__(512) gru_kernel(
        const _Float16* __restrict__ aggF, const _Float16* __restrict__ hFin,
        const _Float16* __restrict__ W2F,
        const float* __restrict__ smallf, const int* __restrict__ bstart, int t,
        const int* __restrict__ order, _Float16* __restrict__ hN,
        _Float16* __restrict__ hFout, int N) {
    int K = bstart[t];
    int row0 = blockIdx.x * BM;
    if (row0 >= K) return;
    int jj0 = blockIdx.y * 16;

    __shared__ _Float16 Ah[128*200];   // [agg|h] 128 x (192+8)
    __shared__ _Float16 Wh[64*200];    // 64 cols x (192+8)

    int tid = threadIdx.x;
    long limit = (long)N * HID;
    #pragma unroll
    for (int j = 0; j < 3; j++) {
        int e = (tid + j*512) * 8;
        {
            int r = e / 96, c = e % 96;
            long ge = (long)(row0 + r)*96 + c;
            half8 va = {0,0,0,0,0,0,0,0}, vh = va;
            if (ge + 8 <= limit) {
                va = *(const half8*)(aggF + ge);
                vh = *(const half8*)(hFin + ge);
            }
            *(half8*)(&Ah[r*200 + c])      = va;
            *(half8*)(&Ah[r*200 + 96 + c]) = vh;
        }
        {
            int wrow = e / 192, k = e % 192;
            int g = wrow >> 4, cc = wrow & 15;
            *(half8*)(&Wh[wrow*200 + k]) = *(const half8*)(W2F + (long)(g*96 + jj0 + cc)*192 + k);
        }
    }
    __syncthreads();

    int lane = tid & 63;
    int w = tid >> 6;
    int m15 = lane & 15, quad = lane >> 4;
    floatx4 acc[4];
    #pragma unroll
    for (int g = 0; g < 4; g++) acc[g] = (floatx4){0.f, 0.f, 0.f, 0.f};

    int abase = (w*16 + m15)*200 + quad*8;
    #pragma unroll
    for (int ks = 0; ks < 6; ks++) {
        int k0 = ks*32;
        half8 a = *(const half8*)(&Ah[abase + k0]);
        #pragma unroll
        for (int g = 0; g < 4; g++) {
            half8 b = *(const half8*)(&Wh[(g*16 + m15)*200 + quad*8 + k0]);
            acc[g] = __builtin_amdgcn_mfma_f32_16x16x32_f16(a, b, acc[g], 0, 0, 0);
        }
    }

    int jj = jj0 + m15;
    float bir = smallf[96+jj],  biz = smallf[192+jj], bin = smallf[288+jj];
    float bhr = smallf[384+jj], bhz = smallf[480+jj], bhn = smallf[576+jj];
    #pragma unroll
    for (int reg = 0; reg < 4; reg++) {
        int li = row0 + w*16 + quad*4 + reg;
        if (li < K) {
            float rp = acc[0][reg] + bir + bhr;
            float zp = acc[1][reg] + biz + bhz;
            float ip = acc[2][reg] + bin;
            float hn = acc[3][reg] + bhn;
            float r  = 1.f/(1.f + expf(-rp));
            float z  = 1.f/(1.f + expf(-zp));
            float nn = tanhf(ip + r*hn);
            int tr = w*16 + quad*4 + reg;             // row within tile
            float hold = (float)Ah[tr*200 + 96 + jj]; // h_old from LDS A-tile
            _Float16 v16 = (_Float16)((1.f - z)*nn + z*hold);
            int node = order[li];
            hN[(long)node*HID + jj] = v16;
            hFout[(long)li*HID + jj] = v16;
        }
    }
}

// ---------------- out = h @ w_out + b_out via fp16 MFMA ----------------
__global__ void __launch_bounds__(512) out_kernel(
        const _Float16* __restrict__ hN, const _Float16* __restrict__ WoutF,
        const float* __restrict__ smallf, void* out, const int* mode, int N) {
    int row0 = blockIdx.x * BM;
    int jj0 = blockIdx.y * 16;

    __shared__ _Float16 Ah[128*104];
    __shared__ _Float16 Wh[16*104];

    int tid = threadIdx.x;
    long limit = (long)N * HID;
    #pragma unroll
    for (int j = 0; j < 3; j++) {
        int e = (tid + j*512) * 8;        // 12288 elems per tile
        int r = e / 96, c = e % 96;
        long ge = (long)(row0 + r)*HID + c;
        half8 v = {0,0,0,0,0,0,0,0};
        if (ge + 8 <= limit) v = *(const half8*)(hN + ge);
        *(half8*)(&Ah[r*104 + c]) = v;
    }
    if (tid < 192) {
        int wrow = tid / 12;
        int k = (tid % 12) * 8;
        *(half8*)(&Wh[wrow*104 + k]) = *(const half8*)(WoutF + (long)(jj0 + wrow)*HID + k);
    }
    __syncthreads();

    int lane = tid & 63;
    int w = tid >> 6;
    int m15 = lane & 15, quad = lane >> 4;
    floatx4 acc = {0.f, 0.f, 0.f, 0.f};
    int abase = (w*16 + m15)*104 + quad*8;
    #pragma unroll
    for (int ks = 0; ks < 3; ks++) {
        int k0 = ks*32;
        half8 a = *(const half8*)(&Ah[abase + k0]);
        half8 b = *(const half8*)(&Wh[m15*104 + quad*8 + k0]);
        acc = __builtin_amdgcn_mfma_f32_16x16x32_f16(a, b, acc, 0, 0, 0);
    }

    int jj = jj0 + m15;
    float b = smallf[672+jj];
    int m = *mode;
    #pragma unroll
    for (int reg = 0; reg < 4; reg++) {
        int li = row0 + w*16 + quad*4 + reg;
        if (li < N) {
            float v = acc[reg] + b;
            long oi = (long)li*OUTDIM + jj;
            if (m) ((float*)out)[oi] = v;
            else   ((__hip_bfloat16*)out)[oi] = __float2bfloat16(v);
        }
    }
}

extern "C" void kernel_launch(void* const* d_in, const int* in_sizes, int n_in,
                              void* d_out, int out_size, void* d_ws, size_t ws_size,
                              hipStream_t stream) {
    const void* x      = d_in[0];
    const int*  ei     = (const int*)d_in[1];
    const void* w_in   = d_in[2],  *b_in   = d_in[3];
    const void* tau_w1 = d_in[4],  *tau_b1 = d_in[5];
    const void* tau_w2 = d_in[6],  *tau_b2 = d_in[7];
    const void* wih    = d_in[8],  *whh    = d_in[9];
    const void* bih    = d_in[10], *bhh    = d_in[11];
    const void* w_out  = d_in[12], *b_out  = d_in[13];

    int N = in_sizes[0] / INDIM;
    int E = in_sizes[1] / 2;
    const int* row = ei;
    const int* col = ei + E;

    char* ws = (char*)d_ws;
    size_t o = 0;
    auto take = [&](size_t bytes) -> char* {
        char* p = ws + o;
        o = (o + bytes + 255) & ~(size_t)255;
        return p;
    };
    _Float16* hN    = (_Float16*)take((size_t)N*HID*2);
    _Float16* hFa   = (_Float16*)take((size_t)N*HID*2);
    _Float16* hFb   = (_Float16*)take((size_t)N*HID*2);
    _Float16* aggF  = (_Float16*)take((size_t)N*HID*2);
    _Float16* W2F   = (_Float16*)take((size_t)384*192*2);
    _Float16* WinF  = (_Float16*)take((size_t)96*128*2);
    _Float16* WoutF = (_Float16*)take((size_t)64*96*2);
    float* tau_w1_f = (float*)take((size_t)INDIM*16*4);
    float* smallf   = (float*)take(1024*4);
    int*   off      = (int*)take((size_t)(N+1)*4);
    int*   csr_col  = (int*)take((size_t)E*4);
    int*   order    = (int*)take((size_t)N*4);
    int*   steps    = (int*)take((size_t)N*4);
    int*   bstart   = (int*)take(64);
    int*   mode     = (int*)take(64);
    int*   blksum   = (int*)take((size_t)GP*8*4);
    int*   blkbase  = (int*)take((size_t)GP*8*4);
    char*  zbase    = ws + o;
    int*   deg      = (int*)take((size_t)N*4);
    int*   cur      = (int*)take((size_t)N*4);
    size_t zbytes   = (size_t)((ws + o) - zbase);

    hipMemsetAsync(zbase, 0, zbytes, stream);
    sniff_kernel<<<1, 64, 0, stream>>>((const unsigned int*)x, mode);

    prep_kernel<<<(384*192 + 255)/256, 256, 0, stream>>>(
        w_in, b_in, tau_w1, tau_b1, tau_w2, tau_b2, wih, whh, bih, bhh, w_out, b_out,
        W2F, WinF, WoutF, tau_w1_f, smallf, mode);

    dim3 hgrid((N + BM - 1)/BM, 6);
    h0_kernel<<<hgrid, 512, 0, stream>>>(x, WinF, smallf, mode, hN, N);
    tau_kernel<<<(N + 127)/128, 128, 0, stream>>>(x, tau_w1_f, smallf, mode, steps, N);
    deg_kernel<<<(E + 255)/256, 256, 0, stream>>>(row, deg, E);

    int C = (N + GP*256 - 1) / (GP*256);
    partial_kernel<<<GP, 256, 0, stream>>>(steps, deg, N, C, blksum);
    base_kernel<<<1, 64, 0, stream>>>(blksum, bstart, blkbase, off, N);
    scatter_kernel<<<GP, 256, 0, stream>>>(steps, deg, blkbase, N, C, order, off);

    pack_kernel<<<(N*HID + 255)/256, 256, 0, stream>>>(hN, order, hFa, N);
    fill_kernel<<<(E + 255)/256, 256, 0, stream>>>(row, col, off, cur, csr_col, E);

    dim3 ggrid((N + BM - 1)/BM, 6);
    _Float16* hin = hFa;
    _Float16* hout = hFb;
    for (int t = 0; t < 5; t++) {
        agg_kernel<<<4096, 256, 0, stream>>>(hN, off, csr_col, order, bstart, t, aggF);
        gru_kernel<<<ggrid, 512, 0, stream>>>(aggF, hin, W2F, smallf, bstart, t,
                                              order, hN, hout, N);
        _Float16* tmp = hin; hin = hout; hout = tmp;
    }

    dim3 ogrid((N + BM - 1)/BM, 4);
    out_kernel<<<ogrid, 512, 0, stream>>>(hN, WoutF, smallf, d_out, mode, N);
}